// Round 12
// baseline (881.416 us; speedup 1.0000x reference)
//
#include <hip/hip_runtime.h>
#include <hip/hip_bf16.h>
#include <math.h>

// xLSTM-Large forward: S=2048, D=1024, NH=4 (Dqk=128, Dv=256), UP=2752, L=2, V=32000.
// GEMMs: bf16 x bf16 MFMA, m97 single-buffered global_load_lds(16B) staging,
// XOR-swizzled LDS, bijective XCD block remap.
// This round: lm256 asymmetric buffering — A x2 (L2-resident, 1-deep) + B x3
// (HBM stream, 2-deep) = 80 KB LDS -> 2 blocks/CU (16 waves), counted vmcnt(2).

#define S_LEN 2048
#define DMODEL 1024
#define WLAYER 12845056  // elements per layer in W16

typedef __attribute__((ext_vector_type(8))) __bf16 bf16x8;
typedef __attribute__((ext_vector_type(8))) unsigned short u16x8;
typedef __attribute__((ext_vector_type(4))) unsigned short u16x4;
typedef __attribute__((ext_vector_type(4))) float f32x4v;

union cvu { u16x8 u; bf16x8 b; };

__device__ __forceinline__ unsigned short bf_us(float f) {
  union { __bf16 b; unsigned short u; } c;
  c.b = (__bf16)f;   // RNE, native v_cvt on gfx950
  return c.u;
}
__device__ __forceinline__ float us_f(unsigned short u) {
  union { __bf16 b; unsigned short u; } c;
  c.u = u;
  return (float)c.b;
}
__device__ __forceinline__ bf16x8 ld_bf8(const unsigned short* p, int byte_off) {
  cvu c;
  c.u = *(const u16x8*)((const char*)p + byte_off);
  return c.b;
}
__device__ __forceinline__ float fast_sigmoid(float v) {
  return 1.0f / (1.0f + __expf(-v));
}
__device__ __forceinline__ float fast_softcap30(float v) {
  float e = __expf(-fabsf(v) * (1.0f / 15.0f));  // e^{-2|v|/30}
  float t = (1.0f - e) / (1.0f + e);             // tanh(|v|/30)
  return copysignf(30.0f * t, v);
}

#define AS_G __attribute__((address_space(1)))
#define AS_L __attribute__((address_space(3)))

// Stage a 128x64 bf16 tile (16 KB) from global (row stride K elems) into LDS.
// LDS dest linear (DMA requirement); global SOURCE column-group pre-swizzled
// (cg ^= row&7) so the matching XOR on the read side is conflict-free (rule #21).
__device__ __forceinline__ void stage64(const unsigned short* gbase, int K,
                                        unsigned short* lds, int wave, int lane, int k0) {
#pragma unroll
  for (int j = 0; j < 4; ++j) {
    const int rbase = (j * 4 + wave) * 8;
    const int r = rbase + (lane >> 3);
    const int cg = (lane & 7) ^ (r & 7);   // pre-swizzled source column group
    const unsigned short* src = gbase + (size_t)r * K + k0 + cg * 8;
    __builtin_amdgcn_global_load_lds((const AS_G void*)src,
                                     (AS_L void*)(lds + rbase * 64), 16, 0, 0);
  }
}

// ---------------- embed ----------------
__global__ __launch_bounds__(256) void embed_kernel(
    const int* __restrict__ tok, const float* __restrict__ emb, float* __restrict__ x) {
  int s = blockIdx.x;
  int t = tok[s];
  const float4 v = *(const float4*)(emb + (size_t)t * DMODEL + threadIdx.x * 4);
  *(float4*)(x + (size_t)s * DMODEL + threadIdx.x * 4) = v;
}

// ---------------- rmsnorm (row = 1024): writes bf16 ----------------
__global__ __launch_bounds__(256) void rmsnorm_kernel(
    const float* __restrict__ x, const float* __restrict__ w,
    unsigned short* __restrict__ outb) {
  int s = blockIdx.x, tid = threadIdx.x;
  const float* xr = x + (size_t)s * DMODEL;
  float4 v = *(const float4*)(xr + tid * 4);
  float ss = v.x * v.x + v.y * v.y + v.z * v.z + v.w * v.w;
#pragma unroll
  for (int off = 32; off > 0; off >>= 1) ss += __shfl_down(ss, off);
  __shared__ float red[4];
  if ((tid & 63) == 0) red[tid >> 6] = ss;
  __syncthreads();
  float tot = red[0] + red[1] + red[2] + red[3];
  float scale = rsqrtf(tot * (1.0f / DMODEL) + 1e-6f);
  float4 wv = *(const float4*)(w + tid * 4);
  u16x4 ub;
  ub[0] = bf_us(v.x * scale * wv.x);
  ub[1] = bf_us(v.y * scale * wv.y);
  ub[2] = bf_us(v.z * scale * wv.z);
  ub[3] = bf_us(v.w * scale * wv.w);
  *(u16x4*)(outb + (size_t)s * DMODEL + tid * 4) = ub;
}

// ---------------- weight convert f32 -> bf16: both layers + LM head --------------
__global__ __launch_bounds__(256) void wcvt8_kernel(
    const float* __restrict__ Wq, const float* __restrict__ Wk,
    const float* __restrict__ Wv, const float* __restrict__ Wog,
    const float* __restrict__ Wout, const float* __restrict__ Wg,
    const float* __restrict__ Wu, const float* __restrict__ Wd,
    const float* __restrict__ Wlm,
    unsigned short* __restrict__ W, unsigned short* __restrict__ Wlm16) {
  const size_t de = ((size_t)blockIdx.x * 256 + threadIdx.x) * 8;
  if (de >= 2ull * WLAYER) {  // LM head region
    size_t i = de - 2ull * WLAYER;
    float4 a0 = *(const float4*)(Wlm + i);
    float4 a1 = *(const float4*)(Wlm + i + 4);
    u16x8 o;
    o[0] = bf_us(a0.x); o[1] = bf_us(a0.y); o[2] = bf_us(a0.z); o[3] = bf_us(a0.w);
    o[4] = bf_us(a1.x); o[5] = bf_us(a1.y); o[6] = bf_us(a1.z); o[7] = bf_us(a1.w);
    *(u16x8*)(Wlm16 + i) = o;
    return;
  }
  int e = (int)de, l = 0;
  if (e >= WLAYER) { l = 1; e -= WLAYER; }
  const float* src = nullptr;
  size_t idx = 0;
  if (e < 524288)       { src = Wq  + (size_t)l * 524288;  idx = e; }
  else if (e < 1048576) { src = Wk  + (size_t)l * 524288;  idx = e - 524288; }
  else if (e < 2097152) { src = Wv  + (size_t)l * 1048576; idx = e - 1048576; }
  else if (e < 3145728) { src = Wog + (size_t)l * 1048576; idx = e - 2097152; }
  else if (e < 4194304) { src = Wout + (size_t)l * 1048576; idx = e - 3145728; }
  else if (e < 7077888) {
    int t = e - 4194304, row = t >> 10;
    if (row < 2752) { src = Wg + (size_t)l * 2818048; idx = t; }
  } else if (e < 9961472) {
    int t = e - 7077888, row = t >> 10;
    if (row < 2752) { src = Wu + (size_t)l * 2818048; idx = t; }
  } else {
    int t = e - 9961472, row = t / 2816, col = t - row * 2816;
    if (col < 2752) { src = Wd + (size_t)l * 2818048; idx = row * 2752 + col; }
  }
  u16x8 o;
  if (src) {
    float4 a0 = *(const float4*)(src + idx);
    float4 a1 = *(const float4*)(src + idx + 4);
    o[0] = bf_us(a0.x); o[1] = bf_us(a0.y); o[2] = bf_us(a0.z); o[3] = bf_us(a0.w);
    o[4] = bf_us(a1.x); o[5] = bf_us(a1.y); o[6] = bf_us(a1.z); o[7] = bf_us(a1.w);
  } else {
#pragma unroll
    for (int k = 0; k < 8; ++k) o[k] = 0;
  }
  *(u16x8*)(W + de) = o;
}

// ---------------- GEMM core: 128x128 tile (layer GEMMs) ----------------
// EPI: 0 f32 store | 1 f32 acc+X residual
template <int EPI>
__global__ __launch_bounds__(256) void gemm_bb_kernel(
    const unsigned short* __restrict__ A, const unsigned short* __restrict__ B,
    const void* Xv, void* Cv, int K, int ldc) {
  __shared__ __align__(16) unsigned short As[128 * 64];
  __shared__ __align__(16) unsigned short Bs[128 * 64];
  const int tid = threadIdx.x;
  const int wave = tid >> 6, lane = tid & 63;
  const int gx = gridDim.x;
  const int nwg = gx * gridDim.y;
  const int d = blockIdx.y * gx + blockIdx.x;
  const int q = nwg >> 3;
  const int lgc = (d & 7) * q + (d >> 3);
  const int bm = (lgc % gx) * 128, bn = (lgc / gx) * 128;
  const int wr = (wave >> 1) * 64, wc = (wave & 1) * 64;
  const int lr = lane & 15, lhi = lane >> 4;
  const unsigned short* Ab = A + (size_t)bm * K;
  const unsigned short* Bb = B + (size_t)bn * K;
  f32x4v acc[4][4] = {};

  const int NK = K >> 6;
  for (int it = 0; it < NK; ++it) {
    stage64(Ab, K, As, wave, lane, it << 6);
    stage64(Bb, K, Bs, wave, lane, it << 6);
    __syncthreads();
#pragma unroll
    for (int kk = 0; kk < 2; ++kk) {
      const int sw = (((kk * 4 + lhi) ^ (lr & 7)) << 3);
      bf16x8 af[4], bfr[4];
#pragma unroll
      for (int mi = 0; mi < 4; ++mi) af[mi] = *(const bf16x8*)&As[(wr + mi * 16 + lr) * 64 + sw];
#pragma unroll
      for (int ni = 0; ni < 4; ++ni) bfr[ni] = *(const bf16x8*)&Bs[(wc + ni * 16 + lr) * 64 + sw];
#pragma unroll
      for (int mi = 0; mi < 4; ++mi)
#pragma unroll
        for (int ni = 0; ni < 4; ++ni)
          acc[mi][ni] = __builtin_amdgcn_mfma_f32_16x16x32_bf16(af[mi], bfr[ni], acc[mi][ni], 0, 0, 0);
    }
    __syncthreads();
  }
#pragma unroll
  for (int mi = 0; mi < 4; ++mi) {
#pragma unroll
    for (int ni = 0; ni < 4; ++ni) {
#pragma unroll
      for (int j = 0; j < 4; ++j) {
        int row = bm + wr + mi * 16 + lhi * 4 + j;   // C/D layout (m89)
        int col = bn + wc + ni * 16 + lr;
        float v = acc[mi][ni][j];
        if (EPI == 0)
          ((float*)Cv)[(size_t)row * ldc + col] = v;
        if (EPI == 1)
          ((float*)Cv)[(size_t)row * ldc + col] = v + ((const float*)Xv)[(size_t)row * ldc + col];
      }
    }
  }
}

// ---------------- LM head GEMM: 256x256 tile, 8 waves, BK=32 ----------------
// Asymmetric buffering: A x2 (32 KB, L2-resident, 1-deep prefetch) + B x3 (48 KB,
// HBM stream, 2-deep prefetch) = 80 KB -> 2 blocks/CU. Per K-tile:
//   vmcnt(2) -> s_barrier -> stageA(t+1) -> stageB(t+2) -> 12 ds_read + 32 MFMA.
// Issue-order proof: outstanding at wait = {B(t),A(t),B(t+1)} (6 loads); vmcnt(2)
// drains the 4 oldest = B(t),A(t) exactly. Final iter: vmcnt(0).
__global__ __launch_bounds__(512, 2) void lm256_kernel(
    const unsigned short* __restrict__ A, const unsigned short* __restrict__ B,
    float* __restrict__ C) {
  __shared__ __align__(16) unsigned short SHA[2 * 8192];  // 2 x 256x32 A tiles, 32 KB
  __shared__ __align__(16) unsigned short SHB[3 * 8192];  // 3 x 256x32 B tiles, 48 KB
  const int K = 1024, N = 32000, NT = 32;
  const int tid = threadIdx.x;
  const int wave = tid >> 6, lane = tid & 63;
  const int lr = lane & 15, lg = lane >> 4;
  const int wm = wave >> 2, wn = wave & 3;     // 2M x 4N waves, 128x64 each
  const int d = blockIdx.y * 8 + blockIdx.x;
  const int lgc = (d & 7) * 125 + (d >> 3);
  const int bm = (lgc & 7) * 256;
  const int bn = (lgc >> 3) * 256;
  const unsigned short* Ab = A + (size_t)bm * K;
  const unsigned short* Bb = B + (size_t)bn * K;

  // stage one 256x32 matrix tile (16 KB) into linear LDS: 2 issues of 8 KB
  auto stageM = [&](const unsigned short* gbase, unsigned short* lds, int k0) {
#pragma unroll
    for (int j = 0; j < 2; ++j) {
      const int r = j * 128 + wave * 16 + (lane >> 2);
      const int cg = (lane & 3) ^ ((r >> 1) & 3);   // pre-swizzled source column group
      const unsigned short* src = gbase + (size_t)r * K + k0 + cg * 8;
      __builtin_amdgcn_global_load_lds((const AS_G void*)src,
                                       (AS_L void*)(lds + (j * 128 + wave * 16) * 32), 16, 0, 0);
    }
  };
  auto stageA = [&](int tau) { stageM(Ab, SHA + (tau & 1) * 8192, tau * 32); };
  auto stageB = [&](int tau) { stageM(Bb, SHB + (tau % 3) * 8192, tau * 32); };

  f32x4v acc[8][4] = {};
  stageA(0);
  stageB(0);
  stageB(1);
  for (int t = 0; t < NT; ++t) {
    if (t < NT - 1) asm volatile("s_waitcnt vmcnt(2)" ::: "memory");
    else            asm volatile("s_waitcnt vmcnt(0)" ::: "memory");
    asm volatile("s_barrier" ::: "memory");
    if (t + 1 < NT) stageA(t + 1);
    if (t + 2 < NT) stageB(t + 2);
    const unsigned short* Al = SHA + (t & 1) * 8192;
    const unsigned short* Bl = SHB + (t % 3) * 8192;
    bf16x8 bfr[4];
#pragma unroll
    for (int ni = 0; ni < 4; ++ni) {
      int row = wn * 64 + ni * 16 + lr;
      bfr[ni] = *(const bf16x8*)&Bl[row * 32 + ((lg ^ ((row >> 1) & 3)) << 3)];
    }
#pragma unroll
    for (int mi = 0; mi < 8; ++mi) {
      int row = wm * 128 + mi * 16 + lr;
      bf16x8 af = *(const bf16x8*)&Al[row * 32 + ((lg ^ ((row >> 1) & 3)) << 3)];
      __builtin_amdgcn_s_setprio(1);
#pragma unroll
      for (int ni = 0; ni < 4; ++ni)
        acc[mi][ni] = __builtin_amdgcn_mfma_f32_16x16x32_bf16(af, bfr[ni], acc[mi][ni], 0, 0, 0);
      __builtin_amdgcn_s_setprio(0);
    }
  }
#pragma unroll
  for (int mi = 0; mi < 8; ++mi)
#pragma unroll
    for (int ni = 0; ni < 4; ++ni)
#pragma unroll
      for (int jj = 0; jj < 4; ++jj) {
        int row = bm + wm * 128 + mi * 16 + lg * 4 + jj;
        int col = bn + wn * 64 + ni * 16 + lr;
        C[(size_t)row * N + col] = fast_softcap30(acc[mi][ni][jj]);
      }
}

// ---------------- fused QKV+OG GEMM ----------------
__global__ __launch_bounds__(256) void qkvo_kernel(
    const unsigned short* __restrict__ A, const unsigned short* __restrict__ Wq16,
    const unsigned short* __restrict__ Wk16, const unsigned short* __restrict__ Wv16,
    const unsigned short* __restrict__ Wog16,
    unsigned short* __restrict__ qb, unsigned short* __restrict__ kb,
    unsigned short* __restrict__ vTb, float* __restrict__ og) {
  __shared__ __align__(16) unsigned short SH[2 * 128 * 64];
  unsigned short* Asb = SH;
  unsigned short* Bsb = SH + 128 * 64;
  const int tid = threadIdx.x;
  const int wave = tid >> 6, lane = tid & 63;
  const int gx = gridDim.x;                 // 16 (M)
  const int nwg = gx * gridDim.y;           // 384
  const int dd = blockIdx.y * gx + blockIdx.x;
  const int qq = nwg >> 3;
  const int lgc = (dd & 7) * qq + (dd >> 3);
  const int bm = (lgc % gx) * 128;
  const int by = lgc / gx;
  const unsigned short* B;
  int bnl, mode;
  if (by < 4)       { B = Wq16;  bnl = by * 128;        mode = 0; }
  else if (by < 8)  { B = Wk16;  bnl = (by - 4) * 128;  mode = 1; }
  else if (by < 16) { B = Wv16;  bnl = (by - 8) * 128;  mode = 2; }
  else              { B = Wog16; bnl = (by - 16) * 128; mode = 3; }
  const int K = 1024;
  const int wr = (wave >> 1) * 64, wc = (wave & 1) * 64;
  const int lr = lane & 15, lhi = lane >> 4;
  const unsigned short* Ab = A + (size_t)bm * K;
  const unsigned short* Bb = B + (size_t)bnl * K;
  f32x4v acc[4][4] = {};

  for (int it = 0; it < 16; ++it) {
    stage64(Ab, K, Asb, wave, lane, it << 6);
    stage64(Bb, K, Bsb, wave, lane, it << 6);
    __syncthreads();
#pragma unroll
    for (int kk = 0; kk < 2; ++kk) {
      const int sw = (((kk * 4 + lhi) ^ (lr & 7)) << 3);
      bf16x8 af[4], bfr[4];
#pragma unroll
      for (int mi = 0; mi < 4; ++mi) af[mi] = *(const bf16x8*)&Asb[(wr + mi * 16 + lr) * 64 + sw];
#pragma unroll
      for (int ni = 0; ni < 4; ++ni) bfr[ni] = *(const bf16x8*)&Bsb[(wc + ni * 16 + lr) * 64 + sw];
#pragma unroll
      for (int mi = 0; mi < 4; ++mi)
#pragma unroll
        for (int ni = 0; ni < 4; ++ni)
          acc[mi][ni] = __builtin_amdgcn_mfma_f32_16x16x32_bf16(af[mi], bfr[ni], acc[mi][ni], 0, 0, 0);
    }
    __syncthreads();
  }
  if (mode == 2) {
#pragma unroll
    for (int mi = 0; mi < 4; ++mi)
#pragma unroll
      for (int ni = 0; ni < 4; ++ni)
#pragma unroll
        for (int j = 0; j < 4; ++j) {
          int row = wr + mi * 16 + lhi * 4 + j;
          int col = wc + ni * 16 + lr;
          int byte = col * 256 + ((((row >> 3) ^ (col & 7)) << 4)) + (row & 7) * 2;
          *(unsigned short*)((char*)SH + byte) = bf_us(acc[mi][ni][j]);
        }
    __syncthreads();
#pragma unroll
    for (int i = 0; i < 8; ++i) {
      int c = i * 16 + (tid >> 4);
      int rg = tid & 15;
      u16x8 u = *(const u16x8*)((const char*)SH + c * 256 + ((rg ^ (c & 7)) << 4));
      *(u16x8*)(vTb + (size_t)(bnl + c) * S_LEN + bm + rg * 8) = u;
    }
  } else {
#pragma unroll
    for (int mi = 0; mi < 4; ++mi)
#pragma unroll
      for (int ni = 0; ni < 4; ++ni)
#pragma unroll
        for (int j = 0; j < 4; ++j) {
          int row = bm + wr + mi * 16 + lhi * 4 + j;
          int col = bnl + wc + ni * 16 + lr;
          if (mode == 0)      qb[(size_t)row * 512 + col] = bf_us(acc[mi][ni][j]);
          else if (mode == 1) kb[(size_t)row * 512 + col] = bf_us(acc[mi][ni][j]);
          else                og[(size_t)row * 1024 + col] = acc[mi][ni][j];
        }
  }
}

// ---------------- fused FFN gate+up GEMM: Gb = silu(A Wg^T) * (A Wu^T), bf16 -------
__global__ __launch_bounds__(256) void ffn_kernel(
    const unsigned short* __restrict__ A, const unsigned short* __restrict__ Bg,
    const unsigned short* __restrict__ Bu, unsigned short* __restrict__ Gb) {
  __shared__ __align__(16) unsigned short As[128 * 64];
  __shared__ __align__(16) unsigned short Bgs[128 * 64];
  __shared__ __align__(16) unsigned short Bus[128 * 64];
  const int K = 1024;
  const int tid = threadIdx.x;
  const int wave = tid >> 6, lane = tid & 63;
  const int gx = gridDim.x;                 // 16
  const int nwg = gx * gridDim.y;           // 352
  const int dd = blockIdx.y * gx + blockIdx.x;
  const int qq = nwg >> 3;
  const int lgc = (dd & 7) * qq + (dd >> 3);
  const int bm = (lgc % gx) * 128;
  const int bn = (lgc / gx) * 128;
  const int wr = (wave >> 1) * 64, wc = (wave & 1) * 64;
  const int lr = lane & 15, lhi = lane >> 4;
  const unsigned short* Ab = A + (size_t)bm * K;
  const unsigned short* Bgb = Bg + (size_t)bn * K;
  const unsigned short* Bub = Bu + (size_t)bn * K;
  f32x4v accg[4][4] = {};
  f32x4v accu[4][4] = {};
  for (int it = 0; it < 16; ++it) {
    stage64(Ab, K, As, wave, lane, it << 6);
    stage64(Bgb, K, Bgs, wave, lane, it << 6);
    stage64(Bub, K, Bus, wave, lane, it << 6);
    __syncthreads();
#pragma unroll
    for (int kk = 0; kk < 2; ++kk) {
      const int sw = (((kk * 4 + lhi) ^ (lr & 7)) << 3);
      bf16x8 af[4], bg[4], bu[4];
#pragma unroll
      for (int mi = 0; mi < 4; ++mi) af[mi] = *(const bf16x8*)&As[(wr + mi * 16 + lr) * 64 + sw];
#pragma unroll
      for (int ni = 0; ni < 4; ++ni) bg[ni] = *(const bf16x8*)&Bgs[(wc + ni * 16 + lr) * 64 + sw];
#pragma unroll
      for (int ni = 0; ni < 4; ++ni) bu[ni] = *(const bf16x8*)&Bus[(wc + ni * 16 + lr) * 64 + sw];
#pragma unroll
      for (int mi = 0; mi < 4; ++mi)
#pragma unroll
        for (int ni = 0; ni < 4; ++ni) {
          accg[mi][ni] = __builtin_amdgcn_mfma_f32_16x16x32_bf16(af[mi], bg[ni], accg[mi][ni], 0, 0, 0);
          accu[mi][ni] = __builtin_amdgcn_mfma_f32_16x16x32_bf16(af[mi], bu[ni], accu[mi][ni], 0, 0, 0);
        }
    }
    __syncthreads();
  }
#pragma unroll
  for (int mi = 0; mi < 4; ++mi) {
#pragma unroll
    for (int ni = 0; ni < 4; ++ni) {
#pragma unroll
      for (int j = 0; j < 4; ++j) {
        int row = bm + wr + mi * 16 + lhi * 4 + j;
        int col = bn + wc + ni * 16 + lr;
        float g = accg[mi][ni][j];
        float sv = g * fast_sigmoid(g) * accu[mi][ni][j];
        Gb[(size_t)row * 2816 + col] = bf_us(sv);
      }
    }
  }
}

// ---------------- gate pre-activations (inline rmsnorm from f32 x) ----------------
__global__ __launch_bounds__(256) void gates_kernel(
    const float* __restrict__ x, const float* __restrict__ n1,
    const float* __restrict__ Wi, const float* __restrict__ bi,
    const float* __restrict__ Wf, const float* __restrict__ bfv,
    float* __restrict__ ipre, float* __restrict__ fpre) {
  int s = blockIdx.x;
  int head = threadIdx.x >> 6, lane = threadIdx.x & 63;
  const float* xr = x + (size_t)s * DMODEL;
  float xv[16];
  float ss = 0.f;
#pragma unroll
  for (int j = 0; j < 16; ++j) { xv[j] = xr[lane + j * 64]; ss += xv[j] * xv[j]; }
#pragma unroll
  for (int off = 32; off > 0; off >>= 1) ss += __shfl_xor(ss, off);
  float scale = rsqrtf(ss * (1.0f / DMODEL) + 1e-6f);
  const float* wi = Wi + head * DMODEL;
  const float* wf = Wf + head * DMODEL;
  float si = 0.f, sf = 0.f;
#pragma unroll
  for (int j = 0; j < 16; ++j) {
    int c = lane + j * 64;
    float xm = xv[j] * scale * n1[c];
    si += xm * wi[c];
    sf += xm * wf[c];
  }
#pragma unroll
  for (int off = 32; off > 0; off >>= 1) {
    si += __shfl_down(si, off);
    sf += __shfl_down(sf, off);
  }
  if (lane == 0) {
    ipre[head * S_LEN + s] = 15.0f * tanhf((si + bi[head]) * (1.0f / 15.0f));
    fpre[head * S_LEN + s] = 15.0f * tanhf((sf + bfv[head]) * (1.0f / 15.0f));
  }
}

// ---------------- per-head scan ----------------
__global__ __launch_bounds__(256) void scan_kernel(
    const float* __restrict__ ipre, const float* __restrict__ fpre,
    float* __restrict__ garr, float* __restrict__ Marr, float* __restrict__ earr) {
  const int h = threadIdx.x >> 6;
  const int lane = threadIdx.x & 63;
  const int base = h * S_LEN + lane * 32;
  float lf[32];
  float lsum = 0.f;
#pragma unroll
  for (int e = 0; e < 32; ++e) {
    float f = fpre[base + e];
    float v = fminf(f, 0.f) - log1pf(expf(-fabsf(f)));
    lf[e] = v;
    lsum += v;
  }
  float scan = lsum;
#pragma unroll
  for (int off = 1; off < 64; off <<= 1) {
    float t = __shfl_up(scan, off);
    if (lane >= off) scan += t;
  }
  float F0 = scan - lsum;
  float gv[32];
  float F = F0, lmax = -1e30f;
#pragma unroll
  for (int e = 0; e < 32; ++e) {
    F += lf[e];
    float g = ipre[base + e] - F;
    gv[e] = g;
    lmax = fmaxf(lmax, g);
    garr[base + e] = g;
  }
  float ms = lmax;
#pragma unroll
  for (int off = 1; off < 64; off <<= 1) {
    float t = __shfl_up(ms, off);
    if (lane >= off) ms = fmaxf(ms, t);
  }
  float em = __shfl_up(ms, 1);
  if (lane == 0) em = -1e30f;
  float run = em;
  F = F0;
#pragma unroll
  for (int e = 0; e < 32; ++e) {
    F += lf[e];
    run = fmaxf(run, gv[e]);
    Marr[base + e] = run;
    earr[base + e] = expf(-(F + run));
  }
}

// ---------------- mLSTM parallel, bf16 MFMA flash-style, s-split x2 ----------------
__global__ __launch_bounds__(256) void mlstm_mfma_kernel(
    const unsigned short* __restrict__ Q, const unsigned short* __restrict__ Kb,
    const unsigned short* __restrict__ vT, const float* __restrict__ garr,
    const float* __restrict__ Marr,
    float* __restrict__ hp0, float* __restrict__ hp1, float* __restrict__ npart) {
  const int h = blockIdx.y;
  const int T = blockIdx.x;
  const int sp = blockIdx.z;
  float* hpart = sp ? hp1 : hp0;
  const int tid = threadIdx.x;
  const int w = tid >> 6, l = tid & 63;
  const int lr = l & 15, lg = l >> 4;
  const int hbase = h * S_LEN;
  const int sr = tid >> 4;
  const int sc = tid & 15;

  __shared__ __align__(16) unsigned short Ks[64 * 128];
  __shared__ __align__(16) unsigned short Vs[256 * 64];
  __shared__ __align__(16) unsigned short Ps[64 * 64];

  bf16x8 qf[4];
  {
    const unsigned short* qrow = Q + (size_t)(T * 64 + w * 16 + lr) * 512 + h * 128 + lg * 8;
#pragma unroll
    for (int kt = 0; kt < 4; ++kt) {
      cvu c;
      c.u = *(const u16x8*)(qrow + kt * 32);
      qf[kt] = c.b;
    }
  }
  float Mt[4];
#pragma unroll
  for (int j = 0; j < 4; ++j) Mt[j] = Marr[hbase + T * 64 + w * 16 + lg * 4 + j];

  f32x4v pv[16] = {};
  float nacc[4] = {0.f, 0.f, 0.f, 0.f};
  const float rs = 0.08838834764831845f;  // 1/sqrt(128)

  for (int ch = sp; ch <= T; ch += 2) {
    const int s0 = ch * 64;
    __syncthreads();
#pragma unroll
    for (int i = 0; i < 4; ++i) {
      int r = i * 16 + sr;
      u16x8 u = *(const u16x8*)(Kb + (size_t)(s0 + r) * 512 + h * 128 + sc * 8);
      int byte = r * 256 + ((sc * 16) ^ ((r & 7) << 4));
      *(u16x8*)((char*)Ks + byte) = u;
    }
#pragma unroll
    for (int i = 0; i < 16; ++i) {
      int r = i * 16 + sr;
      u16x4 u = *(const u16x4*)(vT + (size_t)(h * 256 + r) * S_LEN + s0 + sc * 4);
      int byte = r * 128 + ((sc * 8) ^ ((r & 7) << 4));
      *(u16x4*)((char*)Vs + byte) = u;
    }
    __syncthreads();
    f32x4v sa[4] = {};
#pragma unroll
    for (int ni = 0; ni < 4; ++ni) {
#pragma unroll
      for (int kt = 0; kt < 4; ++kt) {
        int row = ni * 16 + lr;
        int byte = row * 256 + (((kt * 32 + lg * 8) * 2) ^ ((row & 7) << 4));
        bf16x8 kf = ld_bf8(Ks, byte);
        sa[ni] = __builtin_amdgcn_mfma_f32_16x16x32_bf16(qf[kt], kf, sa[ni], 0, 0, 0);
      }
    }
#pragma unroll
    for (int ni = 0; ni < 4; ++ni) {
      int sl = ni * 16 + lr;
      int sg = s0 + sl;
      float gv = garr[hbase + sg];
#pragma unroll
      for (int j = 0; j < 4; ++j) {
        int tloc = w * 16 + lg * 4 + j;
        int tg = T * 64 + tloc;
        float wgt = (sg <= tg) ? __expf(gv - Mt[j]) : 0.f;
        float val = sa[ni][j] * rs * wgt;
        nacc[j] += val;
        int byte = tloc * 128 + ((sl * 2) ^ ((tloc & 7) << 4));
        *(unsigned short*)((char*)Ps + byte) = bf_us(val);
      }
    }
#pragma unroll
    for (int kt2 = 0; kt2 < 2; ++kt2) {
      int tloc = w * 16 + lr;
      int sb = (kt2 * 32 + lg * 8) * 2;
      bf16x8 pa = ld_bf8(Ps, tloc * 128 + (sb ^ ((tloc & 7) << 4)));
#pragma unroll
      for (int nv = 0; nv < 16; ++nv) {
        int dv = nv * 16 + lr;
        bf16x8 vb = ld_bf8(Vs, dv * 128 + (sb ^ ((dv & 7) << 4)));
        pv[nv] = __builtin_amdgcn_mfma_f32_16x16x32_bf16(pa, vb, pv[nv], 0, 0, 0);
      }
    }
  }
#pragma unroll
  for (int j = 0; j < 4; ++j) {
#pragma unroll
    for (int off = 1; off < 16; off <<= 1) nacc[j] += __shfl_xor(nacc[j], off);
  }
#pragma unroll
  for (int j = 0; j < 4; ++j) {
    int tg = T * 64 + w * 16 + lg * 4 + j;
    if (lr == 0) npart[sp * 8192 + hbase + tg] = nacc[j];
    float* orow = hpart + (size_t)tg * DMODEL + h * 256;
#pragma unroll
    for (int nvt = 0; nvt < 16; ++nvt) orow[nvt * 16 + lr] = pv[nvt][j];
  }
}

// ---------------- combine + multihead LayerNorm * mhw * sigmoid(og) -> bf16 -------
__global__ __launch_bounds__(256) void mhln_gate_kernel(
    const float* __restrict__ hp0, const float* __restrict__ hp1,
    const float* __restrict__ npart, const float* __restrict__ earr,
    const float* __restrict__ mhw, const float* __restrict__ og,
    unsigned short* __restrict__ gact) {
  int s = blockIdx.x;
  int head = threadIdx.x >> 6, lane = threadIdx.x & 63;
  float n = npart[head * S_LEN + s] + npart[8192 + head * S_LEN + s];
  float nvv = fmaxf(fabsf(n), earr[head * S_LEN + s]);
  float inv = 1.0f / (nvv + 1e-6f);
  const size_t base = (size_t)s * DMODEL + head * 256;
  float v0 = (hp0[base + lane] + hp1[base + lane]) * inv;
  float v1 = (hp0[base + lane + 64] + hp1[base + lane + 64]) * inv;
  float v2 = (hp0[base + lane + 128] + hp1[base + lane + 128]) * inv;
  float v3 = (hp0[base + lane + 192] + hp1[base + lane + 192]) * inv;
  float sum = v0 + v1 + v2 + v3;
#pragma unroll
  for (int off = 32; off > 0; off >>= 1) sum += __shfl_xor(sum, off);
  float mu = sum * (1.0f / 256.0f);
  float d0 = v0 - mu, d1 = v1 - mu, d2 = v2 - mu, d3 = v3 - mu;
  float vs = d0 * d0 + d1 * d1 + d2 * d2 + d3 * d3;
#pragma unroll
  for (int off = 32; off > 0; off >>= 1) vs += __shfl_xor(vs, off);
  float rstd = rsqrtf(vs * (1.0f / 256.0f) + 1e-6f);
  float dn[4] = {d0, d1, d2, d3};
#pragma unroll
  for (int qy = 0; qy < 4; ++qy) {
    int c = head * 256 + qy * 64 + lane;
    float ov = og[(size_t)s * DMODEL + c];
    gact[(size_t)s * DMODEL + c] = bf_us(dn[qy] * rstd * mhw[c] * fast_sigmoid(ov));
  }
}

extern "C" void kernel_launch(void* const* d_in, const int* in_sizes, int n_in,
                              void* d_out, int out_size, void* d_ws, size_t ws_size,
                              hipStream_t stream) {
  (void)in_sizes; (void)n_in; (void)out_size; (void)ws_size;
  const int*   tok   = (const int*)d_in[0];
  const float* emb   = (const float*)d_in[1];
  const float* norm1 = (const float*)d_in[2];
  const float* Wq    = (const float*)d_in[3];
  const float* Wk    = (const float*)d_in[4];
  const float* Wv    = (const float*)d_in[5];
  const float* Wog   = (const float*)d_in[6];
  const float* Wi    = (const float*)d_in[7];
  const float* bi    = (const float*)d_in[8];
  const float* Wf    = (const float*)d_in[9];
  const float* bfp   = (const float*)d_in[10];
  const float* mhw   = (const float*)d_in[11];
  const float* Wout  = (const float*)d_in[12];
  const float* norm2 = (const float*)d_in[13];
  const float* Wg    = (const float*)d_in[14];
  const float* Wu    = (const float*)d_in[15];
  const float* Wd    = (const float*)d_in[16];
  const float* onw   = (const float*)d_in[17];
  const float* Wlm   = (const float*)d_in[18];

  char* wsb = (char*)d_ws;
  const size_t MB = 1ull << 20;
  float*          x    = (float*)wsb;                          // 8 MiB
  unsigned short* xmb  = (unsigned short*)(wsb + 8 * MB);      // 4 MiB
  float*          ipre = (float*)(wsb + 12 * MB);              // 5 x 32 KiB
  float*          fpre = ipre + 8192;
  float*          garr = fpre + 8192;
  float*          Marr = garr + 8192;
  float*          earr = Marr + 8192;
  float*          npart = earr + 8192;                         // 2 x 32 KiB
  unsigned short* W16  = (unsigned short*)(wsb + 13 * MB);     // 49 MiB -> ends 62
  const size_t OQ = 0, OKk = 524288, OV = 1048576, OOG = 2097152, OOUT = 3145728,
               OGt = 4194304, OU = 7077888, OD = 9961472;
  unsigned short* qb    = (unsigned short*)(wsb + 62 * MB);    // 2 MiB
  unsigned short* kb    = (unsigned short*)(wsb + 64 * MB);    // 2 MiB
  unsigned short* vTb   = (unsigned short*)(wsb + 66 * MB);    // 4 MiB
  float*          og    = (float*)(wsb + 70 * MB);             // 8 MiB
  float*          hp0   = (float*)(wsb + 78 * MB);             // 8 MiB
  float*          hp1   = (float*)(wsb + 86 * MB);             // 8 MiB
  unsigned short* gact  = (unsigned short*)(wsb + 94 * MB);    // 4 MiB
  unsigned short* Gb16  = (unsigned short*)(wsb + 98 * MB);    // 11 MiB -> ends 109
  unsigned short* wlm16 = (unsigned short*)(wsb + 110 * MB);   // 62.5 MiB -> ends 172.5

  embed_kernel<<<2048, 256, 0, stream>>>(tok, emb, x);
  wcvt8_kernel<<<28544, 256, 0, stream>>>(Wq, Wk, Wv, Wog, Wout, Wg, Wu, Wd, Wlm,
                                          W16, wlm16);

  for (int l = 0; l < 2; ++l) {
    const unsigned short* Wl = W16 + (size_t)l * WLAYER;
    const float* n1   = norm1 + (size_t)l * 1024;
    const float* wiv  = Wi   + (size_t)l * 4 * 1024;
    const float* bil  = bi   + (size_t)l * 4;
    const float* wfv  = Wf   + (size_t)l * 4 * 1024;
    const float* bfl  = bfp  + (size_t)l * 4;
    const float* mhwl = mhw  + (size_t)l * 1024;
    const float* n2   = norm2 + (size_t)l * 1024;

    rmsnorm_kernel<<<2048, 256, 0, stream>>>(x, n1, xmb);
    qkvo_kernel<<<dim3(16, 24), 256, 0, stream>>>(xmb, Wl + OQ, Wl + OKk, Wl + OV,
                                                  Wl + OOG, qb, kb, vTb, og);
    gates_kernel<<<2048, 256, 0, stream>>>(x, n1, wiv, bil, wfv, bfl, ipre, fpre);
    scan_kernel<<<1, 256, 0, stream>>>(ipre, fpre, garr, Marr, earr);
    mlstm_mfma_kernel<<<dim3(32, 4, 2), 256, 0, stream>>>(qb, kb, vTb, garr, Marr,
                                                          hp0, hp1, npart);
    mhln_gate_kernel<<<2048, 256, 0, stream>>>(hp0, hp1, npart, earr, mhwl, og, gact);
    gemm_bb_kernel<1><<<dim3(16, 8), 256, 0, stream>>>(gact, Wl + OOUT, x, x, 1024, 1024);
    rmsnorm_kernel<<<2048, 256, 0, stream>>>(x, n2, xmb);
    ffn_kernel<<<dim3(16, 22), 256, 0, stream>>>(xmb, Wl + OGt, Wl + OU, Gb16);
    gemm_bb_kernel<1><<<dim3(16, 8), 256, 0, stream>>>(Gb16, Wl + OD, x, x, 2816, 1024);
  }

  rmsnorm_kernel<<<2048, 256, 0, stream>>>(x, onw, xmb);
  lm256_kernel<<<dim3(8, 125), 512, 0, stream>>>(xmb, wlm16, (float*)d_out);
}

// Round 13
// 870.447 us; speedup vs baseline: 1.0126x; 1.0126x over previous
//
#include <hip/hip_runtime.h>
#include <hip/hip_bf16.h>
#include <math.h>

// xLSTM-Large forward: S=2048, D=1024, NH=4 (Dqk=128, Dv=256), UP=2752, L=2, V=32000.
// GEMMs: bf16 x bf16 MFMA, m97 single-buffered global_load_lds(16B) staging,
// XOR-swizzled LDS, bijective XCD block remap.
// This round: lm256 = BK=32, symmetric 2-buffer (64 KB -> 2 blocks/CU), 2-deep
// prefetch via stage-after-trailing-barrier, counted vmcnt(4) (round-9-verified
// placement; round-12's asymmetric 80 KB variant reverted — 1-deep A stalls + no
// occupancy gain at exactly-160KB).

#define S_LEN 2048
#define DMODEL 1024
#define WLAYER 12845056  // elements per layer in W16

typedef __attribute__((ext_vector_type(8))) __bf16 bf16x8;
typedef __attribute__((ext_vector_type(8))) unsigned short u16x8;
typedef __attribute__((ext_vector_type(4))) unsigned short u16x4;
typedef __attribute__((ext_vector_type(4))) float f32x4v;

union cvu { u16x8 u; bf16x8 b; };

__device__ __forceinline__ unsigned short bf_us(float f) {
  union { __bf16 b; unsigned short u; } c;
  c.b = (__bf16)f;   // RNE, native v_cvt on gfx950
  return c.u;
}
__device__ __forceinline__ float us_f(unsigned short u) {
  union { __bf16 b; unsigned short u; } c;
  c.u = u;
  return (float)c.b;
}
__device__ __forceinline__ bf16x8 ld_bf8(const unsigned short* p, int byte_off) {
  cvu c;
  c.u = *(const u16x8*)((const char*)p + byte_off);
  return c.b;
}
__device__ __forceinline__ float fast_sigmoid(float v) {
  return 1.0f / (1.0f + __expf(-v));
}
__device__ __forceinline__ float fast_softcap30(float v) {
  float e = __expf(-fabsf(v) * (1.0f / 15.0f));  // e^{-2|v|/30}
  float t = (1.0f - e) / (1.0f + e);             // tanh(|v|/30)
  return copysignf(30.0f * t, v);
}

#define AS_G __attribute__((address_space(1)))
#define AS_L __attribute__((address_space(3)))

// Stage a 128x64 bf16 tile (16 KB) from global (row stride K elems) into LDS.
// LDS dest linear (DMA requirement); global SOURCE column-group pre-swizzled
// (cg ^= row&7) so the matching XOR on the read side is conflict-free (rule #21).
__device__ __forceinline__ void stage64(const unsigned short* gbase, int K,
                                        unsigned short* lds, int wave, int lane, int k0) {
#pragma unroll
  for (int j = 0; j < 4; ++j) {
    const int rbase = (j * 4 + wave) * 8;
    const int r = rbase + (lane >> 3);
    const int cg = (lane & 7) ^ (r & 7);   // pre-swizzled source column group
    const unsigned short* src = gbase + (size_t)r * K + k0 + cg * 8;
    __builtin_amdgcn_global_load_lds((const AS_G void*)src,
                                     (AS_L void*)(lds + rbase * 64), 16, 0, 0);
  }
}

// ---------------- embed ----------------
__global__ __launch_bounds__(256) void embed_kernel(
    const int* __restrict__ tok, const float* __restrict__ emb, float* __restrict__ x) {
  int s = blockIdx.x;
  int t = tok[s];
  const float4 v = *(const float4*)(emb + (size_t)t * DMODEL + threadIdx.x * 4);
  *(float4*)(x + (size_t)s * DMODEL + threadIdx.x * 4) = v;
}

// ---------------- rmsnorm (row = 1024): writes bf16 ----------------
__global__ __launch_bounds__(256) void rmsnorm_kernel(
    const float* __restrict__ x, const float* __restrict__ w,
    unsigned short* __restrict__ outb) {
  int s = blockIdx.x, tid = threadIdx.x;
  const float* xr = x + (size_t)s * DMODEL;
  float4 v = *(const float4*)(xr + tid * 4);
  float ss = v.x * v.x + v.y * v.y + v.z * v.z + v.w * v.w;
#pragma unroll
  for (int off = 32; off > 0; off >>= 1) ss += __shfl_down(ss, off);
  __shared__ float red[4];
  if ((tid & 63) == 0) red[tid >> 6] = ss;
  __syncthreads();
  float tot = red[0] + red[1] + red[2] + red[3];
  float scale = rsqrtf(tot * (1.0f / DMODEL) + 1e-6f);
  float4 wv = *(const float4*)(w + tid * 4);
  u16x4 ub;
  ub[0] = bf_us(v.x * scale * wv.x);
  ub[1] = bf_us(v.y * scale * wv.y);
  ub[2] = bf_us(v.z * scale * wv.z);
  ub[3] = bf_us(v.w * scale * wv.w);
  *(u16x4*)(outb + (size_t)s * DMODEL + tid * 4) = ub;
}

// ---------------- weight convert f32 -> bf16: both layers + LM head --------------
__global__ __launch_bounds__(256) void wcvt8_kernel(
    const float* __restrict__ Wq, const float* __restrict__ Wk,
    const float* __restrict__ Wv, const float* __restrict__ Wog,
    const float* __restrict__ Wout, const float* __restrict__ Wg,
    const float* __restrict__ Wu, const float* __restrict__ Wd,
    const float* __restrict__ Wlm,
    unsigned short* __restrict__ W, unsigned short* __restrict__ Wlm16) {
  const size_t de = ((size_t)blockIdx.x * 256 + threadIdx.x) * 8;
  if (de >= 2ull * WLAYER) {  // LM head region
    size_t i = de - 2ull * WLAYER;
    float4 a0 = *(const float4*)(Wlm + i);
    float4 a1 = *(const float4*)(Wlm + i + 4);
    u16x8 o;
    o[0] = bf_us(a0.x); o[1] = bf_us(a0.y); o[2] = bf_us(a0.z); o[3] = bf_us(a0.w);
    o[4] = bf_us(a1.x); o[5] = bf_us(a1.y); o[6] = bf_us(a1.z); o[7] = bf_us(a1.w);
    *(u16x8*)(Wlm16 + i) = o;
    return;
  }
  int e = (int)de, l = 0;
  if (e >= WLAYER) { l = 1; e -= WLAYER; }
  const float* src = nullptr;
  size_t idx = 0;
  if (e < 524288)       { src = Wq  + (size_t)l * 524288;  idx = e; }
  else if (e < 1048576) { src = Wk  + (size_t)l * 524288;  idx = e - 524288; }
  else if (e < 2097152) { src = Wv  + (size_t)l * 1048576; idx = e - 1048576; }
  else if (e < 3145728) { src = Wog + (size_t)l * 1048576; idx = e - 2097152; }
  else if (e < 4194304) { src = Wout + (size_t)l * 1048576; idx = e - 3145728; }
  else if (e < 7077888) {
    int t = e - 4194304, row = t >> 10;
    if (row < 2752) { src = Wg + (size_t)l * 2818048; idx = t; }
  } else if (e < 9961472) {
    int t = e - 7077888, row = t >> 10;
    if (row < 2752) { src = Wu + (size_t)l * 2818048; idx = t; }
  } else {
    int t = e - 9961472, row = t / 2816, col = t - row * 2816;
    if (col < 2752) { src = Wd + (size_t)l * 2818048; idx = row * 2752 + col; }
  }
  u16x8 o;
  if (src) {
    float4 a0 = *(const float4*)(src + idx);
    float4 a1 = *(const float4*)(src + idx + 4);
    o[0] = bf_us(a0.x); o[1] = bf_us(a0.y); o[2] = bf_us(a0.z); o[3] = bf_us(a0.w);
    o[4] = bf_us(a1.x); o[5] = bf_us(a1.y); o[6] = bf_us(a1.z); o[7] = bf_us(a1.w);
  } else {
#pragma unroll
    for (int k = 0; k < 8; ++k) o[k] = 0;
  }
  *(u16x8*)(W + de) = o;
}

// ---------------- GEMM core: 128x128 tile (layer GEMMs) ----------------
// EPI: 0 f32 store | 1 f32 acc+X residual
template <int EPI>
__global__ __launch_bounds__(256) void gemm_bb_kernel(
    const unsigned short* __restrict__ A, const unsigned short* __restrict__ B,
    const void* Xv, void* Cv, int K, int ldc) {
  __shared__ __align__(16) unsigned short As[128 * 64];
  __shared__ __align__(16) unsigned short Bs[128 * 64];
  const int tid = threadIdx.x;
  const int wave = tid >> 6, lane = tid & 63;
  const int gx = gridDim.x;
  const int nwg = gx * gridDim.y;
  const int d = blockIdx.y * gx + blockIdx.x;
  const int q = nwg >> 3;
  const int lgc = (d & 7) * q + (d >> 3);
  const int bm = (lgc % gx) * 128, bn = (lgc / gx) * 128;
  const int wr = (wave >> 1) * 64, wc = (wave & 1) * 64;
  const int lr = lane & 15, lhi = lane >> 4;
  const unsigned short* Ab = A + (size_t)bm * K;
  const unsigned short* Bb = B + (size_t)bn * K;
  f32x4v acc[4][4] = {};

  const int NK = K >> 6;
  for (int it = 0; it < NK; ++it) {
    stage64(Ab, K, As, wave, lane, it << 6);
    stage64(Bb, K, Bs, wave, lane, it << 6);
    __syncthreads();
#pragma unroll
    for (int kk = 0; kk < 2; ++kk) {
      const int sw = (((kk * 4 + lhi) ^ (lr & 7)) << 3);
      bf16x8 af[4], bfr[4];
#pragma unroll
      for (int mi = 0; mi < 4; ++mi) af[mi] = *(const bf16x8*)&As[(wr + mi * 16 + lr) * 64 + sw];
#pragma unroll
      for (int ni = 0; ni < 4; ++ni) bfr[ni] = *(const bf16x8*)&Bs[(wc + ni * 16 + lr) * 64 + sw];
#pragma unroll
      for (int mi = 0; mi < 4; ++mi)
#pragma unroll
        for (int ni = 0; ni < 4; ++ni)
          acc[mi][ni] = __builtin_amdgcn_mfma_f32_16x16x32_bf16(af[mi], bfr[ni], acc[mi][ni], 0, 0, 0);
    }
    __syncthreads();
  }
#pragma unroll
  for (int mi = 0; mi < 4; ++mi) {
#pragma unroll
    for (int ni = 0; ni < 4; ++ni) {
#pragma unroll
      for (int j = 0; j < 4; ++j) {
        int row = bm + wr + mi * 16 + lhi * 4 + j;   // C/D layout (m89)
        int col = bn + wc + ni * 16 + lr;
        float v = acc[mi][ni][j];
        if (EPI == 0)
          ((float*)Cv)[(size_t)row * ldc + col] = v;
        if (EPI == 1)
          ((float*)Cv)[(size_t)row * ldc + col] = v + ((const float*)Xv)[(size_t)row * ldc + col];
      }
    }
  }
}

// ---------------- LM head GEMM: 256x256 tile, 8 waves, BK=32, 2-buffer 64 KB ------
// Per K-tile t: vmcnt(4) -> s_barrier -> 12 ds_read + 32 MFMA -> s_barrier ->
// stage(t+2) into buf t&1 (safe: all waves finished reading it).
// Prologue stages t=0,1 (8 loads); vmcnt(4) at top drains exactly tile t's 4 loads;
// 2-deep prefetch (stage at end of t, consumed at t+2). 64 KB -> 2 blocks/CU.
__global__ __launch_bounds__(512, 2) void lm256_kernel(
    const unsigned short* __restrict__ A, const unsigned short* __restrict__ B,
    float* __restrict__ C) {
  __shared__ __align__(16) unsigned short SHA[2 * 8192];  // 2 x 256x32 A tiles, 32 KB
  __shared__ __align__(16) unsigned short SHB[2 * 8192];  // 2 x 256x32 B tiles, 32 KB
  const int K = 1024, N = 32000, NT = 32;
  const int tid = threadIdx.x;
  const int wave = tid >> 6, lane = tid & 63;
  const int lr = lane & 15, lg = lane >> 4;
  const int wm = wave >> 2, wn = wave & 3;     // 2M x 4N waves, 128x64 each
  const int d = blockIdx.y * 8 + blockIdx.x;
  const int lgc = (d & 7) * 125 + (d >> 3);
  const int bm = (lgc & 7) * 256;
  const int bn = (lgc >> 3) * 256;
  const unsigned short* Ab = A + (size_t)bm * K;
  const unsigned short* Bb = B + (size_t)bn * K;

  // stage one 256x32 matrix tile (16 KB) into linear LDS: 2 issues of 8 KB
  auto stageM = [&](const unsigned short* gbase, unsigned short* lds, int k0) {
#pragma unroll
    for (int j = 0; j < 2; ++j) {
      const int r = j * 128 + wave * 16 + (lane >> 2);
      const int cg = (lane & 3) ^ ((r >> 1) & 3);   // pre-swizzled source column group
      const unsigned short* src = gbase + (size_t)r * K + k0 + cg * 8;
      __builtin_amdgcn_global_load_lds((const AS_G void*)src,
                                       (AS_L void*)(lds + (j * 128 + wave * 16) * 32), 16, 0, 0);
    }
  };
  auto stageT = [&](int tau) {
    stageM(Ab, SHA + (tau & 1) * 8192, tau * 32);
    stageM(Bb, SHB + (tau & 1) * 8192, tau * 32);
  };

  f32x4v acc[8][4] = {};
  stageT(0);
  stageT(1);
  for (int t = 0; t < NT; ++t) {
    if (t < NT - 1) asm volatile("s_waitcnt vmcnt(4)" ::: "memory");
    else            asm volatile("s_waitcnt vmcnt(0)" ::: "memory");
    asm volatile("s_barrier" ::: "memory");
    const unsigned short* Al = SHA + (t & 1) * 8192;
    const unsigned short* Bl = SHB + (t & 1) * 8192;
    bf16x8 bfr[4];
#pragma unroll
    for (int ni = 0; ni < 4; ++ni) {
      int row = wn * 64 + ni * 16 + lr;
      bfr[ni] = *(const bf16x8*)&Bl[row * 32 + ((lg ^ ((row >> 1) & 3)) << 3)];
    }
#pragma unroll
    for (int mi = 0; mi < 8; ++mi) {
      int row = wm * 128 + mi * 16 + lr;
      bf16x8 af = *(const bf16x8*)&Al[row * 32 + ((lg ^ ((row >> 1) & 3)) << 3)];
      __builtin_amdgcn_s_setprio(1);
#pragma unroll
      for (int ni = 0; ni < 4; ++ni)
        acc[mi][ni] = __builtin_amdgcn_mfma_f32_16x16x32_bf16(af, bfr[ni], acc[mi][ni], 0, 0, 0);
      __builtin_amdgcn_s_setprio(0);
    }
    asm volatile("s_barrier" ::: "memory");
    if (t + 2 < NT) stageT(t + 2);
  }
#pragma unroll
  for (int mi = 0; mi < 8; ++mi)
#pragma unroll
    for (int ni = 0; ni < 4; ++ni)
#pragma unroll
      for (int jj = 0; jj < 4; ++jj) {
        int row = bm + wm * 128 + mi * 16 + lg * 4 + jj;
        int col = bn + wn * 64 + ni * 16 + lr;
        C[(size_t)row * N + col] = fast_softcap30(acc[mi][ni][jj]);
      }
}

// ---------------- fused QKV+OG GEMM ----------------
__global__ __launch_bounds__(256) void qkvo_kernel(
    const unsigned short* __restrict__ A, const unsigned short* __restrict__ Wq16,
    const unsigned short* __restrict__ Wk16, const unsigned short* __restrict__ Wv16,
    const unsigned short* __restrict__ Wog16,
    unsigned short* __restrict__ qb, unsigned short* __restrict__ kb,
    unsigned short* __restrict__ vTb, float* __restrict__ og) {
  __shared__ __align__(16) unsigned short SH[2 * 128 * 64];
  unsigned short* Asb = SH;
  unsigned short* Bsb = SH + 128 * 64;
  const int tid = threadIdx.x;
  const int wave = tid >> 6, lane = tid & 63;
  const int gx = gridDim.x;                 // 16 (M)
  const int nwg = gx * gridDim.y;           // 384
  const int dd = blockIdx.y * gx + blockIdx.x;
  const int qq = nwg >> 3;
  const int lgc = (dd & 7) * qq + (dd >> 3);
  const int bm = (lgc % gx) * 128;
  const int by = lgc / gx;
  const unsigned short* B;
  int bnl, mode;
  if (by < 4)       { B = Wq16;  bnl = by * 128;        mode = 0; }
  else if (by < 8)  { B = Wk16;  bnl = (by - 4) * 128;  mode = 1; }
  else if (by < 16) { B = Wv16;  bnl = (by - 8) * 128;  mode = 2; }
  else              { B = Wog16; bnl = (by - 16) * 128; mode = 3; }
  const int K = 1024;
  const int wr = (wave >> 1) * 64, wc = (wave & 1) * 64;
  const int lr = lane & 15, lhi = lane >> 4;
  const unsigned short* Ab = A + (size_t)bm * K;
  const unsigned short* Bb = B + (size_t)bnl * K;
  f32x4v acc[4][4] = {};

  for (int it = 0; it < 16; ++it) {
    stage64(Ab, K, Asb, wave, lane, it << 6);
    stage64(Bb, K, Bsb, wave, lane, it << 6);
    __syncthreads();
#pragma unroll
    for (int kk = 0; kk < 2; ++kk) {
      const int sw = (((kk * 4 + lhi) ^ (lr & 7)) << 3);
      bf16x8 af[4], bfr[4];
#pragma unroll
      for (int mi = 0; mi < 4; ++mi) af[mi] = *(const bf16x8*)&Asb[(wr + mi * 16 + lr) * 64 + sw];
#pragma unroll
      for (int ni = 0; ni < 4; ++ni) bfr[ni] = *(const bf16x8*)&Bsb[(wc + ni * 16 + lr) * 64 + sw];
#pragma unroll
      for (int mi = 0; mi < 4; ++mi)
#pragma unroll
        for (int ni = 0; ni < 4; ++ni)
          acc[mi][ni] = __builtin_amdgcn_mfma_f32_16x16x32_bf16(af[mi], bfr[ni], acc[mi][ni], 0, 0, 0);
    }
    __syncthreads();
  }
  if (mode == 2) {
#pragma unroll
    for (int mi = 0; mi < 4; ++mi)
#pragma unroll
      for (int ni = 0; ni < 4; ++ni)
#pragma unroll
        for (int j = 0; j < 4; ++j) {
          int row = wr + mi * 16 + lhi * 4 + j;
          int col = wc + ni * 16 + lr;
          int byte = col * 256 + ((((row >> 3) ^ (col & 7)) << 4)) + (row & 7) * 2;
          *(unsigned short*)((char*)SH + byte) = bf_us(acc[mi][ni][j]);
        }
    __syncthreads();
#pragma unroll
    for (int i = 0; i < 8; ++i) {
      int c = i * 16 + (tid >> 4);
      int rg = tid & 15;
      u16x8 u = *(const u16x8*)((const char*)SH + c * 256 + ((rg ^ (c & 7)) << 4));
      *(u16x8*)(vTb + (size_t)(bnl + c) * S_LEN + bm + rg * 8) = u;
    }
  } else {
#pragma unroll
    for (int mi = 0; mi < 4; ++mi)
#pragma unroll
      for (int ni = 0; ni < 4; ++ni)
#pragma unroll
        for (int j = 0; j < 4; ++j) {
          int row = bm + wr + mi * 16 + lhi * 4 + j;
          int col = bnl + wc + ni * 16 + lr;
          if (mode == 0)      qb[(size_t)row * 512 + col] = bf_us(acc[mi][ni][j]);
          else if (mode == 1) kb[(size_t)row * 512 + col] = bf_us(acc[mi][ni][j]);
          else                og[(size_t)row * 1024 + col] = acc[mi][ni][j];
        }
  }
}

// ---------------- fused FFN gate+up GEMM: Gb = silu(A Wg^T) * (A Wu^T), bf16 -------
__global__ __launch_bounds__(256) void ffn_kernel(
    const unsigned short* __restrict__ A, const unsigned short* __restrict__ Bg,
    const unsigned short* __restrict__ Bu, unsigned short* __restrict__ Gb) {
  __shared__ __align__(16) unsigned short As[128 * 64];
  __shared__ __align__(16) unsigned short Bgs[128 * 64];
  __shared__ __align__(16) unsigned short Bus[128 * 64];
  const int K = 1024;
  const int tid = threadIdx.x;
  const int wave = tid >> 6, lane = tid & 63;
  const int gx = gridDim.x;                 // 16
  const int nwg = gx * gridDim.y;           // 352
  const int dd = blockIdx.y * gx + blockIdx.x;
  const int qq = nwg >> 3;
  const int lgc = (dd & 7) * qq + (dd >> 3);
  const int bm = (lgc % gx) * 128;
  const int bn = (lgc / gx) * 128;
  const int wr = (wave >> 1) * 64, wc = (wave & 1) * 64;
  const int lr = lane & 15, lhi = lane >> 4;
  const unsigned short* Ab = A + (size_t)bm * K;
  const unsigned short* Bgb = Bg + (size_t)bn * K;
  const unsigned short* Bub = Bu + (size_t)bn * K;
  f32x4v accg[4][4] = {};
  f32x4v accu[4][4] = {};
  for (int it = 0; it < 16; ++it) {
    stage64(Ab, K, As, wave, lane, it << 6);
    stage64(Bgb, K, Bgs, wave, lane, it << 6);
    stage64(Bub, K, Bus, wave, lane, it << 6);
    __syncthreads();
#pragma unroll
    for (int kk = 0; kk < 2; ++kk) {
      const int sw = (((kk * 4 + lhi) ^ (lr & 7)) << 3);
      bf16x8 af[4], bg[4], bu[4];
#pragma unroll
      for (int mi = 0; mi < 4; ++mi) af[mi] = *(const bf16x8*)&As[(wr + mi * 16 + lr) * 64 + sw];
#pragma unroll
      for (int ni = 0; ni < 4; ++ni) bg[ni] = *(const bf16x8*)&Bgs[(wc + ni * 16 + lr) * 64 + sw];
#pragma unroll
      for (int ni = 0; ni < 4; ++ni) bu[ni] = *(const bf16x8*)&Bus[(wc + ni * 16 + lr) * 64 + sw];
#pragma unroll
      for (int mi = 0; mi < 4; ++mi)
#pragma unroll
        for (int ni = 0; ni < 4; ++ni) {
          accg[mi][ni] = __builtin_amdgcn_mfma_f32_16x16x32_bf16(af[mi], bg[ni], accg[mi][ni], 0, 0, 0);
          accu[mi][ni] = __builtin_amdgcn_mfma_f32_16x16x32_bf16(af[mi], bu[ni], accu[mi][ni], 0, 0, 0);
        }
    }
    __syncthreads();
  }
#pragma unroll
  for (int mi = 0; mi < 4; ++mi) {
#pragma unroll
    for (int ni = 0; ni < 4; ++ni) {
#pragma unroll
      for (int j = 0; j < 4; ++j) {
        int row = bm + wr + mi * 16 + lhi * 4 + j;
        int col = bn + wc + ni * 16 + lr;
        float g = accg[mi][ni][j];
        float sv = g * fast_sigmoid(g) * accu[mi][ni][j];
        Gb[(size_t)row * 2816 + col] = bf_us(sv);
      }
    }
  }
}

// ---------------- gate pre-activations (inline rmsnorm from f32 x) ----------------
__global__ __launch_bounds__(256) void gates_kernel(
    const float* __restrict__ x, const float* __restrict__ n1,
    const float* __restrict__ Wi, const float* __restrict__ bi,
    const float* __restrict__ Wf, const float* __restrict__ bfv,
    float* __restrict__ ipre, float* __restrict__ fpre) {
  int s = blockIdx.x;
  int head = threadIdx.x >> 6, lane = threadIdx.x & 63;
  const float* xr = x + (size_t)s * DMODEL;
  float xv[16];
  float ss = 0.f;
#pragma unroll
  for (int j = 0; j < 16; ++j) { xv[j] = xr[lane + j * 64]; ss += xv[j] * xv[j]; }
#pragma unroll
  for (int off = 32; off > 0; off >>= 1) ss += __shfl_xor(ss, off);
  float scale = rsqrtf(ss * (1.0f / DMODEL) + 1e-6f);
  const float* wi = Wi + head * DMODEL;
  const float* wf = Wf + head * DMODEL;
  float si = 0.f, sf = 0.f;
#pragma unroll
  for (int j = 0; j < 16; ++j) {
    int c = lane + j * 64;
    float xm = xv[j] * scale * n1[c];
    si += xm * wi[c];
    sf += xm * wf[c];
  }
#pragma unroll
  for (int off = 32; off > 0; off >>= 1) {
    si += __shfl_down(si, off);
    sf += __shfl_down(sf, off);
  }
  if (lane == 0) {
    ipre[head * S_LEN + s] = 15.0f * tanhf((si + bi[head]) * (1.0f / 15.0f));
    fpre[head * S_LEN + s] = 15.0f * tanhf((sf + bfv[head]) * (1.0f / 15.0f));
  }
}

// ---------------- per-head scan ----------------
__global__ __launch_bounds__(256) void scan_kernel(
    const float* __restrict__ ipre, const float* __restrict__ fpre,
    float* __restrict__ garr, float* __restrict__ Marr, float* __restrict__ earr) {
  const int h = threadIdx.x >> 6;
  const int lane = threadIdx.x & 63;
  const int base = h * S_LEN + lane * 32;
  float lf[32];
  float lsum = 0.f;
#pragma unroll
  for (int e = 0; e < 32; ++e) {
    float f = fpre[base + e];
    float v = fminf(f, 0.f) - log1pf(expf(-fabsf(f)));
    lf[e] = v;
    lsum += v;
  }
  float scan = lsum;
#pragma unroll
  for (int off = 1; off < 64; off <<= 1) {
    float t = __shfl_up(scan, off);
    if (lane >= off) scan += t;
  }
  float F0 = scan - lsum;
  float gv[32];
  float F = F0, lmax = -1e30f;
#pragma unroll
  for (int e = 0; e < 32; ++e) {
    F += lf[e];
    float g = ipre[base + e] - F;
    gv[e] = g;
    lmax = fmaxf(lmax, g);
    garr[base + e] = g;
  }
  float ms = lmax;
#pragma unroll
  for (int off = 1; off < 64; off <<= 1) {
    float t = __shfl_up(ms, off);
    if (lane >= off) ms = fmaxf(ms, t);
  }
  float em = __shfl_up(ms, 1);
  if (lane == 0) em = -1e30f;
  float run = em;
  F = F0;
#pragma unroll
  for (int e = 0; e < 32; ++e) {
    F += lf[e];
    run = fmaxf(run, gv[e]);
    Marr[base + e] = run;
    earr[base + e] = expf(-(F + run));
  }
}

// ---------------- mLSTM parallel, bf16 MFMA flash-style, s-split x2 ----------------
__global__ __launch_bounds__(256) void mlstm_mfma_kernel(
    const unsigned short* __restrict__ Q, const unsigned short* __restrict__ Kb,
    const unsigned short* __restrict__ vT, const float* __restrict__ garr,
    const float* __restrict__ Marr,
    float* __restrict__ hp0, float* __restrict__ hp1, float* __restrict__ npart) {
  const int h = blockIdx.y;
  const int T = blockIdx.x;
  const int sp = blockIdx.z;
  float* hpart = sp ? hp1 : hp0;
  const int tid = threadIdx.x;
  const int w = tid >> 6, l = tid & 63;
  const int lr = l & 15, lg = l >> 4;
  const int hbase = h * S_LEN;
  const int sr = tid >> 4;
  const int sc = tid & 15;

  __shared__ __align__(16) unsigned short Ks[64 * 128];
  __shared__ __align__(16) unsigned short Vs[256 * 64];
  __shared__ __align__(16) unsigned short Ps[64 * 64];

  bf16x8 qf[4];
  {
    const unsigned short* qrow = Q + (size_t)(T * 64 + w * 16 + lr) * 512 + h * 128 + lg * 8;
#pragma unroll
    for (int kt = 0; kt < 4; ++kt) {
      cvu c;
      c.u = *(const u16x8*)(qrow + kt * 32);
      qf[kt] = c.b;
    }
  }
  float Mt[4];
#pragma unroll
  for (int j = 0; j < 4; ++j) Mt[j] = Marr[hbase + T * 64 + w * 16 + lg * 4 + j];

  f32x4v pv[16] = {};
  float nacc[4] = {0.f, 0.f, 0.f, 0.f};
  const float rs = 0.08838834764831845f;  // 1/sqrt(128)

  for (int ch = sp; ch <= T; ch += 2) {
    const int s0 = ch * 64;
    __syncthreads();
#pragma unroll
    for (int i = 0; i < 4; ++i) {
      int r = i * 16 + sr;
      u16x8 u = *(const u16x8*)(Kb + (size_t)(s0 + r) * 512 + h * 128 + sc * 8);
      int byte = r * 256 + ((sc * 16) ^ ((r & 7) << 4));
      *(u16x8*)((char*)Ks + byte) = u;
    }
#pragma unroll
    for (int i = 0; i < 16; ++i) {
      int r = i * 16 + sr;
      u16x4 u = *(const u16x4*)(vT + (size_t)(h * 256 + r) * S_LEN + s0 + sc * 4);
      int byte = r * 128 + ((sc * 8) ^ ((r & 7) << 4));
      *(u16x4*)((char*)Vs + byte) = u;
    }
    __syncthreads();
    f32x4v sa[4] = {};
#pragma unroll
    for (int ni = 0; ni < 4; ++ni) {
#pragma unroll
      for (int kt = 0; kt < 4; ++kt) {
        int row = ni * 16 + lr;
        int byte = row * 256 + (((kt * 32 + lg * 8) * 2) ^ ((row & 7) << 4));
        bf16x8 kf = ld_bf8(Ks, byte);
        sa[ni] = __builtin_amdgcn_mfma_f32_16x16x32_bf16(qf[kt], kf, sa[ni], 0, 0, 0);
      }
    }
#pragma unroll
    for (int ni = 0; ni < 4; ++ni) {
      int sl = ni * 16 + lr;
      int sg = s0 + sl;
      float gv = garr[hbase + sg];
#pragma unroll
      for (int j = 0; j < 4; ++j) {
        int tloc = w * 16 + lg * 4 + j;
        int tg = T * 64 + tloc;
        float wgt = (sg <= tg) ? __expf(gv - Mt[j]) : 0.f;
        float val = sa[ni][j] * rs * wgt;
        nacc[j] += val;
        int byte = tloc * 128 + ((sl * 2) ^ ((tloc & 7) << 4));
        *(unsigned short*)((char*)Ps + byte) = bf_us(val);
      }
    }
#pragma unroll
    for (int kt2 = 0; kt2 < 2; ++kt2) {
      int tloc = w * 16 + lr;
      int sb = (kt2 * 32 + lg * 8) * 2;
      bf16x8 pa = ld_bf8(Ps, tloc * 128 + (sb ^ ((tloc & 7) << 4)));
#pragma unroll
      for (int nv = 0; nv < 16; ++nv) {
        int dv = nv * 16 + lr;
        bf16x8 vb = ld_bf8(Vs, dv * 128 + (sb ^ ((dv & 7) << 4)));
        pv[nv] = __builtin_amdgcn_mfma_f32_16x16x32_bf16(pa, vb, pv[nv], 0, 0, 0);
      }
    }
  }
#pragma unroll
  for (int j = 0; j < 4; ++j) {
#pragma unroll
    for (int off = 1; off < 16; off <<= 1) nacc[j] += __shfl_xor(nacc[j], off);
  }
#pragma unroll
  for (int j = 0; j < 4; ++j) {
    int tg = T * 64 + w * 16 + lg * 4 + j;
    if (lr == 0) npart[sp * 8192 + hbase + tg] = nacc[j];
    float* orow = hpart + (size_t)tg * DMODEL + h * 256;
#pragma unroll
    for (int nvt = 0; nvt < 16; ++nvt) orow[nvt * 16 + lr] = pv[nvt][j];
  }
}

// ---------------- combine + multihead LayerNorm * mhw * sigmoid(og) -> bf16 -------
__global__ __launch_bounds__(256) void mhln_gate_kernel(
    const float* __restrict__ hp0, const float* __restrict__ hp1,
    const float* __restrict__ npart, const float* __restrict__ earr,
    const float* __restrict__ mhw, const float* __restrict__ og,
    unsigned short* __restrict__ gact) {
  int s = blockIdx.x;
  int head = threadIdx.x >> 6, lane = threadIdx.x & 63;
  float n = npart[head * S_LEN + s] + npart[8192 + head * S_LEN + s];
  float nvv = fmaxf(fabsf(n), earr[head * S_LEN + s]);
  float inv = 1.0f / (nvv + 1e-6f);
  const size_t base = (size_t)s * DMODEL + head * 256;
  float v0 = (hp0[base + lane] + hp1[base + lane]) * inv;
  float v1 = (hp0[base + lane + 64] + hp1[base + lane + 64]) * inv;
  float v2 = (hp0[base + lane + 128] + hp1[base + lane + 128]) * inv;
  float v3 = (hp0[base + lane + 192] + hp1[base + lane + 192]) * inv;
  float sum = v0 + v1 + v2 + v3;
#pragma unroll
  for (int off = 32; off > 0; off >>= 1) sum += __shfl_xor(sum, off);
  float mu = sum * (1.0f / 256.0f);
  float d0 = v0 - mu, d1 = v1 - mu, d2 = v2 - mu, d3 = v3 - mu;
  float vs = d0 * d0 + d1 * d1 + d2 * d2 + d3 * d3;
#pragma unroll
  for (int off = 32; off > 0; off >>= 1) vs += __shfl_xor(vs, off);
  float rstd = rsqrtf(vs * (1.0f / 256.0f) + 1e-6f);
  float dn[4] = {d0, d1, d2, d3};
#pragma unroll
  for (int qy = 0; qy < 4; ++qy) {
    int c = head * 256 + qy * 64 + lane;
    float ov = og[(size_t)s * DMODEL + c];
    gact[(size_t)s * DMODEL + c] = bf_us(dn[qy] * rstd * mhw[c] * fast_sigmoid(ov));
  }
}

extern "C" void kernel_launch(void* const* d_in, const int* in_sizes, int n_in,
                              void* d_out, int out_size, void* d_ws, size_t ws_size,
                              hipStream_t stream) {
  (void)in_sizes; (void)n_in; (void)out_size; (void)ws_size;
  const int*   tok   = (const int*)d_in[0];
  const float* emb   = (const float*)d_in[1];
  const float* norm1 = (const float*)d_in[2];
  const float* Wq    = (const float*)d_in[3];
  const float* Wk    = (const float*)d_in[4];
  const float* Wv    = (const float*)d_in[5];
  const float* Wog   = (const float*)d_in[6];
  const float* Wi    = (const float*)d_in[7];
  const float* bi    = (const float*)d_in[8];
  const float* Wf    = (const float*)d_in[9];
  const float* bfp   = (const float*)d_in[10];
  const float* mhw   = (const float*)d_in[11];
  const float* Wout  = (const float*)d_in[12];
  const float* norm2 = (const float*)d_in[13];
  const float* Wg    = (const float*)d_in[14];
  const float* Wu    = (const float*)d_in[15];
  const float* Wd    = (const float*)d_in[16];
  const float* onw   = (const float*)d_in[17];
  const float* Wlm   = (const float*)d_in[18];

  char* wsb = (char*)d_ws;
  const size_t MB = 1ull << 20;
  float*          x    = (float*)wsb;                          // 8 MiB
  unsigned short* xmb  = (unsigned short*)(wsb + 8 * MB);      // 4 MiB
  float*          ipre = (float*)(wsb + 12 * MB);              // 5 x 32 KiB
  float*          fpre = ipre + 8192;
  float*          garr = fpre + 8192;
  float*          Marr = garr + 8192;
  float*          earr = Marr + 8192;
  float*          npart = earr + 8192;                         // 2 x 32 KiB
  unsigned short* W16  = (unsigned short*)(wsb + 13 * MB);     // 49 MiB -> ends 62
  const size_t OQ = 0, OKk = 524288, OV = 1048576, OOG = 2097152, OOUT = 3145728,
               OGt = 4194304, OU = 7077888, OD = 9961472;
  unsigned short* qb    = (unsigned short*)(wsb + 62 * MB);    // 2 MiB
  unsigned short* kb    = (unsigned short*)(wsb + 64 * MB);    // 2 MiB
  unsigned short* vTb   = (unsigned short*)(wsb + 66 * MB);    // 4 MiB
  float*          og    = (float*)(wsb + 70 * MB);             // 8 MiB
  float*          hp0   = (float*)(wsb + 78 * MB);             // 8 MiB
  float*          hp1   = (float*)(wsb + 86 * MB);             // 8 MiB
  unsigned short* gact  = (unsigned short*)(wsb + 94 * MB);    // 4 MiB
  unsigned short* Gb16  = (unsigned short*)(wsb + 98 * MB);    // 11 MiB -> ends 109
  unsigned short* wlm16 = (unsigned short*)(wsb + 110 * MB);   // 62.5 MiB -> ends 172.5

  embed_kernel<<<2048, 256, 0, stream>>>(tok, emb, x);
  wcvt8_kernel<<<28544, 256, 0, stream>>>(Wq, Wk, Wv, Wog, Wout, Wg, Wu, Wd, Wlm,
                                          W16, wlm16);

  for (int l = 0; l < 2; ++l) {
    const unsigned short* Wl = W16 + (size_t)l * WLAYER;
    const float* n1   = norm1 + (size_t)l * 1024;
    const float* wiv  = Wi   + (size_t)l * 4 * 1024;
    const float* bil  = bi   + (size_t)l * 4;
    const float* wfv  = Wf   + (size_t)l * 4 * 1024;
    const float* bfl  = bfp  + (size_t)l * 4;
    const float* mhwl = mhw  + (size_t)l * 1024;
    const float* n2   = norm2 + (size_t)l * 1024;

    rmsnorm_kernel<<<2048, 256, 0, stream>>>(x, n1, xmb);
    qkvo_kernel<<<dim3(16, 24), 256, 0, stream>>>(xmb, Wl + OQ, Wl + OKk, Wl + OV,
                                                  Wl + OOG, qb, kb, vTb, og);
    gates_kernel<<<2048, 256, 0, stream>>>(x, n1, wiv, bil, wfv, bfl, ipre, fpre);
    scan_kernel<<<1, 256, 0, stream>>>(ipre, fpre, garr, Marr, earr);
    mlstm_mfma_kernel<<<dim3(32, 4, 2), 256, 0, stream>>>(qb, kb, vTb, garr, Marr,
                                                          hp0, hp1, npart);
    mhln_gate_kernel<<<2048, 256, 0, stream>>>(hp0, hp1, npart, earr, mhwl, og, gact);
    gemm_bb_kernel<1><<<dim3(16, 8), 256, 0, stream>>>(gact, Wl + OOUT, x, x, 1024, 1024);
    rmsnorm_kernel<<<2048, 256, 0, stream>>>(x, n2, xmb);
    ffn_kernel<<<dim3(16, 22), 256, 0, stream>>>(xmb, Wl + OGt, Wl + OU, Gb16);
    gemm_bb_kernel<1><<<dim3(16, 8), 256, 0, stream>>>(Gb16, Wl + OD, x, x, 2816, 1024);
  }

  rmsnorm_kernel<<<2048, 256, 0, stream>>>(x, onw, xmb);
  lm256_kernel<<<dim3(8, 125), 512, 0, stream>>>(xmb, wlm16, (float*)d_out);
}

// Round 14
// 831.583 us; speedup vs baseline: 1.0599x; 1.0467x over previous
//
#include <hip/hip_runtime.h>
#include <hip/hip_bf16.h>
#include <math.h>

// xLSTM-Large forward: S=2048, D=1024, NH=4 (Dqk=128, Dv=256), UP=2752, L=2, V=32000.
// GEMMs: bf16 x bf16 MFMA, m97 single-buffered global_load_lds(16B) staging,
// XOR-swizzled LDS, bijective XCD block remap.
// This round: revert to round-11 state (best known, 826us); lm256 deepened to
// 4-buffer / 3-deep prefetch (128 KB; occupancy is pinned at 1 block/CU anyway,
// so spend LDS on latency cover): vmcnt(8) steady / 4 / 0 tail.

#define S_LEN 2048
#define DMODEL 1024
#define WLAYER 12845056  // elements per layer in W16

typedef __attribute__((ext_vector_type(8))) __bf16 bf16x8;
typedef __attribute__((ext_vector_type(8))) unsigned short u16x8;
typedef __attribute__((ext_vector_type(4))) unsigned short u16x4;
typedef __attribute__((ext_vector_type(4))) float f32x4v;

union cvu { u16x8 u; bf16x8 b; };

__device__ __forceinline__ unsigned short bf_us(float f) {
  union { __bf16 b; unsigned short u; } c;
  c.b = (__bf16)f;   // RNE, native v_cvt on gfx950
  return c.u;
}
__device__ __forceinline__ float us_f(unsigned short u) {
  union { __bf16 b; unsigned short u; } c;
  c.u = u;
  return (float)c.b;
}
__device__ __forceinline__ bf16x8 ld_bf8(const unsigned short* p, int byte_off) {
  cvu c;
  c.u = *(const u16x8*)((const char*)p + byte_off);
  return c.b;
}
__device__ __forceinline__ float fast_sigmoid(float v) {
  return 1.0f / (1.0f + __expf(-v));
}
__device__ __forceinline__ float fast_softcap30(float v) {
  float e = __expf(-fabsf(v) * (1.0f / 15.0f));  // e^{-2|v|/30}
  float t = (1.0f - e) / (1.0f + e);             // tanh(|v|/30)
  return copysignf(30.0f * t, v);
}

#define AS_G __attribute__((address_space(1)))
#define AS_L __attribute__((address_space(3)))

// Stage a 128x64 bf16 tile (16 KB) from global (row stride K elems) into LDS.
// LDS dest linear (DMA requirement); global SOURCE column-group pre-swizzled
// (cg ^= row&7) so the matching XOR on the read side is conflict-free (rule #21).
__device__ __forceinline__ void stage64(const unsigned short* gbase, int K,
                                        unsigned short* lds, int wave, int lane, int k0) {
#pragma unroll
  for (int j = 0; j < 4; ++j) {
    const int rbase = (j * 4 + wave) * 8;
    const int r = rbase + (lane >> 3);
    const int cg = (lane & 7) ^ (r & 7);   // pre-swizzled source column group
    const unsigned short* src = gbase + (size_t)r * K + k0 + cg * 8;
    __builtin_amdgcn_global_load_lds((const AS_G void*)src,
                                     (AS_L void*)(lds + rbase * 64), 16, 0, 0);
  }
}

// ---------------- embed ----------------
__global__ __launch_bounds__(256) void embed_kernel(
    const int* __restrict__ tok, const float* __restrict__ emb, float* __restrict__ x) {
  int s = blockIdx.x;
  int t = tok[s];
  const float4 v = *(const float4*)(emb + (size_t)t * DMODEL + threadIdx.x * 4);
  *(float4*)(x + (size_t)s * DMODEL + threadIdx.x * 4) = v;
}

// ---------------- rmsnorm (row = 1024): writes bf16 ----------------
__global__ __launch_bounds__(256) void rmsnorm_kernel(
    const float* __restrict__ x, const float* __restrict__ w,
    unsigned short* __restrict__ outb) {
  int s = blockIdx.x, tid = threadIdx.x;
  const float* xr = x + (size_t)s * DMODEL;
  float4 v = *(const float4*)(xr + tid * 4);
  float ss = v.x * v.x + v.y * v.y + v.z * v.z + v.w * v.w;
#pragma unroll
  for (int off = 32; off > 0; off >>= 1) ss += __shfl_down(ss, off);
  __shared__ float red[4];
  if ((tid & 63) == 0) red[tid >> 6] = ss;
  __syncthreads();
  float tot = red[0] + red[1] + red[2] + red[3];
  float scale = rsqrtf(tot * (1.0f / DMODEL) + 1e-6f);
  float4 wv = *(const float4*)(w + tid * 4);
  u16x4 ub;
  ub[0] = bf_us(v.x * scale * wv.x);
  ub[1] = bf_us(v.y * scale * wv.y);
  ub[2] = bf_us(v.z * scale * wv.z);
  ub[3] = bf_us(v.w * scale * wv.w);
  *(u16x4*)(outb + (size_t)s * DMODEL + tid * 4) = ub;
}

// ---------------- weight convert f32 -> bf16: both layers + LM head --------------
__global__ __launch_bounds__(256) void wcvt8_kernel(
    const float* __restrict__ Wq, const float* __restrict__ Wk,
    const float* __restrict__ Wv, const float* __restrict__ Wog,
    const float* __restrict__ Wout, const float* __restrict__ Wg,
    const float* __restrict__ Wu, const float* __restrict__ Wd,
    const float* __restrict__ Wlm,
    unsigned short* __restrict__ W, unsigned short* __restrict__ Wlm16) {
  const size_t de = ((size_t)blockIdx.x * 256 + threadIdx.x) * 8;
  if (de >= 2ull * WLAYER) {  // LM head region
    size_t i = de - 2ull * WLAYER;
    float4 a0 = *(const float4*)(Wlm + i);
    float4 a1 = *(const float4*)(Wlm + i + 4);
    u16x8 o;
    o[0] = bf_us(a0.x); o[1] = bf_us(a0.y); o[2] = bf_us(a0.z); o[3] = bf_us(a0.w);
    o[4] = bf_us(a1.x); o[5] = bf_us(a1.y); o[6] = bf_us(a1.z); o[7] = bf_us(a1.w);
    *(u16x8*)(Wlm16 + i) = o;
    return;
  }
  int e = (int)de, l = 0;
  if (e >= WLAYER) { l = 1; e -= WLAYER; }
  const float* src = nullptr;
  size_t idx = 0;
  if (e < 524288)       { src = Wq  + (size_t)l * 524288;  idx = e; }
  else if (e < 1048576) { src = Wk  + (size_t)l * 524288;  idx = e - 524288; }
  else if (e < 2097152) { src = Wv  + (size_t)l * 1048576; idx = e - 1048576; }
  else if (e < 3145728) { src = Wog + (size_t)l * 1048576; idx = e - 2097152; }
  else if (e < 4194304) { src = Wout + (size_t)l * 1048576; idx = e - 3145728; }
  else if (e < 7077888) {
    int t = e - 4194304, row = t >> 10;
    if (row < 2752) { src = Wg + (size_t)l * 2818048; idx = t; }
  } else if (e < 9961472) {
    int t = e - 7077888, row = t >> 10;
    if (row < 2752) { src = Wu + (size_t)l * 2818048; idx = t; }
  } else {
    int t = e - 9961472, row = t / 2816, col = t - row * 2816;
    if (col < 2752) { src = Wd + (size_t)l * 2818048; idx = row * 2752 + col; }
  }
  u16x8 o;
  if (src) {
    float4 a0 = *(const float4*)(src + idx);
    float4 a1 = *(const float4*)(src + idx + 4);
    o[0] = bf_us(a0.x); o[1] = bf_us(a0.y); o[2] = bf_us(a0.z); o[3] = bf_us(a0.w);
    o[4] = bf_us(a1.x); o[5] = bf_us(a1.y); o[6] = bf_us(a1.z); o[7] = bf_us(a1.w);
  } else {
#pragma unroll
    for (int k = 0; k < 8; ++k) o[k] = 0;
  }
  *(u16x8*)(W + de) = o;
}

// ---------------- GEMM core: 128x128 tile (layer GEMMs) ----------------
// EPI: 0 f32 store | 1 f32 acc+X residual
template <int EPI>
__global__ __launch_bounds__(256) void gemm_bb_kernel(
    const unsigned short* __restrict__ A, const unsigned short* __restrict__ B,
    const void* Xv, void* Cv, int K, int ldc) {
  __shared__ __align__(16) unsigned short As[128 * 64];
  __shared__ __align__(16) unsigned short Bs[128 * 64];
  const int tid = threadIdx.x;
  const int wave = tid >> 6, lane = tid & 63;
  const int gx = gridDim.x;
  const int nwg = gx * gridDim.y;
  const int d = blockIdx.y * gx + blockIdx.x;
  const int q = nwg >> 3;
  const int lgc = (d & 7) * q + (d >> 3);
  const int bm = (lgc % gx) * 128, bn = (lgc / gx) * 128;
  const int wr = (wave >> 1) * 64, wc = (wave & 1) * 64;
  const int lr = lane & 15, lhi = lane >> 4;
  const unsigned short* Ab = A + (size_t)bm * K;
  const unsigned short* Bb = B + (size_t)bn * K;
  f32x4v acc[4][4] = {};

  const int NK = K >> 6;
  for (int it = 0; it < NK; ++it) {
    stage64(Ab, K, As, wave, lane, it << 6);
    stage64(Bb, K, Bs, wave, lane, it << 6);
    __syncthreads();
#pragma unroll
    for (int kk = 0; kk < 2; ++kk) {
      const int sw = (((kk * 4 + lhi) ^ (lr & 7)) << 3);
      bf16x8 af[4], bfr[4];
#pragma unroll
      for (int mi = 0; mi < 4; ++mi) af[mi] = *(const bf16x8*)&As[(wr + mi * 16 + lr) * 64 + sw];
#pragma unroll
      for (int ni = 0; ni < 4; ++ni) bfr[ni] = *(const bf16x8*)&Bs[(wc + ni * 16 + lr) * 64 + sw];
#pragma unroll
      for (int mi = 0; mi < 4; ++mi)
#pragma unroll
        for (int ni = 0; ni < 4; ++ni)
          acc[mi][ni] = __builtin_amdgcn_mfma_f32_16x16x32_bf16(af[mi], bfr[ni], acc[mi][ni], 0, 0, 0);
    }
    __syncthreads();
  }
#pragma unroll
  for (int mi = 0; mi < 4; ++mi) {
#pragma unroll
    for (int ni = 0; ni < 4; ++ni) {
#pragma unroll
      for (int j = 0; j < 4; ++j) {
        int row = bm + wr + mi * 16 + lhi * 4 + j;   // C/D layout (m89)
        int col = bn + wc + ni * 16 + lr;
        float v = acc[mi][ni][j];
        if (EPI == 0)
          ((float*)Cv)[(size_t)row * ldc + col] = v;
        if (EPI == 1)
          ((float*)Cv)[(size_t)row * ldc + col] = v + ((const float*)Xv)[(size_t)row * ldc + col];
      }
    }
  }
}

// ---------------- LM head GEMM: 256x256 tile, 8 waves, BK=32, 4-buffer pipeline ---
// Per K-tile t: vmcnt(N) -> s_barrier -> issue stage(t+3) -> 12 ds_read + 32 MFMA.
// Prologue stages t=0,1,2 (12 loads). Steady state: outstanding at wait =
// {t,t+1,t+2} = 12 loads; vmcnt(8) drains exactly tile t. Tail: vmcnt(4) at NT-2,
// vmcnt(0) at NT-1. stage(t+3) writes buf (t-1)&3 whose readers passed the barrier.
// 3-deep prefetch (~3 compute phases of latency cover). 128 KB LDS, 1 block/CU.
__global__ __launch_bounds__(512, 2) void lm256_kernel(
    const unsigned short* __restrict__ A, const unsigned short* __restrict__ B,
    float* __restrict__ C) {
  __shared__ __align__(16) unsigned short SH[4 * 16384];  // 4 x (A 256x32 | B 256x32)
  const int K = 1024, N = 32000, NT = 32;
  const int tid = threadIdx.x;
  const int wave = tid >> 6, lane = tid & 63;
  const int lr = lane & 15, lg = lane >> 4;
  const int wm = wave >> 2, wn = wave & 3;     // 2M x 4N waves, 128x64 each
  const int d = blockIdx.y * 8 + blockIdx.x;
  const int lgc = (d & 7) * 125 + (d >> 3);
  const int bm = (lgc & 7) * 256;
  const int bn = (lgc >> 3) * 256;
  const unsigned short* Ab = A + (size_t)bm * K;
  const unsigned short* Bb = B + (size_t)bn * K;

  // stage one 256x32 matrix tile (16 KB) into linear LDS: 2 issues of 8 KB
  auto stageM = [&](const unsigned short* gbase, unsigned short* lds, int k0) {
#pragma unroll
    for (int j = 0; j < 2; ++j) {
      const int r = j * 128 + wave * 16 + (lane >> 2);
      const int cg = (lane & 3) ^ ((r >> 1) & 3);   // pre-swizzled source column group
      const unsigned short* src = gbase + (size_t)r * K + k0 + cg * 8;
      __builtin_amdgcn_global_load_lds((const AS_G void*)src,
                                       (AS_L void*)(lds + (j * 128 + wave * 16) * 32), 16, 0, 0);
    }
  };
  auto stageT = [&](int tau) {
    unsigned short* base = SH + (tau & 3) * 16384;
    stageM(Ab, base, tau * 32);
    stageM(Bb, base + 8192, tau * 32);
  };

  f32x4v acc[8][4] = {};
  stageT(0);
  stageT(1);
  stageT(2);
  for (int t = 0; t < NT; ++t) {
    if (t < NT - 2)      asm volatile("s_waitcnt vmcnt(8)" ::: "memory");
    else if (t == NT - 2) asm volatile("s_waitcnt vmcnt(4)" ::: "memory");
    else                 asm volatile("s_waitcnt vmcnt(0)" ::: "memory");
    asm volatile("s_barrier" ::: "memory");
    if (t + 3 < NT) stageT(t + 3);
    const unsigned short* Al = SH + (t & 3) * 16384;
    const unsigned short* Bl = Al + 8192;
    bf16x8 bfr[4];
#pragma unroll
    for (int ni = 0; ni < 4; ++ni) {
      int row = wn * 64 + ni * 16 + lr;
      bfr[ni] = *(const bf16x8*)&Bl[row * 32 + ((lg ^ ((row >> 1) & 3)) << 3)];
    }
#pragma unroll
    for (int mi = 0; mi < 8; ++mi) {
      int row = wm * 128 + mi * 16 + lr;
      bf16x8 af = *(const bf16x8*)&Al[row * 32 + ((lg ^ ((row >> 1) & 3)) << 3)];
      __builtin_amdgcn_s_setprio(1);
#pragma unroll
      for (int ni = 0; ni < 4; ++ni)
        acc[mi][ni] = __builtin_amdgcn_mfma_f32_16x16x32_bf16(af, bfr[ni], acc[mi][ni], 0, 0, 0);
      __builtin_amdgcn_s_setprio(0);
    }
  }
#pragma unroll
  for (int mi = 0; mi < 8; ++mi)
#pragma unroll
    for (int ni = 0; ni < 4; ++ni)
#pragma unroll
      for (int jj = 0; jj < 4; ++jj) {
        int row = bm + wm * 128 + mi * 16 + lg * 4 + jj;
        int col = bn + wn * 64 + ni * 16 + lr;
        C[(size_t)row * N + col] = fast_softcap30(acc[mi][ni][jj]);
      }
}

// ---------------- fused QKV+OG GEMM ----------------
__global__ __launch_bounds__(256) void qkvo_kernel(
    const unsigned short* __restrict__ A, const unsigned short* __restrict__ Wq16,
    const unsigned short* __restrict__ Wk16, const unsigned short* __restrict__ Wv16,
    const unsigned short* __restrict__ Wog16,
    unsigned short* __restrict__ qb, unsigned short* __restrict__ kb,
    unsigned short* __restrict__ vTb, float* __restrict__ og) {
  __shared__ __align__(16) unsigned short SH[2 * 128 * 64];
  unsigned short* Asb = SH;
  unsigned short* Bsb = SH + 128 * 64;
  const int tid = threadIdx.x;
  const int wave = tid >> 6, lane = tid & 63;
  const int gx = gridDim.x;                 // 16 (M)
  const int nwg = gx * gridDim.y;           // 384
  const int dd = blockIdx.y * gx + blockIdx.x;
  const int qq = nwg >> 3;
  const int lgc = (dd & 7) * qq + (dd >> 3);
  const int bm = (lgc % gx) * 128;
  const int by = lgc / gx;
  const unsigned short* B;
  int bnl, mode;
  if (by < 4)       { B = Wq16;  bnl = by * 128;        mode = 0; }
  else if (by < 8)  { B = Wk16;  bnl = (by - 4) * 128;  mode = 1; }
  else if (by < 16) { B = Wv16;  bnl = (by - 8) * 128;  mode = 2; }
  else              { B = Wog16; bnl = (by - 16) * 128; mode = 3; }
  const int K = 1024;
  const int wr = (wave >> 1) * 64, wc = (wave & 1) * 64;
  const int lr = lane & 15, lhi = lane >> 4;
  const unsigned short* Ab = A + (size_t)bm * K;
  const unsigned short* Bb = B + (size_t)bnl * K;
  f32x4v acc[4][4] = {};

  for (int it = 0; it < 16; ++it) {
    stage64(Ab, K, Asb, wave, lane, it << 6);
    stage64(Bb, K, Bsb, wave, lane, it << 6);
    __syncthreads();
#pragma unroll
    for (int kk = 0; kk < 2; ++kk) {
      const int sw = (((kk * 4 + lhi) ^ (lr & 7)) << 3);
      bf16x8 af[4], bfr[4];
#pragma unroll
      for (int mi = 0; mi < 4; ++mi) af[mi] = *(const bf16x8*)&Asb[(wr + mi * 16 + lr) * 64 + sw];
#pragma unroll
      for (int ni = 0; ni < 4; ++ni) bfr[ni] = *(const bf16x8*)&Bsb[(wc + ni * 16 + lr) * 64 + sw];
#pragma unroll
      for (int mi = 0; mi < 4; ++mi)
#pragma unroll
        for (int ni = 0; ni < 4; ++ni)
          acc[mi][ni] = __builtin_amdgcn_mfma_f32_16x16x32_bf16(af[mi], bfr[ni], acc[mi][ni], 0, 0, 0);
    }
    __syncthreads();
  }
  if (mode == 2) {
#pragma unroll
    for (int mi = 0; mi < 4; ++mi)
#pragma unroll
      for (int ni = 0; ni < 4; ++ni)
#pragma unroll
        for (int j = 0; j < 4; ++j) {
          int row = wr + mi * 16 + lhi * 4 + j;
          int col = wc + ni * 16 + lr;
          int byte = col * 256 + ((((row >> 3) ^ (col & 7)) << 4)) + (row & 7) * 2;
          *(unsigned short*)((char*)SH + byte) = bf_us(acc[mi][ni][j]);
        }
    __syncthreads();
#pragma unroll
    for (int i = 0; i < 8; ++i) {
      int c = i * 16 + (tid >> 4);
      int rg = tid & 15;
      u16x8 u = *(const u16x8*)((const char*)SH + c * 256 + ((rg ^ (c & 7)) << 4));
      *(u16x8*)(vTb + (size_t)(bnl + c) * S_LEN + bm + rg * 8) = u;
    }
  } else {
#pragma unroll
    for (int mi = 0; mi < 4; ++mi)
#pragma unroll
      for (int ni = 0; ni < 4; ++ni)
#pragma unroll
        for (int j = 0; j < 4; ++j) {
          int row = bm + wr + mi * 16 + lhi * 4 + j;
          int col = bnl + wc + ni * 16 + lr;
          if (mode == 0)      qb[(size_t)row * 512 + col] = bf_us(acc[mi][ni][j]);
          else if (mode == 1) kb[(size_t)row * 512 + col] = bf_us(acc[mi][ni][j]);
          else                og[(size_t)row * 1024 + col] = acc[mi][ni][j];
        }
  }
}

// ---------------- fused FFN gate+up GEMM: Gb = silu(A Wg^T) * (A Wu^T), bf16 -------
__global__ __launch_bounds__(256) void ffn_kernel(
    const unsigned short* __restrict__ A, const unsigned short* __restrict__ Bg,
    const unsigned short* __restrict__ Bu, unsigned short* __restrict__ Gb) {
  __shared__ __align__(16) unsigned short As[128 * 64];
  __shared__ __align__(16) unsigned short Bgs[128 * 64];
  __shared__ __align__(16) unsigned short Bus[128 * 64];
  const int K = 1024;
  const int tid = threadIdx.x;
  const int wave = tid >> 6, lane = tid & 63;
  const int gx = gridDim.x;                 // 16
  const int nwg = gx * gridDim.y;           // 352
  const int dd = blockIdx.y * gx + blockIdx.x;
  const int qq = nwg >> 3;
  const int lgc = (dd & 7) * qq + (dd >> 3);
  const int bm = (lgc % gx) * 128;
  const int bn = (lgc / gx) * 128;
  const int wr = (wave >> 1) * 64, wc = (wave & 1) * 64;
  const int lr = lane & 15, lhi = lane >> 4;
  const unsigned short* Ab = A + (size_t)bm * K;
  const unsigned short* Bgb = Bg + (size_t)bn * K;
  const unsigned short* Bub = Bu + (size_t)bn * K;
  f32x4v accg[4][4] = {};
  f32x4v accu[4][4] = {};
  for (int it = 0; it < 16; ++it) {
    stage64(Ab, K, As, wave, lane, it << 6);
    stage64(Bgb, K, Bgs, wave, lane, it << 6);
    stage64(Bub, K, Bus, wave, lane, it << 6);
    __syncthreads();
#pragma unroll
    for (int kk = 0; kk < 2; ++kk) {
      const int sw = (((kk * 4 + lhi) ^ (lr & 7)) << 3);
      bf16x8 af[4], bg[4], bu[4];
#pragma unroll
      for (int mi = 0; mi < 4; ++mi) af[mi] = *(const bf16x8*)&As[(wr + mi * 16 + lr) * 64 + sw];
#pragma unroll
      for (int ni = 0; ni < 4; ++ni) bg[ni] = *(const bf16x8*)&Bgs[(wc + ni * 16 + lr) * 64 + sw];
#pragma unroll
      for (int ni = 0; ni < 4; ++ni) bu[ni] = *(const bf16x8*)&Bus[(wc + ni * 16 + lr) * 64 + sw];
#pragma unroll
      for (int mi = 0; mi < 4; ++mi)
#pragma unroll
        for (int ni = 0; ni < 4; ++ni) {
          accg[mi][ni] = __builtin_amdgcn_mfma_f32_16x16x32_bf16(af[mi], bg[ni], accg[mi][ni], 0, 0, 0);
          accu[mi][ni] = __builtin_amdgcn_mfma_f32_16x16x32_bf16(af[mi], bu[ni], accu[mi][ni], 0, 0, 0);
        }
    }
    __syncthreads();
  }
#pragma unroll
  for (int mi = 0; mi < 4; ++mi) {
#pragma unroll
    for (int ni = 0; ni < 4; ++ni) {
#pragma unroll
      for (int j = 0; j < 4; ++j) {
        int row = bm + wr + mi * 16 + lhi * 4 + j;
        int col = bn + wc + ni * 16 + lr;
        float g = accg[mi][ni][j];
        float sv = g * fast_sigmoid(g) * accu[mi][ni][j];
        Gb[(size_t)row * 2816 + col] = bf_us(sv);
      }
    }
  }
}

// ---------------- gate pre-activations (inline rmsnorm from f32 x) ----------------
__global__ __launch_bounds__(256) void gates_kernel(
    const float* __restrict__ x, const float* __restrict__ n1,
    const float* __restrict__ Wi, const float* __restrict__ bi,
    const float* __restrict__ Wf, const float* __restrict__ bfv,
    float* __restrict__ ipre, float* __restrict__ fpre) {
  int s = blockIdx.x;
  int head = threadIdx.x >> 6, lane = threadIdx.x & 63;
  const float* xr = x + (size_t)s * DMODEL;
  float xv[16];
  float ss = 0.f;
#pragma unroll
  for (int j = 0; j < 16; ++j) { xv[j] = xr[lane + j * 64]; ss += xv[j] * xv[j]; }
#pragma unroll
  for (int off = 32; off > 0; off >>= 1) ss += __shfl_xor(ss, off);
  float scale = rsqrtf(ss * (1.0f / DMODEL) + 1e-6f);
  const float* wi = Wi + head * DMODEL;
  const float* wf = Wf + head * DMODEL;
  float si = 0.f, sf = 0.f;
#pragma unroll
  for (int j = 0; j < 16; ++j) {
    int c = lane + j * 64;
    float xm = xv[j] * scale * n1[c];
    si += xm * wi[c];
    sf += xm * wf[c];
  }
#pragma unroll
  for (int off = 32; off > 0; off >>= 1) {
    si += __shfl_down(si, off);
    sf += __shfl_down(sf, off);
  }
  if (lane == 0) {
    ipre[head * S_LEN + s] = 15.0f * tanhf((si + bi[head]) * (1.0f / 15.0f));
    fpre[head * S_LEN + s] = 15.0f * tanhf((sf + bfv[head]) * (1.0f / 15.0f));
  }
}

// ---------------- per-head scan ----------------
__global__ __launch_bounds__(256) void scan_kernel(
    const float* __restrict__ ipre, const float* __restrict__ fpre,
    float* __restrict__ garr, float* __restrict__ Marr, float* __restrict__ earr) {
  const int h = threadIdx.x >> 6;
  const int lane = threadIdx.x & 63;
  const int base = h * S_LEN + lane * 32;
  float lf[32];
  float lsum = 0.f;
#pragma unroll
  for (int e = 0; e < 32; ++e) {
    float f = fpre[base + e];
    float v = fminf(f, 0.f) - log1pf(expf(-fabsf(f)));
    lf[e] = v;
    lsum += v;
  }
  float scan = lsum;
#pragma unroll
  for (int off = 1; off < 64; off <<= 1) {
    float t = __shfl_up(scan, off);
    if (lane >= off) scan += t;
  }
  float F0 = scan - lsum;
  float gv[32];
  float F = F0, lmax = -1e30f;
#pragma unroll
  for (int e = 0; e < 32; ++e) {
    F += lf[e];
    float g = ipre[base + e] - F;
    gv[e] = g;
    lmax = fmaxf(lmax, g);
    garr[base + e] = g;
  }
  float ms = lmax;
#pragma unroll
  for (int off = 1; off < 64; off <<= 1) {
    float t = __shfl_up(ms, off);
    if (lane >= off) ms = fmaxf(ms, t);
  }
  float em = __shfl_up(ms, 1);
  if (lane == 0) em = -1e30f;
  float run = em;
  F = F0;
#pragma unroll
  for (int e = 0; e < 32; ++e) {
    F += lf[e];
    run = fmaxf(run, gv[e]);
    Marr[base + e] = run;
    earr[base + e] = expf(-(F + run));
  }
}

// ---------------- mLSTM parallel, bf16 MFMA flash-style, s-split x2 ----------------
__global__ __launch_bounds__(256) void mlstm_mfma_kernel(
    const unsigned short* __restrict__ Q, const unsigned short* __restrict__ Kb,
    const unsigned short* __restrict__ vT, const float* __restrict__ garr,
    const float* __restrict__ Marr,
    float* __restrict__ hp0, float* __restrict__ hp1, float* __restrict__ npart) {
  const int h = blockIdx.y;
  const int T = blockIdx.x;
  const int sp = blockIdx.z;
  float* hpart = sp ? hp1 : hp0;
  const int tid = threadIdx.x;
  const int w = tid >> 6, l = tid & 63;
  const int lr = l & 15, lg = l >> 4;
  const int hbase = h * S_LEN;
  const int sr = tid >> 4;
  const int sc = tid & 15;

  __shared__ __align__(16) unsigned short Ks[64 * 128];
  __shared__ __align__(16) unsigned short Vs[256 * 64];
  __shared__ __align__(16) unsigned short Ps[64 * 64];

  bf16x8 qf[4];
  {
    const unsigned short* qrow = Q + (size_t)(T * 64 + w * 16 + lr) * 512 + h * 128 + lg * 8;
#pragma unroll
    for (int kt = 0; kt < 4; ++kt) {
      cvu c;
      c.u = *(const u16x8*)(qrow + kt * 32);
      qf[kt] = c.b;
    }
  }
  float Mt[4];
#pragma unroll
  for (int j = 0; j < 4; ++j) Mt[j] = Marr[hbase + T * 64 + w * 16 + lg * 4 + j];

  f32x4v pv[16] = {};
  float nacc[4] = {0.f, 0.f, 0.f, 0.f};
  const float rs = 0.08838834764831845f;  // 1/sqrt(128)

  for (int ch = sp; ch <= T; ch += 2) {
    const int s0 = ch * 64;
    __syncthreads();
#pragma unroll
    for (int i = 0; i < 4; ++i) {
      int r = i * 16 + sr;
      u16x8 u = *(const u16x8*)(Kb + (size_t)(s0 + r) * 512 + h * 128 + sc * 8);
      int byte = r * 256 + ((sc * 16) ^ ((r & 7) << 4));
      *(u16x8*)((char*)Ks + byte) = u;
    }
#pragma unroll
    for (int i = 0; i < 16; ++i) {
      int r = i * 16 + sr;
      u16x4 u = *(const u16x4*)(vT + (size_t)(h * 256 + r) * S_LEN + s0 + sc * 4);
      int byte = r * 128 + ((sc * 8) ^ ((r & 7) << 4));
      *(u16x4*)((char*)Vs + byte) = u;
    }
    __syncthreads();
    f32x4v sa[4] = {};
#pragma unroll
    for (int ni = 0; ni < 4; ++ni) {
#pragma unroll
      for (int kt = 0; kt < 4; ++kt) {
        int row = ni * 16 + lr;
        int byte = row * 256 + (((kt * 32 + lg * 8) * 2) ^ ((row & 7) << 4));
        bf16x8 kf = ld_bf8(Ks, byte);
        sa[ni] = __builtin_amdgcn_mfma_f32_16x16x32_bf16(qf[kt], kf, sa[ni], 0, 0, 0);
      }
    }
#pragma unroll
    for (int ni = 0; ni < 4; ++ni) {
      int sl = ni * 16 + lr;
      int sg = s0 + sl;
      float gv = garr[hbase + sg];
#pragma unroll
      for (int j = 0; j < 4; ++j) {
        int tloc = w * 16 + lg * 4 + j;
        int tg = T * 64 + tloc;
        float wgt = (sg <= tg) ? __expf(gv - Mt[j]) : 0.f;
        float val = sa[ni][j] * rs * wgt;
        nacc[j] += val;
        int byte = tloc * 128 + ((sl * 2) ^ ((tloc & 7) << 4));
        *(unsigned short*)((char*)Ps + byte) = bf_us(val);
      }
    }
#pragma unroll
    for (int kt2 = 0; kt2 < 2; ++kt2) {
      int tloc = w * 16 + lr;
      int sb = (kt2 * 32 + lg * 8) * 2;
      bf16x8 pa = ld_bf8(Ps, tloc * 128 + (sb ^ ((tloc & 7) << 4)));
#pragma unroll
      for (int nv = 0; nv < 16; ++nv) {
        int dv = nv * 16 + lr;
        bf16x8 vb = ld_bf8(Vs, dv * 128 + (sb ^ ((dv & 7) << 4)));
        pv[nv] = __builtin_amdgcn_mfma_f32_16x16x32_bf16(pa, vb, pv[nv], 0, 0, 0);
      }
    }
  }
#pragma unroll
  for (int j = 0; j < 4; ++j) {
#pragma unroll
    for (int off = 1; off < 16; off <<= 1) nacc[j] += __shfl_xor(nacc[j], off);
  }
#pragma unroll
  for (int j = 0; j < 4; ++j) {
    int tg = T * 64 + w * 16 + lg * 4 + j;
    if (lr == 0) npart[sp * 8192 + hbase + tg] = nacc[j];
    float* orow = hpart + (size_t)tg * DMODEL + h * 256;
#pragma unroll
    for (int nvt = 0; nvt < 16; ++nvt) orow[nvt * 16 + lr] = pv[nvt][j];
  }
}

// ---------------- combine + multihead LayerNorm * mhw * sigmoid(og) -> bf16 -------
__global__ __launch_bounds__(256) void mhln_gate_kernel(
    const float* __restrict__ hp0, const float* __restrict__ hp1,
    const float* __restrict__ npart, const float* __restrict__ earr,
    const float* __restrict__ mhw, const float* __restrict__ og,
    unsigned short* __restrict__ gact) {
  int s = blockIdx.x;
  int head = threadIdx.x >> 6, lane = threadIdx.x & 63;
  float n = npart[head * S_LEN + s] + npart[8192 + head * S_LEN + s];
  float nvv = fmaxf(fabsf(n), earr[head * S_LEN + s]);
  float inv = 1.0f / (nvv + 1e-6f);
  const size_t base = (size_t)s * DMODEL + head * 256;
  float v0 = (hp0[base + lane] + hp1[base + lane]) * inv;
  float v1 = (hp0[base + lane + 64] + hp1[base + lane + 64]) * inv;
  float v2 = (hp0[base + lane + 128] + hp1[base + lane + 128]) * inv;
  float v3 = (hp0[base + lane + 192] + hp1[base + lane + 192]) * inv;
  float sum = v0 + v1 + v2 + v3;
#pragma unroll
  for (int off = 32; off > 0; off >>= 1) sum += __shfl_xor(sum, off);
  float mu = sum * (1.0f / 256.0f);
  float d0 = v0 - mu, d1 = v1 - mu, d2 = v2 - mu, d3 = v3 - mu;
  float vs = d0 * d0 + d1 * d1 + d2 * d2 + d3 * d3;
#pragma unroll
  for (int off = 32; off > 0; off >>= 1) vs += __shfl_xor(vs, off);
  float rstd = rsqrtf(vs * (1.0f / 256.0f) + 1e-6f);
  float dn[4] = {d0, d1, d2, d3};
#pragma unroll
  for (int qy = 0; qy < 4; ++qy) {
    int c = head * 256 + qy * 64 + lane;
    float ov = og[(size_t)s * DMODEL + c];
    gact[(size_t)s * DMODEL + c] = bf_us(dn[qy] * rstd * mhw[c] * fast_sigmoid(ov));
  }
}

extern "C" void kernel_launch(void* const* d_in, const int* in_sizes, int n_in,
                              void* d_out, int out_size, void* d_ws, size_t ws_size,
                              hipStream_t stream) {
  (void)in_sizes; (void)n_in; (void)out_size; (void)ws_size;
  const int*   tok   = (const int*)d_in[0];
  const float* emb   = (const float*)d_in[1];
  const float* norm1 = (const float*)d_in[2];
  const float* Wq    = (const float*)d_in[3];
  const float* Wk    = (const float*)d_in[4];
  const float* Wv    = (const float*)d_in[5];
  const float* Wog   = (const float*)d_in[6];
  const float* Wi    = (const float*)d_in[7];
  const float* bi    = (const float*)d_in[8];
  const float* Wf    = (const float*)d_in[9];
  const float* bfp   = (const float*)d_in[10];
  const float* mhw   = (const float*)d_in[11];
  const float* Wout  = (const float*)d_in[12];
  const float* norm2 = (const float*)d_in[13];
  const float* Wg    = (const float*)d_in[14];
  const float* Wu    = (const float*)d_in[15];
  const float* Wd    = (const float*)d_in[16];
  const float* onw   = (const float*)d_in[17];
  const float* Wlm   = (const float*)d_in[18];

  char* wsb = (char*)d_ws;
  const size_t MB = 1ull << 20;
  float*          x    = (float*)wsb;                          // 8 MiB
  unsigned short* xmb  = (unsigned short*)(wsb + 8 * MB);      // 4 MiB
  float*          ipre = (float*)(wsb + 12 * MB);              // 5 x 32 KiB
  float*          fpre = ipre + 8192;
  float*          garr = fpre + 8192;
  float*          Marr = garr + 8192;
  float*          earr = Marr + 8192;
  float*          npart = earr + 8192;                         // 2 x 32 KiB
  unsigned short* W16  = (unsigned short*)(wsb + 13 * MB);     // 49 MiB -> ends 62
  const size_t OQ = 0, OKk = 524288, OV = 1048576, OOG = 2097152, OOUT = 3145728,
               OGt = 4194304, OU = 7077888, OD = 9961472;
  unsigned short* qb    = (unsigned short*)(wsb + 62 * MB);    // 2 MiB
  unsigned short* kb    = (unsigned short*)(wsb + 64 * MB);    // 2 MiB
  unsigned short* vTb   = (unsigned short*)(wsb + 66 * MB);    // 4 MiB
  float*          og    = (float*)(wsb + 70 * MB);             // 8 MiB
  float*          hp0   = (float*)(wsb + 78 * MB);             // 8 MiB
  float*          hp1   = (float*)(wsb + 86 * MB);             // 8 MiB
  unsigned short* gact  = (unsigned short*)(wsb + 94 * MB);    // 4 MiB
  unsigned short* Gb16  = (unsigned short*)(wsb + 98 * MB);    // 11 MiB -> ends 109
  unsigned short* wlm16 = (unsigned short*)(wsb + 110 * MB);   // 62.5 MiB -> ends 172.5

  embed_kernel<<<2048, 256, 0, stream>>>(tok, emb, x);
  wcvt8_kernel<<<28544, 256, 0, stream>>>(Wq, Wk, Wv, Wog, Wout, Wg, Wu, Wd, Wlm,
                                          W16, wlm16);

  for (int l = 0; l < 2; ++l) {
    const unsigned short* Wl = W16 + (size_t)l * WLAYER;
    const float* n1   = norm1 + (size_t)l * 1024;
    const float* wiv  = Wi   + (size_t)l * 4 * 1024;
    const float* bil  = bi   + (size_t)l * 4;
    const float* wfv  = Wf   + (size_t)l * 4 * 1024;
    const float* bfl  = bfp  + (size_t)l * 4;
    const float* mhwl = mhw  + (size_t)l * 1024;
    const float* n2   = norm2 + (size_t)l * 1024;

    rmsnorm_kernel<<<2048, 256, 0, stream>>>(x, n1, xmb);
    qkvo_kernel<<<dim3(16, 24), 256, 0, stream>>>(xmb, Wl + OQ, Wl + OKk, Wl + OV,
                                                  Wl + OOG, qb, kb, vTb, og);
    gates_kernel<<<2048, 256, 0, stream>>>(x, n1, wiv, bil, wfv, bfl, ipre, fpre);
    scan_kernel<<<1, 256, 0, stream>>>(ipre, fpre, garr, Marr, earr);
    mlstm_mfma_kernel<<<dim3(32, 4, 2), 256, 0, stream>>>(qb, kb, vTb, garr, Marr,
                                                          hp0, hp1, npart);
    mhln_gate_kernel<<<2048, 256, 0, stream>>>(hp0, hp1, npart, earr, mhwl, og, gact);
    gemm_bb_kernel<1><<<dim3(16, 8), 256, 0, stream>>>(gact, Wl + OOUT, x, x, 1024, 1024);
    rmsnorm_kernel<<<2048, 256, 0, stream>>>(x, n2, xmb);
    ffn_kernel<<<dim3(16, 22), 256, 0, stream>>>(xmb, Wl + OGt, Wl + OU, Gb16);
    gemm_bb_kernel<1><<<dim3(16, 8), 256, 0, stream>>>(Gb16, Wl + OD, x, x, 2816, 1024);
  }

  rmsnorm_kernel<<<2048, 256, 0, stream>>>(x, onw, xmb);
  lm256_kernel<<<dim3(8, 125), 512, 0, stream>>>(xmb, wlm16, (float*)d_out);
}

// Round 15
// 810.075 us; speedup vs baseline: 1.0881x; 1.0266x over previous
//
#include <hip/hip_runtime.h>
#include <hip/hip_bf16.h>
#include <math.h>

// xLSTM-Large forward: S=2048, D=1024, NH=4 (Dqk=128, Dv=256), UP=2752, L=2, V=32000.
// GEMMs: bf16 x bf16 MFMA, m97 single-buffered global_load_lds(16B) staging,
// XOR-swizzled LDS, bijective XCD block remap.
// This round: lm256 restored to round-11 best (BK=32, 3-buffer, vmcnt(4),
// stage-before-compute); mLSTM s-split widened x2 -> x4 (512 blocks, 2/CU).

#define S_LEN 2048
#define DMODEL 1024
#define WLAYER 12845056  // elements per layer in W16

typedef __attribute__((ext_vector_type(8))) __bf16 bf16x8;
typedef __attribute__((ext_vector_type(8))) unsigned short u16x8;
typedef __attribute__((ext_vector_type(4))) unsigned short u16x4;
typedef __attribute__((ext_vector_type(4))) float f32x4v;

union cvu { u16x8 u; bf16x8 b; };

__device__ __forceinline__ unsigned short bf_us(float f) {
  union { __bf16 b; unsigned short u; } c;
  c.b = (__bf16)f;   // RNE, native v_cvt on gfx950
  return c.u;
}
__device__ __forceinline__ float us_f(unsigned short u) {
  union { __bf16 b; unsigned short u; } c;
  c.u = u;
  return (float)c.b;
}
__device__ __forceinline__ bf16x8 ld_bf8(const unsigned short* p, int byte_off) {
  cvu c;
  c.u = *(const u16x8*)((const char*)p + byte_off);
  return c.b;
}
__device__ __forceinline__ float fast_sigmoid(float v) {
  return 1.0f / (1.0f + __expf(-v));
}
__device__ __forceinline__ float fast_softcap30(float v) {
  float e = __expf(-fabsf(v) * (1.0f / 15.0f));  // e^{-2|v|/30}
  float t = (1.0f - e) / (1.0f + e);             // tanh(|v|/30)
  return copysignf(30.0f * t, v);
}

#define AS_G __attribute__((address_space(1)))
#define AS_L __attribute__((address_space(3)))

// Stage a 128x64 bf16 tile (16 KB) from global (row stride K elems) into LDS.
// LDS dest linear (DMA requirement); global SOURCE column-group pre-swizzled
// (cg ^= row&7) so the matching XOR on the read side is conflict-free (rule #21).
__device__ __forceinline__ void stage64(const unsigned short* gbase, int K,
                                        unsigned short* lds, int wave, int lane, int k0) {
#pragma unroll
  for (int j = 0; j < 4; ++j) {
    const int rbase = (j * 4 + wave) * 8;
    const int r = rbase + (lane >> 3);
    const int cg = (lane & 7) ^ (r & 7);   // pre-swizzled source column group
    const unsigned short* src = gbase + (size_t)r * K + k0 + cg * 8;
    __builtin_amdgcn_global_load_lds((const AS_G void*)src,
                                     (AS_L void*)(lds + rbase * 64), 16, 0, 0);
  }
}

// ---------------- embed ----------------
__global__ __launch_bounds__(256) void embed_kernel(
    const int* __restrict__ tok, const float* __restrict__ emb, float* __restrict__ x) {
  int s = blockIdx.x;
  int t = tok[s];
  const float4 v = *(const float4*)(emb + (size_t)t * DMODEL + threadIdx.x * 4);
  *(float4*)(x + (size_t)s * DMODEL + threadIdx.x * 4) = v;
}

// ---------------- rmsnorm (row = 1024): writes bf16 ----------------
__global__ __launch_bounds__(256) void rmsnorm_kernel(
    const float* __restrict__ x, const float* __restrict__ w,
    unsigned short* __restrict__ outb) {
  int s = blockIdx.x, tid = threadIdx.x;
  const float* xr = x + (size_t)s * DMODEL;
  float4 v = *(const float4*)(xr + tid * 4);
  float ss = v.x * v.x + v.y * v.y + v.z * v.z + v.w * v.w;
#pragma unroll
  for (int off = 32; off > 0; off >>= 1) ss += __shfl_down(ss, off);
  __shared__ float red[4];
  if ((tid & 63) == 0) red[tid >> 6] = ss;
  __syncthreads();
  float tot = red[0] + red[1] + red[2] + red[3];
  float scale = rsqrtf(tot * (1.0f / DMODEL) + 1e-6f);
  float4 wv = *(const float4*)(w + tid * 4);
  u16x4 ub;
  ub[0] = bf_us(v.x * scale * wv.x);
  ub[1] = bf_us(v.y * scale * wv.y);
  ub[2] = bf_us(v.z * scale * wv.z);
  ub[3] = bf_us(v.w * scale * wv.w);
  *(u16x4*)(outb + (size_t)s * DMODEL + tid * 4) = ub;
}

// ---------------- weight convert f32 -> bf16: both layers + LM head --------------
__global__ __launch_bounds__(256) void wcvt8_kernel(
    const float* __restrict__ Wq, const float* __restrict__ Wk,
    const float* __restrict__ Wv, const float* __restrict__ Wog,
    const float* __restrict__ Wout, const float* __restrict__ Wg,
    const float* __restrict__ Wu, const float* __restrict__ Wd,
    const float* __restrict__ Wlm,
    unsigned short* __restrict__ W, unsigned short* __restrict__ Wlm16) {
  const size_t de = ((size_t)blockIdx.x * 256 + threadIdx.x) * 8;
  if (de >= 2ull * WLAYER) {  // LM head region
    size_t i = de - 2ull * WLAYER;
    float4 a0 = *(const float4*)(Wlm + i);
    float4 a1 = *(const float4*)(Wlm + i + 4);
    u16x8 o;
    o[0] = bf_us(a0.x); o[1] = bf_us(a0.y); o[2] = bf_us(a0.z); o[3] = bf_us(a0.w);
    o[4] = bf_us(a1.x); o[5] = bf_us(a1.y); o[6] = bf_us(a1.z); o[7] = bf_us(a1.w);
    *(u16x8*)(Wlm16 + i) = o;
    return;
  }
  int e = (int)de, l = 0;
  if (e >= WLAYER) { l = 1; e -= WLAYER; }
  const float* src = nullptr;
  size_t idx = 0;
  if (e < 524288)       { src = Wq  + (size_t)l * 524288;  idx = e; }
  else if (e < 1048576) { src = Wk  + (size_t)l * 524288;  idx = e - 524288; }
  else if (e < 2097152) { src = Wv  + (size_t)l * 1048576; idx = e - 1048576; }
  else if (e < 3145728) { src = Wog + (size_t)l * 1048576; idx = e - 2097152; }
  else if (e < 4194304) { src = Wout + (size_t)l * 1048576; idx = e - 3145728; }
  else if (e < 7077888) {
    int t = e - 4194304, row = t >> 10;
    if (row < 2752) { src = Wg + (size_t)l * 2818048; idx = t; }
  } else if (e < 9961472) {
    int t = e - 7077888, row = t >> 10;
    if (row < 2752) { src = Wu + (size_t)l * 2818048; idx = t; }
  } else {
    int t = e - 9961472, row = t / 2816, col = t - row * 2816;
    if (col < 2752) { src = Wd + (size_t)l * 2818048; idx = row * 2752 + col; }
  }
  u16x8 o;
  if (src) {
    float4 a0 = *(const float4*)(src + idx);
    float4 a1 = *(const float4*)(src + idx + 4);
    o[0] = bf_us(a0.x); o[1] = bf_us(a0.y); o[2] = bf_us(a0.z); o[3] = bf_us(a0.w);
    o[4] = bf_us(a1.x); o[5] = bf_us(a1.y); o[6] = bf_us(a1.z); o[7] = bf_us(a1.w);
  } else {
#pragma unroll
    for (int k = 0; k < 8; ++k) o[k] = 0;
  }
  *(u16x8*)(W + de) = o;
}

// ---------------- GEMM core: 128x128 tile (layer GEMMs) ----------------
// EPI: 0 f32 store | 1 f32 acc+X residual
template <int EPI>
__global__ __launch_bounds__(256) void gemm_bb_kernel(
    const unsigned short* __restrict__ A, const unsigned short* __restrict__ B,
    const void* Xv, void* Cv, int K, int ldc) {
  __shared__ __align__(16) unsigned short As[128 * 64];
  __shared__ __align__(16) unsigned short Bs[128 * 64];
  const int tid = threadIdx.x;
  const int wave = tid >> 6, lane = tid & 63;
  const int gx = gridDim.x;
  const int nwg = gx * gridDim.y;
  const int d = blockIdx.y * gx + blockIdx.x;
  const int q = nwg >> 3;
  const int lgc = (d & 7) * q + (d >> 3);
  const int bm = (lgc % gx) * 128, bn = (lgc / gx) * 128;
  const int wr = (wave >> 1) * 64, wc = (wave & 1) * 64;
  const int lr = lane & 15, lhi = lane >> 4;
  const unsigned short* Ab = A + (size_t)bm * K;
  const unsigned short* Bb = B + (size_t)bn * K;
  f32x4v acc[4][4] = {};

  const int NK = K >> 6;
  for (int it = 0; it < NK; ++it) {
    stage64(Ab, K, As, wave, lane, it << 6);
    stage64(Bb, K, Bs, wave, lane, it << 6);
    __syncthreads();
#pragma unroll
    for (int kk = 0; kk < 2; ++kk) {
      const int sw = (((kk * 4 + lhi) ^ (lr & 7)) << 3);
      bf16x8 af[4], bfr[4];
#pragma unroll
      for (int mi = 0; mi < 4; ++mi) af[mi] = *(const bf16x8*)&As[(wr + mi * 16 + lr) * 64 + sw];
#pragma unroll
      for (int ni = 0; ni < 4; ++ni) bfr[ni] = *(const bf16x8*)&Bs[(wc + ni * 16 + lr) * 64 + sw];
#pragma unroll
      for (int mi = 0; mi < 4; ++mi)
#pragma unroll
        for (int ni = 0; ni < 4; ++ni)
          acc[mi][ni] = __builtin_amdgcn_mfma_f32_16x16x32_bf16(af[mi], bfr[ni], acc[mi][ni], 0, 0, 0);
    }
    __syncthreads();
  }
#pragma unroll
  for (int mi = 0; mi < 4; ++mi) {
#pragma unroll
    for (int ni = 0; ni < 4; ++ni) {
#pragma unroll
      for (int j = 0; j < 4; ++j) {
        int row = bm + wr + mi * 16 + lhi * 4 + j;   // C/D layout (m89)
        int col = bn + wc + ni * 16 + lr;
        float v = acc[mi][ni][j];
        if (EPI == 0)
          ((float*)Cv)[(size_t)row * ldc + col] = v;
        if (EPI == 1)
          ((float*)Cv)[(size_t)row * ldc + col] = v + ((const float*)Xv)[(size_t)row * ldc + col];
      }
    }
  }
}

// ---------------- LM head GEMM: 256x256 tile, 8 waves, BK=32, 3-buffer pipeline ---
// Per K-tile: vmcnt(4) -> s_barrier -> issue stage(t+2) -> 12 ds_read + 32 MFMA.
// Buffer t%3: stage(t+2) never touches the buffers of t or t+1 (race-free).
// Swizzle for 64B rows: cg ^= (row>>1)&3 on BOTH source and read (involution).
// Round-11 proven configuration (181 us, MfmaUtil ~31%).
__global__ __launch_bounds__(512, 2) void lm256_kernel(
    const unsigned short* __restrict__ A, const unsigned short* __restrict__ B,
    float* __restrict__ C) {
  __shared__ __align__(16) unsigned short SH[3 * 16384];  // 3 x (A 256x32 | B 256x32) = 96 KB
  const int K = 1024, N = 32000, NT = 32;
  const int tid = threadIdx.x;
  const int wave = tid >> 6, lane = tid & 63;
  const int lr = lane & 15, lg = lane >> 4;
  const int wm = wave >> 2, wn = wave & 3;     // 2M x 4N waves, 128x64 each
  const int d = blockIdx.y * 8 + blockIdx.x;
  const int lgc = (d & 7) * 125 + (d >> 3);
  const int bm = (lgc & 7) * 256;
  const int bn = (lgc >> 3) * 256;
  const unsigned short* Ab = A + (size_t)bm * K;
  const unsigned short* Bb = B + (size_t)bn * K;

  // stage one 256x32 matrix tile (16 KB) into linear LDS: 2 issues of 8 KB
  auto stageM = [&](const unsigned short* gbase, unsigned short* lds, int k0) {
#pragma unroll
    for (int j = 0; j < 2; ++j) {
      const int r = j * 128 + wave * 16 + (lane >> 2);
      const int cg = (lane & 3) ^ ((r >> 1) & 3);   // pre-swizzled source column group
      const unsigned short* src = gbase + (size_t)r * K + k0 + cg * 8;
      __builtin_amdgcn_global_load_lds((const AS_G void*)src,
                                       (AS_L void*)(lds + (j * 128 + wave * 16) * 32), 16, 0, 0);
    }
  };
  auto stageT = [&](int tau) {
    unsigned short* base = SH + (tau % 3) * 16384;
    stageM(Ab, base, tau * 32);
    stageM(Bb, base + 8192, tau * 32);
  };

  f32x4v acc[8][4] = {};
  stageT(0);
  stageT(1);
  for (int t = 0; t < NT; ++t) {
    if (t < NT - 1) asm volatile("s_waitcnt vmcnt(4)" ::: "memory");
    else            asm volatile("s_waitcnt vmcnt(0)" ::: "memory");
    asm volatile("s_barrier" ::: "memory");
    if (t + 2 < NT) stageT(t + 2);
    const unsigned short* Al = SH + (t % 3) * 16384;
    const unsigned short* Bl = Al + 8192;
    bf16x8 bfr[4];
#pragma unroll
    for (int ni = 0; ni < 4; ++ni) {
      int row = wn * 64 + ni * 16 + lr;
      bfr[ni] = *(const bf16x8*)&Bl[row * 32 + ((lg ^ ((row >> 1) & 3)) << 3)];
    }
#pragma unroll
    for (int mi = 0; mi < 8; ++mi) {
      int row = wm * 128 + mi * 16 + lr;
      bf16x8 af = *(const bf16x8*)&Al[row * 32 + ((lg ^ ((row >> 1) & 3)) << 3)];
      __builtin_amdgcn_s_setprio(1);
#pragma unroll
      for (int ni = 0; ni < 4; ++ni)
        acc[mi][ni] = __builtin_amdgcn_mfma_f32_16x16x32_bf16(af, bfr[ni], acc[mi][ni], 0, 0, 0);
      __builtin_amdgcn_s_setprio(0);
    }
  }
#pragma unroll
  for (int mi = 0; mi < 8; ++mi)
#pragma unroll
    for (int ni = 0; ni < 4; ++ni)
#pragma unroll
      for (int jj = 0; jj < 4; ++jj) {
        int row = bm + wm * 128 + mi * 16 + lg * 4 + jj;
        int col = bn + wn * 64 + ni * 16 + lr;
        C[(size_t)row * N + col] = fast_softcap30(acc[mi][ni][jj]);
      }
}

// ---------------- fused QKV+OG GEMM ----------------
__global__ __launch_bounds__(256) void qkvo_kernel(
    const unsigned short* __restrict__ A, const unsigned short* __restrict__ Wq16,
    const unsigned short* __restrict__ Wk16, const unsigned short* __restrict__ Wv16,
    const unsigned short* __restrict__ Wog16,
    unsigned short* __restrict__ qb, unsigned short* __restrict__ kb,
    unsigned short* __restrict__ vTb, float* __restrict__ og) {
  __shared__ __align__(16) unsigned short SH[2 * 128 * 64];
  unsigned short* Asb = SH;
  unsigned short* Bsb = SH + 128 * 64;
  const int tid = threadIdx.x;
  const int wave = tid >> 6, lane = tid & 63;
  const int gx = gridDim.x;                 // 16 (M)
  const int nwg = gx * gridDim.y;           // 384
  const int dd = blockIdx.y * gx + blockIdx.x;
  const int qq = nwg >> 3;
  const int lgc = (dd & 7) * qq + (dd >> 3);
  const int bm = (lgc % gx) * 128;
  const int by = lgc / gx;
  const unsigned short* B;
  int bnl, mode;
  if (by < 4)       { B = Wq16;  bnl = by * 128;        mode = 0; }
  else if (by < 8)  { B = Wk16;  bnl = (by - 4) * 128;  mode = 1; }
  else if (by < 16) { B = Wv16;  bnl = (by - 8) * 128;  mode = 2; }
  else              { B = Wog16; bnl = (by - 16) * 128; mode = 3; }
  const int K = 1024;
  const int wr = (wave >> 1) * 64, wc = (wave & 1) * 64;
  const int lr = lane & 15, lhi = lane >> 4;
  const unsigned short* Ab = A + (size_t)bm * K;
  const unsigned short* Bb = B + (size_t)bnl * K;
  f32x4v acc[4][4] = {};

  for (int it = 0; it < 16; ++it) {
    stage64(Ab, K, Asb, wave, lane, it << 6);
    stage64(Bb, K, Bsb, wave, lane, it << 6);
    __syncthreads();
#pragma unroll
    for (int kk = 0; kk < 2; ++kk) {
      const int sw = (((kk * 4 + lhi) ^ (lr & 7)) << 3);
      bf16x8 af[4], bfr[4];
#pragma unroll
      for (int mi = 0; mi < 4; ++mi) af[mi] = *(const bf16x8*)&Asb[(wr + mi * 16 + lr) * 64 + sw];
#pragma unroll
      for (int ni = 0; ni < 4; ++ni) bfr[ni] = *(const bf16x8*)&Bsb[(wc + ni * 16 + lr) * 64 + sw];
#pragma unroll
      for (int mi = 0; mi < 4; ++mi)
#pragma unroll
        for (int ni = 0; ni < 4; ++ni)
          acc[mi][ni] = __builtin_amdgcn_mfma_f32_16x16x32_bf16(af[mi], bfr[ni], acc[mi][ni], 0, 0, 0);
    }
    __syncthreads();
  }
  if (mode == 2) {
#pragma unroll
    for (int mi = 0; mi < 4; ++mi)
#pragma unroll
      for (int ni = 0; ni < 4; ++ni)
#pragma unroll
        for (int j = 0; j < 4; ++j) {
          int row = wr + mi * 16 + lhi * 4 + j;
          int col = wc + ni * 16 + lr;
          int byte = col * 256 + ((((row >> 3) ^ (col & 7)) << 4)) + (row & 7) * 2;
          *(unsigned short*)((char*)SH + byte) = bf_us(acc[mi][ni][j]);
        }
    __syncthreads();
#pragma unroll
    for (int i = 0; i < 8; ++i) {
      int c = i * 16 + (tid >> 4);
      int rg = tid & 15;
      u16x8 u = *(const u16x8*)((const char*)SH + c * 256 + ((rg ^ (c & 7)) << 4));
      *(u16x8*)(vTb + (size_t)(bnl + c) * S_LEN + bm + rg * 8) = u;
    }
  } else {
#pragma unroll
    for (int mi = 0; mi < 4; ++mi)
#pragma unroll
      for (int ni = 0; ni < 4; ++ni)
#pragma unroll
        for (int j = 0; j < 4; ++j) {
          int row = bm + wr + mi * 16 + lhi * 4 + j;
          int col = bnl + wc + ni * 16 + lr;
          if (mode == 0)      qb[(size_t)row * 512 + col] = bf_us(acc[mi][ni][j]);
          else if (mode == 1) kb[(size_t)row * 512 + col] = bf_us(acc[mi][ni][j]);
          else                og[(size_t)row * 1024 + col] = acc[mi][ni][j];
        }
  }
}

// ---------------- fused FFN gate+up GEMM: Gb = silu(A Wg^T) * (A Wu^T), bf16 -------
__global__ __launch_bounds__(256) void ffn_kernel(
    const unsigned short* __restrict__ A, const unsigned short* __restrict__ Bg,
    const unsigned short* __restrict__ Bu, unsigned short* __restrict__ Gb) {
  __shared__ __align__(16) unsigned short As[128 * 64];
  __shared__ __align__(16) unsigned short Bgs[128 * 64];
  __shared__ __align__(16) unsigned short Bus[128 * 64];
  const int K = 1024;
  const int tid = threadIdx.x;
  const int wave = tid >> 6, lane = tid & 63;
  const int gx = gridDim.x;                 // 16
  const int nwg = gx * gridDim.y;           // 352
  const int dd = blockIdx.y * gx + blockIdx.x;
  const int qq = nwg >> 3;
  const int lgc = (dd & 7) * qq + (dd >> 3);
  const int bm = (lgc % gx) * 128;
  const int bn = (lgc / gx) * 128;
  const int wr = (wave >> 1) * 64, wc = (wave & 1) * 64;
  const int lr = lane & 15, lhi = lane >> 4;
  const unsigned short* Ab = A + (size_t)bm * K;
  const unsigned short* Bgb = Bg + (size_t)bn * K;
  const unsigned short* Bub = Bu + (size_t)bn * K;
  f32x4v accg[4][4] = {};
  f32x4v accu[4][4] = {};
  for (int it = 0; it < 16; ++it) {
    stage64(Ab, K, As, wave, lane, it << 6);
    stage64(Bgb, K, Bgs, wave, lane, it << 6);
    stage64(Bub, K, Bus, wave, lane, it << 6);
    __syncthreads();
#pragma unroll
    for (int kk = 0; kk < 2; ++kk) {
      const int sw = (((kk * 4 + lhi) ^ (lr & 7)) << 3);
      bf16x8 af[4], bg[4], bu[4];
#pragma unroll
      for (int mi = 0; mi < 4; ++mi) af[mi] = *(const bf16x8*)&As[(wr + mi * 16 + lr) * 64 + sw];
#pragma unroll
      for (int ni = 0; ni < 4; ++ni) bg[ni] = *(const bf16x8*)&Bgs[(wc + ni * 16 + lr) * 64 + sw];
#pragma unroll
      for (int ni = 0; ni < 4; ++ni) bu[ni] = *(const bf16x8*)&Bus[(wc + ni * 16 + lr) * 64 + sw];
#pragma unroll
      for (int mi = 0; mi < 4; ++mi)
#pragma unroll
        for (int ni = 0; ni < 4; ++ni) {
          accg[mi][ni] = __builtin_amdgcn_mfma_f32_16x16x32_bf16(af[mi], bg[ni], accg[mi][ni], 0, 0, 0);
          accu[mi][ni] = __builtin_amdgcn_mfma_f32_16x16x32_bf16(af[mi], bu[ni], accu[mi][ni], 0, 0, 0);
        }
    }
    __syncthreads();
  }
#pragma unroll
  for (int mi = 0; mi < 4; ++mi) {
#pragma unroll
    for (int ni = 0; ni < 4; ++ni) {
#pragma unroll
      for (int j = 0; j < 4; ++j) {
        int row = bm + wr + mi * 16 + lhi * 4 + j;
        int col = bn + wc + ni * 16 + lr;
        float g = accg[mi][ni][j];
        float sv = g * fast_sigmoid(g) * accu[mi][ni][j];
        Gb[(size_t)row * 2816 + col] = bf_us(sv);
      }
    }
  }
}

// ---------------- gate pre-activations (inline rmsnorm from f32 x) ----------------
__global__ __launch_bounds__(256) void gates_kernel(
    const float* __restrict__ x, const float* __restrict__ n1,
    const float* __restrict__ Wi, const float* __restrict__ bi,
    const float* __restrict__ Wf, const float* __restrict__ bfv,
    float* __restrict__ ipre, float* __restrict__ fpre) {
  int s = blockIdx.x;
  int head = threadIdx.x >> 6, lane = threadIdx.x & 63;
  const float* xr = x + (size_t)s * DMODEL;
  float xv[16];
  float ss = 0.f;
#pragma unroll
  for (int j = 0; j < 16; ++j) { xv[j] = xr[lane + j * 64]; ss += xv[j] * xv[j]; }
#pragma unroll
  for (int off = 32; off > 0; off >>= 1) ss += __shfl_xor(ss, off);
  float scale = rsqrtf(ss * (1.0f / DMODEL) + 1e-6f);
  const float* wi = Wi + head * DMODEL;
  const float* wf = Wf + head * DMODEL;
  float si = 0.f, sf = 0.f;
#pragma unroll
  for (int j = 0; j < 16; ++j) {
    int c = lane + j * 64;
    float xm = xv[j] * scale * n1[c];
    si += xm * wi[c];
    sf += xm * wf[c];
  }
#pragma unroll
  for (int off = 32; off > 0; off >>= 1) {
    si += __shfl_down(si, off);
    sf += __shfl_down(sf, off);
  }
  if (lane == 0) {
    ipre[head * S_LEN + s] = 15.0f * tanhf((si + bi[head]) * (1.0f / 15.0f));
    fpre[head * S_LEN + s] = 15.0f * tanhf((sf + bfv[head]) * (1.0f / 15.0f));
  }
}

// ---------------- per-head scan ----------------
__global__ __launch_bounds__(256) void scan_kernel(
    const float* __restrict__ ipre, const float* __restrict__ fpre,
    float* __restrict__ garr, float* __restrict__ Marr, float* __restrict__ earr) {
  const int h = threadIdx.x >> 6;
  const int lane = threadIdx.x & 63;
  const int base = h * S_LEN + lane * 32;
  float lf[32];
  float lsum = 0.f;
#pragma unroll
  for (int e = 0; e < 32; ++e) {
    float f = fpre[base + e];
    float v = fminf(f, 0.f) - log1pf(expf(-fabsf(f)));
    lf[e] = v;
    lsum += v;
  }
  float scan = lsum;
#pragma unroll
  for (int off = 1; off < 64; off <<= 1) {
    float t = __shfl_up(scan, off);
    if (lane >= off) scan += t;
  }
  float F0 = scan - lsum;
  float gv[32];
  float F = F0, lmax = -1e30f;
#pragma unroll
  for (int e = 0; e < 32; ++e) {
    F += lf[e];
    float g = ipre[base + e] - F;
    gv[e] = g;
    lmax = fmaxf(lmax, g);
    garr[base + e] = g;
  }
  float ms = lmax;
#pragma unroll
  for (int off = 1; off < 64; off <<= 1) {
    float t = __shfl_up(ms, off);
    if (lane >= off) ms = fmaxf(ms, t);
  }
  float em = __shfl_up(ms, 1);
  if (lane == 0) em = -1e30f;
  float run = em;
  F = F0;
#pragma unroll
  for (int e = 0; e < 32; ++e) {
    F += lf[e];
    run = fmaxf(run, gv[e]);
    Marr[base + e] = run;
    earr[base + e] = expf(-(F + run));
  }
}

// ---------------- mLSTM parallel, bf16 MFMA flash-style, s-split x4 ----------------
// grid (32 T-tiles, 4 heads, 4 splits). Split sp handles chunks ch = sp, sp+4, ...
// Unscaled partial pv into hp + sp*2M floats; partial row-sums into npart[sp].
__global__ __launch_bounds__(256) void mlstm_mfma_kernel(
    const unsigned short* __restrict__ Q, const unsigned short* __restrict__ Kb,
    const unsigned short* __restrict__ vT, const float* __restrict__ garr,
    const float* __restrict__ Marr,
    float* __restrict__ hp, float* __restrict__ npart) {
  const int h = blockIdx.y;
  const int T = blockIdx.x;
  const int sp = blockIdx.z;
  float* hpart = hp + (size_t)sp * 2097152;
  const int tid = threadIdx.x;
  const int w = tid >> 6, l = tid & 63;
  const int lr = l & 15, lg = l >> 4;
  const int hbase = h * S_LEN;
  const int sr = tid >> 4;
  const int sc = tid & 15;

  __shared__ __align__(16) unsigned short Ks[64 * 128];
  __shared__ __align__(16) unsigned short Vs[256 * 64];
  __shared__ __align__(16) unsigned short Ps[64 * 64];

  bf16x8 qf[4];
  {
    const unsigned short* qrow = Q + (size_t)(T * 64 + w * 16 + lr) * 512 + h * 128 + lg * 8;
#pragma unroll
    for (int kt = 0; kt < 4; ++kt) {
      cvu c;
      c.u = *(const u16x8*)(qrow + kt * 32);
      qf[kt] = c.b;
    }
  }
  float Mt[4];
#pragma unroll
  for (int j = 0; j < 4; ++j) Mt[j] = Marr[hbase + T * 64 + w * 16 + lg * 4 + j];

  f32x4v pv[16] = {};
  float nacc[4] = {0.f, 0.f, 0.f, 0.f};
  const float rs = 0.08838834764831845f;  // 1/sqrt(128)

  for (int ch = sp; ch <= T; ch += 4) {
    const int s0 = ch * 64;
    __syncthreads();
#pragma unroll
    for (int i = 0; i < 4; ++i) {
      int r = i * 16 + sr;
      u16x8 u = *(const u16x8*)(Kb + (size_t)(s0 + r) * 512 + h * 128 + sc * 8);
      int byte = r * 256 + ((sc * 16) ^ ((r & 7) << 4));
      *(u16x8*)((char*)Ks + byte) = u;
    }
#pragma unroll
    for (int i = 0; i < 16; ++i) {
      int r = i * 16 + sr;
      u16x4 u = *(const u16x4*)(vT + (size_t)(h * 256 + r) * S_LEN + s0 + sc * 4);
      int byte = r * 128 + ((sc * 8) ^ ((r & 7) << 4));
      *(u16x4*)((char*)Vs + byte) = u;
    }
    __syncthreads();
    f32x4v sa[4] = {};
#pragma unroll
    for (int ni = 0; ni < 4; ++ni) {
#pragma unroll
      for (int kt = 0; kt < 4; ++kt) {
        int row = ni * 16 + lr;
        int byte = row * 256 + (((kt * 32 + lg * 8) * 2) ^ ((row & 7) << 4));
        bf16x8 kf = ld_bf8(Ks, byte);
        sa[ni] = __builtin_amdgcn_mfma_f32_16x16x32_bf16(qf[kt], kf, sa[ni], 0, 0, 0);
      }
    }
#pragma unroll
    for (int ni = 0; ni < 4; ++ni) {
      int sl = ni * 16 + lr;
      int sg = s0 + sl;
      float gv = garr[hbase + sg];
#pragma unroll
      for (int j = 0; j < 4; ++j) {
        int tloc = w * 16 + lg * 4 + j;
        int tg = T * 64 + tloc;
        float wgt = (sg <= tg) ? __expf(gv - Mt[j]) : 0.f;
        float val = sa[ni][j] * rs * wgt;
        nacc[j] += val;
        int byte = tloc * 128 + ((sl * 2) ^ ((tloc & 7) << 4));
        *(unsigned short*)((char*)Ps + byte) = bf_us(val);
      }
    }
#pragma unroll
    for (int kt2 = 0; kt2 < 2; ++kt2) {
      int tloc = w * 16 + lr;
      int sb = (kt2 * 32 + lg * 8) * 2;
      bf16x8 pa = ld_bf8(Ps, tloc * 128 + (sb ^ ((tloc & 7) << 4)));
#pragma unroll
      for (int nv = 0; nv < 16; ++nv) {
        int dv = nv * 16 + lr;
        bf16x8 vb = ld_bf8(Vs, dv * 128 + (sb ^ ((dv & 7) << 4)));
        pv[nv] = __builtin_amdgcn_mfma_f32_16x16x32_bf16(pa, vb, pv[nv], 0, 0, 0);
      }
    }
  }
#pragma unroll
  for (int j = 0; j < 4; ++j) {
#pragma unroll
    for (int off = 1; off < 16; off <<= 1) nacc[j] += __shfl_xor(nacc[j], off);
  }
#pragma unroll
  for (int j = 0; j < 4; ++j) {
    int tg = T * 64 + w * 16 + lg * 4 + j;
    if (lr == 0) npart[sp * 8192 + hbase + tg] = nacc[j];
    float* orow = hpart + (size_t)tg * DMODEL + h * 256;
#pragma unroll
    for (int nvt = 0; nvt < 16; ++nvt) orow[nvt * 16 + lr] = pv[nvt][j];
  }
}

// ---------------- combine(4) + multihead LayerNorm * mhw * sigmoid(og) -> bf16 ----
__global__ __launch_bounds__(256) void mhln_gate_kernel(
    const float* __restrict__ hp, const float* __restrict__ npart,
    const float* __restrict__ earr, const float* __restrict__ mhw,
    const float* __restrict__ og, unsigned short* __restrict__ gact) {
  int s = blockIdx.x;
  int head = threadIdx.x >> 6, lane = threadIdx.x & 63;
  float n = (npart[head * S_LEN + s] + npart[8192 + head * S_LEN + s]) +
            (npart[16384 + head * S_LEN + s] + npart[24576 + head * S_LEN + s]);
  float nvv = fmaxf(fabsf(n), earr[head * S_LEN + s]);
  float inv = 1.0f / (nvv + 1e-6f);
  const size_t base = (size_t)s * DMODEL + head * 256;
  float vq[4];
#pragma unroll
  for (int qy = 0; qy < 4; ++qy) {
    size_t o = base + qy * 64 + lane;
    vq[qy] = ((hp[o] + hp[o + 2097152]) + (hp[o + 4194304] + hp[o + 6291456])) * inv;
  }
  float sum = vq[0] + vq[1] + vq[2] + vq[3];
#pragma unroll
  for (int off = 32; off > 0; off >>= 1) sum += __shfl_xor(sum, off);
  float mu = sum * (1.0f / 256.0f);
  float d0 = vq[0] - mu, d1 = vq[1] - mu, d2 = vq[2] - mu, d3 = vq[3] - mu;
  float vs = d0 * d0 + d1 * d1 + d2 * d2 + d3 * d3;
#pragma unroll
  for (int off = 32; off > 0; off >>= 1) vs += __shfl_xor(vs, off);
  float rstd = rsqrtf(vs * (1.0f / 256.0f) + 1e-6f);
  float dn[4] = {d0, d1, d2, d3};
#pragma unroll
  for (int qy = 0; qy < 4; ++qy) {
    int c = head * 256 + qy * 64 + lane;
    float ov = og[(size_t)s * DMODEL + c];
    gact[(size_t)s * DMODEL + c] = bf_us(dn[qy] * rstd * mhw[c] * fast_sigmoid(ov));
  }
}

extern "C" void kernel_launch(void* const* d_in, const int* in_sizes, int n_in,
                              void* d_out, int out_size, void* d_ws, size_t ws_size,
                              hipStream_t stream) {
  (void)in_sizes; (void)n_in; (void)out_size; (void)ws_size;
  const int*   tok   = (const int*)d_in[0];
  const float* emb   = (const float*)d_in[1];
  const float* norm1 = (const float*)d_in[2];
  const float* Wq    = (const float*)d_in[3];
  const float* Wk    = (const float*)d_in[4];
  const float* Wv    = (const float*)d_in[5];
  const float* Wog   = (const float*)d_in[6];
  const float* Wi    = (const float*)d_in[7];
  const float* bi    = (const float*)d_in[8];
  const float* Wf    = (const float*)d_in[9];
  const float* bfp   = (const float*)d_in[10];
  const float* mhw   = (const float*)d_in[11];
  const float* Wout  = (const float*)d_in[12];
  const float* norm2 = (const float*)d_in[13];
  const float* Wg    = (const float*)d_in[14];
  const float* Wu    = (const float*)d_in[15];
  const float* Wd    = (const float*)d_in[16];
  const float* onw   = (const float*)d_in[17];
  const float* Wlm   = (const float*)d_in[18];

  char* wsb = (char*)d_ws;
  const size_t MB = 1ull << 20;
  float*          x    = (float*)wsb;                          // 8 MiB
  unsigned short* xmb  = (unsigned short*)(wsb + 8 * MB);      // 4 MiB
  float*          ipre = (float*)(wsb + 12 * MB);              // scalars region
  float*          fpre = ipre + 8192;
  float*          garr = fpre + 8192;
  float*          Marr = garr + 8192;
  float*          earr = Marr + 8192;
  float*          npart = earr + 8192;                         // 4 x 32 KiB
  unsigned short* W16  = (unsigned short*)(wsb + 13 * MB);     // 49 MiB -> ends 62
  const size_t OQ = 0, OKk = 524288, OV = 1048576, OOG = 2097152, OOUT = 3145728,
               OGt = 4194304, OU = 7077888, OD = 9961472;
  unsigned short* qb    = (unsigned short*)(wsb + 62 * MB);    // 2 MiB
  unsigned short* kb    = (unsigned short*)(wsb + 64 * MB);    // 2 MiB
  unsigned short* vTb   = (unsigned short*)(wsb + 66 * MB);    // 4 MiB
  float*          og    = (float*)(wsb + 70 * MB);             // 8 MiB
  float*          hp    = (float*)(wsb + 78 * MB);             // 4 x 8 MiB -> ends 110
  unsigned short* gact  = (unsigned short*)(wsb + 110 * MB);   // 4 MiB
  unsigned short* Gb16  = (unsigned short*)(wsb + 114 * MB);   // 11 MiB -> ends 125
  unsigned short* wlm16 = (unsigned short*)(wsb + 126 * MB);   // 62.5 MiB -> ends 188.5

  embed_kernel<<<2048, 256, 0, stream>>>(tok, emb, x);
  wcvt8_kernel<<<28544, 256, 0, stream>>>(Wq, Wk, Wv, Wog, Wout, Wg, Wu, Wd, Wlm,
                                          W16, wlm16);

  for (int l = 0; l < 2; ++l) {
    const unsigned short* Wl = W16 + (size_t)l * WLAYER;
    const float* n1   = norm1 + (size_t)l * 1024;
    const float* wiv  = Wi   + (size_t)l * 4 * 1024;
    const float* bil  = bi   + (size_t)l * 4;
    const float* wfv  = Wf   + (size_t)l * 4 * 1024;
    const float* bfl  = bfp  + (size_t)l * 4;
    const float* mhwl = mhw  + (size_t)l * 1024;
    const float* n2   = norm2 + (size_t)l * 1024;

    rmsnorm_kernel<<<2048, 256, 0, stream>>>(x, n1, xmb);
    qkvo_kernel<<<dim3(16, 24), 256, 0, stream>>>(xmb, Wl + OQ, Wl + OKk, Wl + OV,
                                                  Wl + OOG, qb, kb, vTb, og);
    gates_kernel<<<2048, 256, 0, stream>>>(x, n1, wiv, bil, wfv, bfl, ipre, fpre);
    scan_kernel<<<1, 256, 0, stream>>>(ipre, fpre, garr, Marr, earr);
    mlstm_mfma_kernel<<<dim3(32, 4, 4), 256, 0, stream>>>(qb, kb, vTb, garr, Marr,
                                                          hp, npart);
    mhln_gate_kernel<<<2048, 256, 0, stream>>>(hp, npart, earr, mhwl, og, gact);
    gemm_bb_kernel<1><<<dim3(16, 8), 256, 0, stream>>>(gact, Wl + OOUT, x, x, 1024, 1024);
    rmsnorm_kernel<<<2048, 256, 0, stream>>>(x, n2, xmb);
    ffn_kernel<<<dim3(16, 22), 256, 0, stream>>>(xmb, Wl + OGt, Wl + OU, Gb16);
    gemm_bb_kernel<1><<<dim3(16, 8), 256, 0, stream>>>(Gb16, Wl + OD, x, x, 2816, 1024);
  }

  rmsnorm_kernel<<<2048, 256, 0, stream>>>(x, onw, xmb);
  lm256_kernel<<<dim3(8, 125), 512, 0, stream>>>(xmb, wlm16, (float*)d_out);
}

// Round 16
// 731.280 us; speedup vs baseline: 1.2053x; 1.1077x over previous
//
#include <hip/hip_runtime.h>
#include <hip/hip_bf16.h>
#include <math.h>

// xLSTM-Large forward: S=2048, D=1024, NH=4 (Dqk=128, Dv=256), UP=2752, L=2, V=32000.
// This round: lm256's proven BK=32/3-buffer/counted-vmcnt pipeline ported to the
// 128x128 layer GEMMs (gemm_bb, qkvo). ffn unchanged (risk containment).

#define S_LEN 2048
#define DMODEL 1024
#define WLAYER 12845056  // elements per layer in W16

typedef __attribute__((ext_vector_type(8))) __bf16 bf16x8;
typedef __attribute__((ext_vector_type(8))) unsigned short u16x8;
typedef __attribute__((ext_vector_type(4))) unsigned short u16x4;
typedef __attribute__((ext_vector_type(4))) float f32x4v;

union cvu { u16x8 u; bf16x8 b; };

__device__ __forceinline__ unsigned short bf_us(float f) {
  union { __bf16 b; unsigned short u; } c;
  c.b = (__bf16)f;   // RNE, native v_cvt on gfx950
  return c.u;
}
__device__ __forceinline__ float us_f(unsigned short u) {
  union { __bf16 b; unsigned short u; } c;
  c.u = u;
  return (float)c.b;
}
__device__ __forceinline__ bf16x8 ld_bf8(const unsigned short* p, int byte_off) {
  cvu c;
  c.u = *(const u16x8*)((const char*)p + byte_off);
  return c.b;
}
__device__ __forceinline__ float fast_sigmoid(float v) {
  return 1.0f / (1.0f + __expf(-v));
}
__device__ __forceinline__ float fast_softcap30(float v) {
  float e = __expf(-fabsf(v) * (1.0f / 15.0f));  // e^{-2|v|/30}
  float t = (1.0f - e) / (1.0f + e);             // tanh(|v|/30)
  return copysignf(30.0f * t, v);
}

#define AS_G __attribute__((address_space(1)))
#define AS_L __attribute__((address_space(3)))

// Stage a 128x64 bf16 tile (16 KB) from global into LDS (legacy, ffn only).
__device__ __forceinline__ void stage64(const unsigned short* gbase, int K,
                                        unsigned short* lds, int wave, int lane, int k0) {
#pragma unroll
  for (int j = 0; j < 4; ++j) {
    const int rbase = (j * 4 + wave) * 8;
    const int r = rbase + (lane >> 3);
    const int cg = (lane & 7) ^ (r & 7);   // pre-swizzled source column group
    const unsigned short* src = gbase + (size_t)r * K + k0 + cg * 8;
    __builtin_amdgcn_global_load_lds((const AS_G void*)src,
                                     (AS_L void*)(lds + rbase * 64), 16, 0, 0);
  }
}

// Stage a 128x32 bf16 tile (8 KB) into linear LDS: 2 issues of 4 KB (64 rows).
// Source col-group pre-swizzled (cg ^= (row>>1)&3); matching XOR on read.
__device__ __forceinline__ void stage32(const unsigned short* gbase, int K,
                                        unsigned short* lds, int wave, int lane, int k0) {
#pragma unroll
  for (int j = 0; j < 2; ++j) {
    const int r = j * 64 + wave * 16 + (lane >> 2);
    const int cg = (lane & 3) ^ ((r >> 1) & 3);
    const unsigned short* src = gbase + (size_t)r * K + k0 + cg * 8;
    __builtin_amdgcn_global_load_lds((const AS_G void*)src,
                                     (AS_L void*)(lds + (j * 64 + wave * 16) * 32), 16, 0, 0);
  }
}

// ---------------- embed ----------------
__global__ __launch_bounds__(256) void embed_kernel(
    const int* __restrict__ tok, const float* __restrict__ emb, float* __restrict__ x) {
  int s = blockIdx.x;
  int t = tok[s];
  const float4 v = *(const float4*)(emb + (size_t)t * DMODEL + threadIdx.x * 4);
  *(float4*)(x + (size_t)s * DMODEL + threadIdx.x * 4) = v;
}

// ---------------- rmsnorm (row = 1024): writes bf16 ----------------
__global__ __launch_bounds__(256) void rmsnorm_kernel(
    const float* __restrict__ x, const float* __restrict__ w,
    unsigned short* __restrict__ outb) {
  int s = blockIdx.x, tid = threadIdx.x;
  const float* xr = x + (size_t)s * DMODEL;
  float4 v = *(const float4*)(xr + tid * 4);
  float ss = v.x * v.x + v.y * v.y + v.z * v.z + v.w * v.w;
#pragma unroll
  for (int off = 32; off > 0; off >>= 1) ss += __shfl_down(ss, off);
  __shared__ float red[4];
  if ((tid & 63) == 0) red[tid >> 6] = ss;
  __syncthreads();
  float tot = red[0] + red[1] + red[2] + red[3];
  float scale = rsqrtf(tot * (1.0f / DMODEL) + 1e-6f);
  float4 wv = *(const float4*)(w + tid * 4);
  u16x4 ub;
  ub[0] = bf_us(v.x * scale * wv.x);
  ub[1] = bf_us(v.y * scale * wv.y);
  ub[2] = bf_us(v.z * scale * wv.z);
  ub[3] = bf_us(v.w * scale * wv.w);
  *(u16x4*)(outb + (size_t)s * DMODEL + tid * 4) = ub;
}

// ---------------- weight convert f32 -> bf16: both layers + LM head --------------
__global__ __launch_bounds__(256) void wcvt8_kernel(
    const float* __restrict__ Wq, const float* __restrict__ Wk,
    const float* __restrict__ Wv, const float* __restrict__ Wog,
    const float* __restrict__ Wout, const float* __restrict__ Wg,
    const float* __restrict__ Wu, const float* __restrict__ Wd,
    const float* __restrict__ Wlm,
    unsigned short* __restrict__ W, unsigned short* __restrict__ Wlm16) {
  const size_t de = ((size_t)blockIdx.x * 256 + threadIdx.x) * 8;
  if (de >= 2ull * WLAYER) {  // LM head region
    size_t i = de - 2ull * WLAYER;
    float4 a0 = *(const float4*)(Wlm + i);
    float4 a1 = *(const float4*)(Wlm + i + 4);
    u16x8 o;
    o[0] = bf_us(a0.x); o[1] = bf_us(a0.y); o[2] = bf_us(a0.z); o[3] = bf_us(a0.w);
    o[4] = bf_us(a1.x); o[5] = bf_us(a1.y); o[6] = bf_us(a1.z); o[7] = bf_us(a1.w);
    *(u16x8*)(Wlm16 + i) = o;
    return;
  }
  int e = (int)de, l = 0;
  if (e >= WLAYER) { l = 1; e -= WLAYER; }
  const float* src = nullptr;
  size_t idx = 0;
  if (e < 524288)       { src = Wq  + (size_t)l * 524288;  idx = e; }
  else if (e < 1048576) { src = Wk  + (size_t)l * 524288;  idx = e - 524288; }
  else if (e < 2097152) { src = Wv  + (size_t)l * 1048576; idx = e - 1048576; }
  else if (e < 3145728) { src = Wog + (size_t)l * 1048576; idx = e - 2097152; }
  else if (e < 4194304) { src = Wout + (size_t)l * 1048576; idx = e - 3145728; }
  else if (e < 7077888) {
    int t = e - 4194304, row = t >> 10;
    if (row < 2752) { src = Wg + (size_t)l * 2818048; idx = t; }
  } else if (e < 9961472) {
    int t = e - 7077888, row = t >> 10;
    if (row < 2752) { src = Wu + (size_t)l * 2818048; idx = t; }
  } else {
    int t = e - 9961472, row = t / 2816, col = t - row * 2816;
    if (col < 2752) { src = Wd + (size_t)l * 2818048; idx = row * 2752 + col; }
  }
  u16x8 o;
  if (src) {
    float4 a0 = *(const float4*)(src + idx);
    float4 a1 = *(const float4*)(src + idx + 4);
    o[0] = bf_us(a0.x); o[1] = bf_us(a0.y); o[2] = bf_us(a0.z); o[3] = bf_us(a0.w);
    o[4] = bf_us(a1.x); o[5] = bf_us(a1.y); o[6] = bf_us(a1.z); o[7] = bf_us(a1.w);
  } else {
#pragma unroll
    for (int k = 0; k < 8; ++k) o[k] = 0;
  }
  *(u16x8*)(W + de) = o;
}

// ---------------- GEMM core: 128x128 tile, BK=32, 3-buffer pipeline ----------------
// lm256-cloned schedule: vmcnt(4) -> s_barrier -> stage(t+2) -> 8 ds_read + 16 MFMA.
// Buffer t%3; 4 global_load_lds per tile (2 per matrix); tail vmcnt(0).
// EPI: 0 f32 store | 1 f32 acc+X residual
template <int EPI>
__global__ __launch_bounds__(256) void gemm_bb_kernel(
    const unsigned short* __restrict__ A, const unsigned short* __restrict__ B,
    const void* Xv, void* Cv, int K, int ldc) {
  __shared__ __align__(16) unsigned short SH[3 * 8192];  // 3 x (A 128x32 | B 128x32)
  const int tid = threadIdx.x;
  const int wave = tid >> 6, lane = tid & 63;
  const int gx = gridDim.x;
  const int nwg = gx * gridDim.y;
  const int d = blockIdx.y * gx + blockIdx.x;
  const int q = nwg >> 3;
  const int lgc = (d & 7) * q + (d >> 3);
  const int bm = (lgc % gx) * 128, bn = (lgc / gx) * 128;
  const int wr = (wave >> 1) * 64, wc = (wave & 1) * 64;
  const int lr = lane & 15, lhi = lane >> 4;
  const unsigned short* Ab = A + (size_t)bm * K;
  const unsigned short* Bb = B + (size_t)bn * K;
  f32x4v acc[4][4] = {};

  auto stageT = [&](int tau) {
    unsigned short* base = SH + (tau % 3) * 8192;
    stage32(Ab, K, base, wave, lane, tau * 32);
    stage32(Bb, K, base + 4096, wave, lane, tau * 32);
  };

  const int NT = K >> 5;
  stageT(0);
  stageT(1);
  for (int t = 0; t < NT; ++t) {
    if (t < NT - 1) asm volatile("s_waitcnt vmcnt(4)" ::: "memory");
    else            asm volatile("s_waitcnt vmcnt(0)" ::: "memory");
    asm volatile("s_barrier" ::: "memory");
    if (t + 2 < NT) stageT(t + 2);
    const unsigned short* Al = SH + (t % 3) * 8192;
    const unsigned short* Bl = Al + 4096;
    bf16x8 af[4], bfr[4];
#pragma unroll
    for (int mi = 0; mi < 4; ++mi) {
      int row = wr + mi * 16 + lr;
      af[mi] = *(const bf16x8*)&Al[row * 32 + ((lhi ^ ((row >> 1) & 3)) << 3)];
    }
#pragma unroll
    for (int ni = 0; ni < 4; ++ni) {
      int row = wc + ni * 16 + lr;
      bfr[ni] = *(const bf16x8*)&Bl[row * 32 + ((lhi ^ ((row >> 1) & 3)) << 3)];
    }
    __builtin_amdgcn_s_setprio(1);
#pragma unroll
    for (int mi = 0; mi < 4; ++mi)
#pragma unroll
      for (int ni = 0; ni < 4; ++ni)
        acc[mi][ni] = __builtin_amdgcn_mfma_f32_16x16x32_bf16(af[mi], bfr[ni], acc[mi][ni], 0, 0, 0);
    __builtin_amdgcn_s_setprio(0);
  }
#pragma unroll
  for (int mi = 0; mi < 4; ++mi) {
#pragma unroll
    for (int ni = 0; ni < 4; ++ni) {
#pragma unroll
      for (int j = 0; j < 4; ++j) {
        int row = bm + wr + mi * 16 + lhi * 4 + j;   // C/D layout (m89)
        int col = bn + wc + ni * 16 + lr;
        float v = acc[mi][ni][j];
        if (EPI == 0)
          ((float*)Cv)[(size_t)row * ldc + col] = v;
        if (EPI == 1)
          ((float*)Cv)[(size_t)row * ldc + col] = v + ((const float*)Xv)[(size_t)row * ldc + col];
      }
    }
  }
}

// ---------------- LM head GEMM: 256x256 tile, 8 waves, BK=32, 3-buffer pipeline ---
// Round-11 proven configuration (181 us).
__global__ __launch_bounds__(512, 2) void lm256_kernel(
    const unsigned short* __restrict__ A, const unsigned short* __restrict__ B,
    float* __restrict__ C) {
  __shared__ __align__(16) unsigned short SH[3 * 16384];  // 3 x (A 256x32 | B 256x32)
  const int K = 1024, N = 32000, NT = 32;
  const int tid = threadIdx.x;
  const int wave = tid >> 6, lane = tid & 63;
  const int lr = lane & 15, lg = lane >> 4;
  const int wm = wave >> 2, wn = wave & 3;     // 2M x 4N waves, 128x64 each
  const int d = blockIdx.y * 8 + blockIdx.x;
  const int lgc = (d & 7) * 125 + (d >> 3);
  const int bm = (lgc & 7) * 256;
  const int bn = (lgc >> 3) * 256;
  const unsigned short* Ab = A + (size_t)bm * K;
  const unsigned short* Bb = B + (size_t)bn * K;

  auto stageM = [&](const unsigned short* gbase, unsigned short* lds, int k0) {
#pragma unroll
    for (int j = 0; j < 2; ++j) {
      const int r = j * 128 + wave * 16 + (lane >> 2);
      const int cg = (lane & 3) ^ ((r >> 1) & 3);
      const unsigned short* src = gbase + (size_t)r * K + k0 + cg * 8;
      __builtin_amdgcn_global_load_lds((const AS_G void*)src,
                                       (AS_L void*)(lds + (j * 128 + wave * 16) * 32), 16, 0, 0);
    }
  };
  auto stageT = [&](int tau) {
    unsigned short* base = SH + (tau % 3) * 16384;
    stageM(Ab, base, tau * 32);
    stageM(Bb, base + 8192, tau * 32);
  };

  f32x4v acc[8][4] = {};
  stageT(0);
  stageT(1);
  for (int t = 0; t < NT; ++t) {
    if (t < NT - 1) asm volatile("s_waitcnt vmcnt(4)" ::: "memory");
    else            asm volatile("s_waitcnt vmcnt(0)" ::: "memory");
    asm volatile("s_barrier" ::: "memory");
    if (t + 2 < NT) stageT(t + 2);
    const unsigned short* Al = SH + (t % 3) * 16384;
    const unsigned short* Bl = Al + 8192;
    bf16x8 bfr[4];
#pragma unroll
    for (int ni = 0; ni < 4; ++ni) {
      int row = wn * 64 + ni * 16 + lr;
      bfr[ni] = *(const bf16x8*)&Bl[row * 32 + ((lg ^ ((row >> 1) & 3)) << 3)];
    }
#pragma unroll
    for (int mi = 0; mi < 8; ++mi) {
      int row = wm * 128 + mi * 16 + lr;
      bf16x8 af = *(const bf16x8*)&Al[row * 32 + ((lg ^ ((row >> 1) & 3)) << 3)];
      __builtin_amdgcn_s_setprio(1);
#pragma unroll
      for (int ni = 0; ni < 4; ++ni)
        acc[mi][ni] = __builtin_amdgcn_mfma_f32_16x16x32_bf16(af, bfr[ni], acc[mi][ni], 0, 0, 0);
      __builtin_amdgcn_s_setprio(0);
    }
  }
#pragma unroll
  for (int mi = 0; mi < 8; ++mi)
#pragma unroll
    for (int ni = 0; ni < 4; ++ni)
#pragma unroll
      for (int jj = 0; jj < 4; ++jj) {
        int row = bm + wm * 128 + mi * 16 + lg * 4 + jj;
        int col = bn + wn * 64 + ni * 16 + lr;
        C[(size_t)row * N + col] = fast_softcap30(acc[mi][ni][jj]);
      }
}

// ---------------- fused QKV+OG GEMM (pipelined BK=32) ----------------
__global__ __launch_bounds__(256) void qkvo_kernel(
    const unsigned short* __restrict__ A, const unsigned short* __restrict__ Wq16,
    const unsigned short* __restrict__ Wk16, const unsigned short* __restrict__ Wv16,
    const unsigned short* __restrict__ Wog16,
    unsigned short* __restrict__ qb, unsigned short* __restrict__ kb,
    unsigned short* __restrict__ vTb, float* __restrict__ og) {
  __shared__ __align__(16) unsigned short SH[3 * 8192];  // 48 KB (also vT transpose buf)
  const int tid = threadIdx.x;
  const int wave = tid >> 6, lane = tid & 63;
  const int gx = gridDim.x;                 // 16 (M)
  const int nwg = gx * gridDim.y;           // 384
  const int dd = blockIdx.y * gx + blockIdx.x;
  const int qq = nwg >> 3;
  const int lgc = (dd & 7) * qq + (dd >> 3);
  const int bm = (lgc % gx) * 128;
  const int by = lgc / gx;
  const unsigned short* B;
  int bnl, mode;
  if (by < 4)       { B = Wq16;  bnl = by * 128;        mode = 0; }
  else if (by < 8)  { B = Wk16;  bnl = (by - 4) * 128;  mode = 1; }
  else if (by < 16) { B = Wv16;  bnl = (by - 8) * 128;  mode = 2; }
  else              { B = Wog16; bnl = (by - 16) * 128; mode = 3; }
  const int K = 1024;
  const int wr = (wave >> 1) * 64, wc = (wave & 1) * 64;
  const int lr = lane & 15, lhi = lane >> 4;
  const unsigned short* Ab = A + (size_t)bm * K;
  const unsigned short* Bb = B + (size_t)bnl * K;
  f32x4v acc[4][4] = {};

  auto stageT = [&](int tau) {
    unsigned short* base = SH + (tau % 3) * 8192;
    stage32(Ab, K, base, wave, lane, tau * 32);
    stage32(Bb, K, base + 4096, wave, lane, tau * 32);
  };

  const int NT = 32;
  stageT(0);
  stageT(1);
  for (int t = 0; t < NT; ++t) {
    if (t < NT - 1) asm volatile("s_waitcnt vmcnt(4)" ::: "memory");
    else            asm volatile("s_waitcnt vmcnt(0)" ::: "memory");
    asm volatile("s_barrier" ::: "memory");
    if (t + 2 < NT) stageT(t + 2);
    const unsigned short* Al = SH + (t % 3) * 8192;
    const unsigned short* Bl = Al + 4096;
    bf16x8 af[4], bfr[4];
#pragma unroll
    for (int mi = 0; mi < 4; ++mi) {
      int row = wr + mi * 16 + lr;
      af[mi] = *(const bf16x8*)&Al[row * 32 + ((lhi ^ ((row >> 1) & 3)) << 3)];
    }
#pragma unroll
    for (int ni = 0; ni < 4; ++ni) {
      int row = wc + ni * 16 + lr;
      bfr[ni] = *(const bf16x8*)&Bl[row * 32 + ((lhi ^ ((row >> 1) & 3)) << 3)];
    }
    __builtin_amdgcn_s_setprio(1);
#pragma unroll
    for (int mi = 0; mi < 4; ++mi)
#pragma unroll
      for (int ni = 0; ni < 4; ++ni)
        acc[mi][ni] = __builtin_amdgcn_mfma_f32_16x16x32_bf16(af[mi], bfr[ni], acc[mi][ni], 0, 0, 0);
    __builtin_amdgcn_s_setprio(0);
  }
  if (mode == 2) {
    __syncthreads();  // all waves done reading staging buffers before SH reuse
#pragma unroll
    for (int mi = 0; mi < 4; ++mi)
#pragma unroll
      for (int ni = 0; ni < 4; ++ni)
#pragma unroll
        for (int j = 0; j < 4; ++j) {
          int row = wr + mi * 16 + lhi * 4 + j;
          int col = wc + ni * 16 + lr;
          int byte = col * 256 + ((((row >> 3) ^ (col & 7)) << 4)) + (row & 7) * 2;
          *(unsigned short*)((char*)SH + byte) = bf_us(acc[mi][ni][j]);
        }
    __syncthreads();
#pragma unroll
    for (int i = 0; i < 8; ++i) {
      int c = i * 16 + (tid >> 4);
      int rg = tid & 15;
      u16x8 u = *(const u16x8*)((const char*)SH + c * 256 + ((rg ^ (c & 7)) << 4));
      *(u16x8*)(vTb + (size_t)(bnl + c) * S_LEN + bm + rg * 8) = u;
    }
  } else {
#pragma unroll
    for (int mi = 0; mi < 4; ++mi)
#pragma unroll
      for (int ni = 0; ni < 4; ++ni)
#pragma unroll
        for (int j = 0; j < 4; ++j) {
          int row = bm + wr + mi * 16 + lhi * 4 + j;
          int col = bnl + wc + ni * 16 + lr;
          if (mode == 0)      qb[(size_t)row * 512 + col] = bf_us(acc[mi][ni][j]);
          else if (mode == 1) kb[(size_t)row * 512 + col] = bf_us(acc[mi][ni][j]);
          else                og[(size_t)row * 1024 + col] = acc[mi][ni][j];
        }
  }
}

// ---------------- fused FFN gate+up GEMM: Gb = silu(A Wg^T) * (A Wu^T), bf16 -------
__global__ __launch_bounds__(256) void ffn_kernel(
    const unsigned short* __restrict__ A, const unsigned short* __restrict__ Bg,
    const unsigned short* __restrict__ Bu, unsigned short* __restrict__ Gb) {
  __shared__ __align__(16) unsigned short As[128 * 64];
  __shared__ __align__(16) unsigned short Bgs[128 * 64];
  __shared__ __align__(16) unsigned short Bus[128 * 64];
  const int K = 1024;
  const int tid = threadIdx.x;
  const int wave = tid >> 6, lane = tid & 63;
  const int gx = gridDim.x;                 // 16
  const int nwg = gx * gridDim.y;           // 352
  const int dd = blockIdx.y * gx + blockIdx.x;
  const int qq = nwg >> 3;
  const int lgc = (dd & 7) * qq + (dd >> 3);
  const int bm = (lgc % gx) * 128;
  const int bn = (lgc / gx) * 128;
  const int wr = (wave >> 1) * 64, wc = (wave & 1) * 64;
  const int lr = lane & 15, lhi = lane >> 4;
  const unsigned short* Ab = A + (size_t)bm * K;
  const unsigned short* Bgb = Bg + (size_t)bn * K;
  const unsigned short* Bub = Bu + (size_t)bn * K;
  f32x4v accg[4][4] = {};
  f32x4v accu[4][4] = {};
  for (int it = 0; it < 16; ++it) {
    stage64(Ab, K, As, wave, lane, it << 6);
    stage64(Bgb, K, Bgs, wave, lane, it << 6);
    stage64(Bub, K, Bus, wave, lane, it << 6);
    __syncthreads();
#pragma unroll
    for (int kk = 0; kk < 2; ++kk) {
      const int sw = (((kk * 4 + lhi) ^ (lr & 7)) << 3);
      bf16x8 af[4], bg[4], bu[4];
#pragma unroll
      for (int mi = 0; mi < 4; ++mi) af[mi] = *(const bf16x8*)&As[(wr + mi * 16 + lr) * 64 + sw];
#pragma unroll
      for (int ni = 0; ni < 4; ++ni) bg[ni] = *(const bf16x8*)&Bgs[(wc + ni * 16 + lr) * 64 + sw];
#pragma unroll
      for (int ni = 0; ni < 4; ++ni) bu[ni] = *(const bf16x8*)&Bus[(wc + ni * 16 + lr) * 64 + sw];
#pragma unroll
      for (int mi = 0; mi < 4; ++mi)
#pragma unroll
        for (int ni = 0; ni < 4; ++ni) {
          accg[mi][ni] = __builtin_amdgcn_mfma_f32_16x16x32_bf16(af[mi], bg[ni], accg[mi][ni], 0, 0, 0);
          accu[mi][ni] = __builtin_amdgcn_mfma_f32_16x16x32_bf16(af[mi], bu[ni], accu[mi][ni], 0, 0, 0);
        }
    }
    __syncthreads();
  }
#pragma unroll
  for (int mi = 0; mi < 4; ++mi) {
#pragma unroll
    for (int ni = 0; ni < 4; ++ni) {
#pragma unroll
      for (int j = 0; j < 4; ++j) {
        int row = bm + wr + mi * 16 + lhi * 4 + j;
        int col = bn + wc + ni * 16 + lr;
        float g = accg[mi][ni][j];
        float sv = g * fast_sigmoid(g) * accu[mi][ni][j];
        Gb[(size_t)row * 2816 + col] = bf_us(sv);
      }
    }
  }
}

// ---------------- gate pre-activations (inline rmsnorm from f32 x) ----------------
__global__ __launch_bounds__(256) void gates_kernel(
    const float* __restrict__ x, const float* __restrict__ n1,
    const float* __restrict__ Wi, const float* __restrict__ bi,
    const float* __restrict__ Wf, const float* __restrict__ bfv,
    float* __restrict__ ipre, float* __restrict__ fpre) {
  int s = blockIdx.x;
  int head = threadIdx.x >> 6, lane = threadIdx.x & 63;
  const float* xr = x + (size_t)s * DMODEL;
  float xv[16];
  float ss = 0.f;
#pragma unroll
  for (int j = 0; j < 16; ++j) { xv[j] = xr[lane + j * 64]; ss += xv[j] * xv[j]; }
#pragma unroll
  for (int off = 32; off > 0; off >>= 1) ss += __shfl_xor(ss, off);
  float scale = rsqrtf(ss * (1.0f / DMODEL) + 1e-6f);
  const float* wi = Wi + head * DMODEL;
  const float* wf = Wf + head * DMODEL;
  float si = 0.f, sf = 0.f;
#pragma unroll
  for (int j = 0; j < 16; ++j) {
    int c = lane + j * 64;
    float xm = xv[j] * scale * n1[c];
    si += xm * wi[c];
    sf += xm * wf[c];
  }
#pragma unroll
  for (int off = 32; off > 0; off >>= 1) {
    si += __shfl_down(si, off);
    sf += __shfl_down(sf, off);
  }
  if (lane == 0) {
    ipre[head * S_LEN + s] = 15.0f * tanhf((si + bi[head]) * (1.0f / 15.0f));
    fpre[head * S_LEN + s] = 15.0f * tanhf((sf + bfv[head]) * (1.0f / 15.0f));
  }
}

// ---------------- per-head scan ----------------
__global__ __launch_bounds__(256) void scan_kernel(
    const float* __restrict__ ipre, const float* __restrict__ fpre,
    float* __restrict__ garr, float* __restrict__ Marr, float* __restrict__ earr) {
  const int h = threadIdx.x >> 6;
  const int lane = threadIdx.x & 63;
  const int base = h * S_LEN + lane * 32;
  float lf[32];
  float lsum = 0.f;
#pragma unroll
  for (int e = 0; e < 32; ++e) {
    float f = fpre[base + e];
    float v = fminf(f, 0.f) - log1pf(expf(-fabsf(f)));
    lf[e] = v;
    lsum += v;
  }
  float scan = lsum;
#pragma unroll
  for (int off = 1; off < 64; off <<= 1) {
    float t = __shfl_up(scan, off);
    if (lane >= off) scan += t;
  }
  float F0 = scan - lsum;
  float gv[32];
  float F = F0, lmax = -1e30f;
#pragma unroll
  for (int e = 0; e < 32; ++e) {
    F += lf[e];
    float g = ipre[base + e] - F;
    gv[e] = g;
    lmax = fmaxf(lmax, g);
    garr[base + e] = g;
  }
  float ms = lmax;
#pragma unroll
  for (int off = 1; off < 64; off <<= 1) {
    float t = __shfl_up(ms, off);
    if (lane >= off) ms = fmaxf(ms, t);
  }
  float em = __shfl_up(ms, 1);
  if (lane == 0) em = -1e30f;
  float run = em;
  F = F0;
#pragma unroll
  for (int e = 0; e < 32; ++e) {
    F += lf[e];
    run = fmaxf(run, gv[e]);
    Marr[base + e] = run;
    earr[base + e] = expf(-(F + run));
  }
}

// ---------------- mLSTM parallel, bf16 MFMA flash-style, s-split x4 ----------------
__global__ __launch_bounds__(256) void mlstm_mfma_kernel(
    const unsigned short* __restrict__ Q, const unsigned short* __restrict__ Kb,
    const unsigned short* __restrict__ vT, const float* __restrict__ garr,
    const float* __restrict__ Marr,
    float* __restrict__ hp, float* __restrict__ npart) {
  const int h = blockIdx.y;
  const int T = blockIdx.x;
  const int sp = blockIdx.z;
  float* hpart = hp + (size_t)sp * 2097152;
  const int tid = threadIdx.x;
  const int w = tid >> 6, l = tid & 63;
  const int lr = l & 15, lg = l >> 4;
  const int hbase = h * S_LEN;
  const int sr = tid >> 4;
  const int sc = tid & 15;

  __shared__ __align__(16) unsigned short Ks[64 * 128];
  __shared__ __align__(16) unsigned short Vs[256 * 64];
  __shared__ __align__(16) unsigned short Ps[64 * 64];

  bf16x8 qf[4];
  {
    const unsigned short* qrow = Q + (size_t)(T * 64 + w * 16 + lr) * 512 + h * 128 + lg * 8;
#pragma unroll
    for (int kt = 0; kt < 4; ++kt) {
      cvu c;
      c.u = *(const u16x8*)(qrow + kt * 32);
      qf[kt] = c.b;
    }
  }
  float Mt[4];
#pragma unroll
  for (int j = 0; j < 4; ++j) Mt[j] = Marr[hbase + T * 64 + w * 16 + lg * 4 + j];

  f32x4v pv[16] = {};
  float nacc[4] = {0.f, 0.f, 0.f, 0.f};
  const float rs = 0.08838834764831845f;  // 1/sqrt(128)

  for (int ch = sp; ch <= T; ch += 4) {
    const int s0 = ch * 64;
    __syncthreads();
#pragma unroll
    for (int i = 0; i < 4; ++i) {
      int r = i * 16 + sr;
      u16x8 u = *(const u16x8*)(Kb + (size_t)(s0 + r) * 512 + h * 128 + sc * 8);
      int byte = r * 256 + ((sc * 16) ^ ((r & 7) << 4));
      *(u16x8*)((char*)Ks + byte) = u;
    }
#pragma unroll
    for (int i = 0; i < 16; ++i) {
      int r = i * 16 + sr;
      u16x4 u = *(const u16x4*)(vT + (size_t)(h * 256 + r) * S_LEN + s0 + sc * 4);
      int byte = r * 128 + ((sc * 8) ^ ((r & 7) << 4));
      *(u16x4*)((char*)Vs + byte) = u;
    }
    __syncthreads();
    f32x4v sa[4] = {};
#pragma unroll
    for (int ni = 0; ni < 4; ++ni) {
#pragma unroll
      for (int kt = 0; kt < 4; ++kt) {
        int row = ni * 16 + lr;
        int byte = row * 256 + (((kt * 32 + lg * 8) * 2) ^ ((row & 7) << 4));
        bf16x8 kf = ld_bf8(Ks, byte);
        sa[ni] = __builtin_amdgcn_mfma_f32_16x16x32_bf16(qf[kt], kf, sa[ni], 0, 0, 0);
      }
    }
#pragma unroll
    for (int ni = 0; ni < 4; ++ni) {
      int sl = ni * 16 + lr;
      int sg = s0 + sl;
      float gv = garr[hbase + sg];
#pragma unroll
      for (int j = 0; j < 4; ++j) {
        int tloc = w * 16 + lg * 4 + j;
        int tg = T * 64 + tloc;
        float wgt = (sg <= tg) ? __expf(gv - Mt[j]) : 0.f;
        float val = sa[ni][j] * rs * wgt;
        nacc[j] += val;
        int byte = tloc * 128 + ((sl * 2) ^ ((tloc & 7) << 4));
        *(unsigned short*)((char*)Ps + byte) = bf_us(val);
      }
    }
#pragma unroll
    for (int kt2 = 0; kt2 < 2; ++kt2) {
      int tloc = w * 16 + lr;
      int sb = (kt2 * 32 + lg * 8) * 2;
      bf16x8 pa = ld_bf8(Ps, tloc * 128 + (sb ^ ((tloc & 7) << 4)));
#pragma unroll
      for (int nv = 0; nv < 16; ++nv) {
        int dv = nv * 16 + lr;
        bf16x8 vb = ld_bf8(Vs, dv * 128 + (sb ^ ((dv & 7) << 4)));
        pv[nv] = __builtin_amdgcn_mfma_f32_16x16x32_bf16(pa, vb, pv[nv], 0, 0, 0);
      }
    }
  }
#pragma unroll
  for (int j = 0; j < 4; ++j) {
#pragma unroll
    for (int off = 1; off < 16; off <<= 1) nacc[j] += __shfl_xor(nacc[j], off);
  }
#pragma unroll
  for (int j = 0; j < 4; ++j) {
    int tg = T * 64 + w * 16 + lg * 4 + j;
    if (lr == 0) npart[sp * 8192 + hbase + tg] = nacc[j];
    float* orow = hpart + (size_t)tg * DMODEL + h * 256;
#pragma unroll
    for (int nvt = 0; nvt < 16; ++nvt) orow[nvt * 16 + lr] = pv[nvt][j];
  }
}

// ---------------- combine(4) + multihead LayerNorm * mhw * sigmoid(og) -> bf16 ----
__global__ __launch_bounds__(256) void mhln_gate_kernel(
    const float* __restrict__ hp, const float* __restrict__ npart,
    const float* __restrict__ earr, const float* __restrict__ mhw,
    const float* __restrict__ og, unsigned short* __restrict__ gact) {
  int s = blockIdx.x;
  int head = threadIdx.x >> 6, lane = threadIdx.x & 63;
  float n = (npart[head * S_LEN + s] + npart[8192 + head * S_LEN + s]) +
            (npart[16384 + head * S_LEN + s] + npart[24576 + head * S_LEN + s]);
  float nvv = fmaxf(fabsf(n), earr[head * S_LEN + s]);
  float inv = 1.0f / (nvv + 1e-6f);
  const size_t base = (size_t)s * DMODEL + head * 256;
  float vq[4];
#pragma unroll
  for (int qy = 0; qy < 4; ++qy) {
    size_t o = base + qy * 64 + lane;
    vq[qy] = ((hp[o] + hp[o + 2097152]) + (hp[o + 4194304] + hp[o + 6291456])) * inv;
  }
  float sum = vq[0] + vq[1] + vq[2] + vq[3];
#pragma unroll
  for (int off = 32; off > 0; off >>= 1) sum += __shfl_xor(sum, off);
  float mu = sum * (1.0f / 256.0f);
  float d0 = vq[0] - mu, d1 = vq[1] - mu, d2 = vq[2] - mu, d3 = vq[3] - mu;
  float vs = d0 * d0 + d1 * d1 + d2 * d2 + d3 * d3;
#pragma unroll
  for (int off = 32; off > 0; off >>= 1) vs += __shfl_xor(vs, off);
  float rstd = rsqrtf(vs * (1.0f / 256.0f) + 1e-6f);
  float dn[4] = {d0, d1, d2, d3};
#pragma unroll
  for (int qy = 0; qy < 4; ++qy) {
    int c = head * 256 + qy * 64 + lane;
    float ov = og[(size_t)s * DMODEL + c];
    gact[(size_t)s * DMODEL + c] = bf_us(dn[qy] * rstd * mhw[c] * fast_sigmoid(ov));
  }
}

extern "C" void kernel_launch(void* const* d_in, const int* in_sizes, int n_in,
                              void* d_out, int out_size, void* d_ws, size_t ws_size,
                              hipStream_t stream) {
  (void)in_sizes; (void)n_in; (void)out_size; (void)ws_size;
  const int*   tok   = (const int*)d_in[0];
  const float* emb   = (const float*)d_in[1];
  const float* norm1 = (const float*)d_in[2];
  const float* Wq    = (const float*)d_in[3];
  const float* Wk    = (const float*)d_in[4];
  const float* Wv    = (const float*)d_in[5];
  const float* Wog   = (const float*)d_in[6];
  const float* Wi    = (const float*)d_in[7];
  const float* bi    = (const float*)d_in[8];
  const float* Wf    = (const float*)d_in[9];
  const float* bfp   = (const float*)d_in[10];
  const float* mhw   = (const float*)d_in[11];
  const float* Wout  = (const float*)d_in[12];
  const float* norm2 = (const float*)d_in[13];
  const float* Wg    = (const float*)d_in[14];
  const float* Wu    = (const float*)d_in[15];
  const float* Wd    = (const float*)d_in[16];
  const float* onw   = (const float*)d_in[17];
  const float* Wlm   = (const float*)d_in[18];

  char* wsb = (char*)d_ws;
  const size_t MB = 1ull << 20;
  float*          x    = (float*)wsb;                          // 8 MiB
  unsigned short* xmb  = (unsigned short*)(wsb + 8 * MB);      // 4 MiB
  float*          ipre = (float*)(wsb + 12 * MB);              // scalars region
  float*          fpre = ipre + 8192;
  float*          garr = fpre + 8192;
  float*          Marr = garr + 8192;
  float*          earr = Marr + 8192;
  float*          npart = earr + 8192;                         // 4 x 32 KiB
  unsigned short* W16  = (unsigned short*)(wsb + 13 * MB);     // 49 MiB -> ends 62
  const size_t OQ = 0, OKk = 524288, OV = 1048576, OOG = 2097152, OOUT = 3145728,
               OGt = 4194304, OU = 7077888, OD = 9961472;
  unsigned short* qb    = (unsigned short*)(wsb + 62 * MB);    // 2 MiB
  unsigned short* kb    = (unsigned short*)(wsb + 64 * MB);    // 2 MiB
  unsigned short* vTb   = (unsigned short*)(wsb + 66 * MB);    // 4 MiB
  float*          og    = (float*)(wsb + 70 * MB);             // 8 MiB
  float*          hp    = (float*)(wsb + 78 * MB);             // 4 x 8 MiB -> ends 110
  unsigned short* gact  = (unsigned short*)(wsb + 110 * MB);   // 4 MiB
  unsigned short* Gb16  = (unsigned short*)(wsb + 114 * MB);   // 11 MiB -> ends 125
  unsigned short* wlm16 = (unsigned short*)(wsb + 126 * MB);   // 62.5 MiB -> ends 188.5

  embed_kernel<<<2048, 256, 0, stream>>>(tok, emb, x);
  wcvt8_kernel<<<28544, 256, 0, stream>>>(Wq, Wk, Wv, Wog, Wout, Wg, Wu, Wd, Wlm,
                                          W16, wlm16);

  for (int l = 0; l < 2; ++l) {
    const unsigned short* Wl = W16 + (size_t)l * WLAYER;
    const float* n1   = norm1 + (size_t)l * 1024;
    const float* wiv  = Wi   + (size_t)l * 4 * 1024;
    const float* bil  = bi   + (size_t)l * 4;
    const float* wfv  = Wf   + (size_t)l * 4 * 1024;
    const float* bfl  = bfp  + (size_t)l * 4;
    const float* mhwl = mhw  + (size_t)l * 1024;
    const float* n2   = norm2 + (size_t)l * 1024;

    rmsnorm_kernel<<<2048, 256, 0, stream>>>(x, n1, xmb);
    qkvo_kernel<<<dim3(16, 24), 256, 0, stream>>>(xmb, Wl + OQ, Wl + OKk, Wl + OV,
                                                  Wl + OOG, qb, kb, vTb, og);
    gates_kernel<<<2048, 256, 0, stream>>>(x, n1, wiv, bil, wfv, bfl, ipre, fpre);
    scan_kernel<<<1, 256, 0, stream>>>(ipre, fpre, garr, Marr, earr);
    mlstm_mfma_kernel<<<dim3(32, 4, 4), 256, 0, stream>>>(qb, kb, vTb, garr, Marr,
                                                          hp, npart);
    mhln_gate_kernel<<<2048, 256, 0, stream>>>(hp, npart, earr, mhwl, og, gact);
    gemm_bb_kernel<1><<<dim3(16, 8), 256, 0, stream>>>(gact, Wl + OOUT, x, x, 1024, 1024);
    rmsnorm_kernel<<<2048, 256, 0, stream>>>(x, n2, xmb);
    ffn_kernel<<<dim3(16, 22), 256, 0, stream>>>(xmb, Wl + OGt, Wl + OU, Gb16);
    gemm_bb_kernel<1><<<dim3(16, 8), 256, 0, stream>>>(Gb16, Wl + OD, x, x, 2816, 1024);
  }

  rmsnorm_kernel<<<2048, 256, 0, stream>>>(x, onw, xmb);
  lm256_kernel<<<dim3(8, 125), 512, 0, stream>>>(xmb, wlm16, (float*)d_out);
}

// Round 17
// 724.232 us; speedup vs baseline: 1.2170x; 1.0097x over previous
//
#include <hip/hip_runtime.h>
#include <hip/hip_bf16.h>
#include <math.h>

// xLSTM-Large forward: S=2048, D=1024, NH=4 (Dqk=128, Dv=256), UP=2752, L=2, V=32000.
// All GEMMs now on the proven BK=32 / 3-buffer / counted-vmcnt pipeline
// (lm256 vmcnt(4); gemm_bb/qkvo vmcnt(4); ffn 3-matrix vmcnt(6)).

#define S_LEN 2048
#define DMODEL 1024
#define WLAYER 12845056  // elements per layer in W16

typedef __attribute__((ext_vector_type(8))) __bf16 bf16x8;
typedef __attribute__((ext_vector_type(8))) unsigned short u16x8;
typedef __attribute__((ext_vector_type(4))) unsigned short u16x4;
typedef __attribute__((ext_vector_type(4))) float f32x4v;

union cvu { u16x8 u; bf16x8 b; };

__device__ __forceinline__ unsigned short bf_us(float f) {
  union { __bf16 b; unsigned short u; } c;
  c.b = (__bf16)f;   // RNE, native v_cvt on gfx950
  return c.u;
}
__device__ __forceinline__ float us_f(unsigned short u) {
  union { __bf16 b; unsigned short u; } c;
  c.u = u;
  return (float)c.b;
}
__device__ __forceinline__ bf16x8 ld_bf8(const unsigned short* p, int byte_off) {
  cvu c;
  c.u = *(const u16x8*)((const char*)p + byte_off);
  return c.b;
}
__device__ __forceinline__ float fast_sigmoid(float v) {
  return 1.0f / (1.0f + __expf(-v));
}
__device__ __forceinline__ float fast_softcap30(float v) {
  float e = __expf(-fabsf(v) * (1.0f / 15.0f));  // e^{-2|v|/30}
  float t = (1.0f - e) / (1.0f + e);             // tanh(|v|/30)
  return copysignf(30.0f * t, v);
}

#define AS_G __attribute__((address_space(1)))
#define AS_L __attribute__((address_space(3)))

// Stage a 128x32 bf16 tile (8 KB) into linear LDS: 2 issues of 4 KB (64 rows).
// Source col-group pre-swizzled (cg ^= (row>>1)&3); matching XOR on read.
__device__ __forceinline__ void stage32(const unsigned short* gbase, int K,
                                        unsigned short* lds, int wave, int lane, int k0) {
#pragma unroll
  for (int j = 0; j < 2; ++j) {
    const int r = j * 64 + wave * 16 + (lane >> 2);
    const int cg = (lane & 3) ^ ((r >> 1) & 3);
    const unsigned short* src = gbase + (size_t)r * K + k0 + cg * 8;
    __builtin_amdgcn_global_load_lds((const AS_G void*)src,
                                     (AS_L void*)(lds + (j * 64 + wave * 16) * 32), 16, 0, 0);
  }
}

// ---------------- embed ----------------
__global__ __launch_bounds__(256) void embed_kernel(
    const int* __restrict__ tok, const float* __restrict__ emb, float* __restrict__ x) {
  int s = blockIdx.x;
  int t = tok[s];
  const float4 v = *(const float4*)(emb + (size_t)t * DMODEL + threadIdx.x * 4);
  *(float4*)(x + (size_t)s * DMODEL + threadIdx.x * 4) = v;
}

// ---------------- rmsnorm (row = 1024): writes bf16 ----------------
__global__ __launch_bounds__(256) void rmsnorm_kernel(
    const float* __restrict__ x, const float* __restrict__ w,
    unsigned short* __restrict__ outb) {
  int s = blockIdx.x, tid = threadIdx.x;
  const float* xr = x + (size_t)s * DMODEL;
  float4 v = *(const float4*)(xr + tid * 4);
  float ss = v.x * v.x + v.y * v.y + v.z * v.z + v.w * v.w;
#pragma unroll
  for (int off = 32; off > 0; off >>= 1) ss += __shfl_down(ss, off);
  __shared__ float red[4];
  if ((tid & 63) == 0) red[tid >> 6] = ss;
  __syncthreads();
  float tot = red[0] + red[1] + red[2] + red[3];
  float scale = rsqrtf(tot * (1.0f / DMODEL) + 1e-6f);
  float4 wv = *(const float4*)(w + tid * 4);
  u16x4 ub;
  ub[0] = bf_us(v.x * scale * wv.x);
  ub[1] = bf_us(v.y * scale * wv.y);
  ub[2] = bf_us(v.z * scale * wv.z);
  ub[3] = bf_us(v.w * scale * wv.w);
  *(u16x4*)(outb + (size_t)s * DMODEL + tid * 4) = ub;
}

// ---------------- weight convert f32 -> bf16: both layers + LM head --------------
__global__ __launch_bounds__(256) void wcvt8_kernel(
    const float* __restrict__ Wq, const float* __restrict__ Wk,
    const float* __restrict__ Wv, const float* __restrict__ Wog,
    const float* __restrict__ Wout, const float* __restrict__ Wg,
    const float* __restrict__ Wu, const float* __restrict__ Wd,
    const float* __restrict__ Wlm,
    unsigned short* __restrict__ W, unsigned short* __restrict__ Wlm16) {
  const size_t de = ((size_t)blockIdx.x * 256 + threadIdx.x) * 8;
  if (de >= 2ull * WLAYER) {  // LM head region
    size_t i = de - 2ull * WLAYER;
    float4 a0 = *(const float4*)(Wlm + i);
    float4 a1 = *(const float4*)(Wlm + i + 4);
    u16x8 o;
    o[0] = bf_us(a0.x); o[1] = bf_us(a0.y); o[2] = bf_us(a0.z); o[3] = bf_us(a0.w);
    o[4] = bf_us(a1.x); o[5] = bf_us(a1.y); o[6] = bf_us(a1.z); o[7] = bf_us(a1.w);
    *(u16x8*)(Wlm16 + i) = o;
    return;
  }
  int e = (int)de, l = 0;
  if (e >= WLAYER) { l = 1; e -= WLAYER; }
  const float* src = nullptr;
  size_t idx = 0;
  if (e < 524288)       { src = Wq  + (size_t)l * 524288;  idx = e; }
  else if (e < 1048576) { src = Wk  + (size_t)l * 524288;  idx = e - 524288; }
  else if (e < 2097152) { src = Wv  + (size_t)l * 1048576; idx = e - 1048576; }
  else if (e < 3145728) { src = Wog + (size_t)l * 1048576; idx = e - 2097152; }
  else if (e < 4194304) { src = Wout + (size_t)l * 1048576; idx = e - 3145728; }
  else if (e < 7077888) {
    int t = e - 4194304, row = t >> 10;
    if (row < 2752) { src = Wg + (size_t)l * 2818048; idx = t; }
  } else if (e < 9961472) {
    int t = e - 7077888, row = t >> 10;
    if (row < 2752) { src = Wu + (size_t)l * 2818048; idx = t; }
  } else {
    int t = e - 9961472, row = t / 2816, col = t - row * 2816;
    if (col < 2752) { src = Wd + (size_t)l * 2818048; idx = row * 2752 + col; }
  }
  u16x8 o;
  if (src) {
    float4 a0 = *(const float4*)(src + idx);
    float4 a1 = *(const float4*)(src + idx + 4);
    o[0] = bf_us(a0.x); o[1] = bf_us(a0.y); o[2] = bf_us(a0.z); o[3] = bf_us(a0.w);
    o[4] = bf_us(a1.x); o[5] = bf_us(a1.y); o[6] = bf_us(a1.z); o[7] = bf_us(a1.w);
  } else {
#pragma unroll
    for (int k = 0; k < 8; ++k) o[k] = 0;
  }
  *(u16x8*)(W + de) = o;
}

// ---------------- GEMM core: 128x128 tile, BK=32, 3-buffer pipeline ----------------
// vmcnt(4) -> s_barrier -> stage(t+2) -> 8 ds_read + 16 MFMA. Buffer t%3.
// EPI: 0 f32 store | 1 f32 acc+X residual
template <int EPI>
__global__ __launch_bounds__(256) void gemm_bb_kernel(
    const unsigned short* __restrict__ A, const unsigned short* __restrict__ B,
    const void* Xv, void* Cv, int K, int ldc) {
  __shared__ __align__(16) unsigned short SH[3 * 8192];  // 3 x (A 128x32 | B 128x32)
  const int tid = threadIdx.x;
  const int wave = tid >> 6, lane = tid & 63;
  const int gx = gridDim.x;
  const int nwg = gx * gridDim.y;
  const int d = blockIdx.y * gx + blockIdx.x;
  const int q = nwg >> 3;
  const int lgc = (d & 7) * q + (d >> 3);
  const int bm = (lgc % gx) * 128, bn = (lgc / gx) * 128;
  const int wr = (wave >> 1) * 64, wc = (wave & 1) * 64;
  const int lr = lane & 15, lhi = lane >> 4;
  const unsigned short* Ab = A + (size_t)bm * K;
  const unsigned short* Bb = B + (size_t)bn * K;
  f32x4v acc[4][4] = {};

  auto stageT = [&](int tau) {
    unsigned short* base = SH + (tau % 3) * 8192;
    stage32(Ab, K, base, wave, lane, tau * 32);
    stage32(Bb, K, base + 4096, wave, lane, tau * 32);
  };

  const int NT = K >> 5;
  stageT(0);
  stageT(1);
  for (int t = 0; t < NT; ++t) {
    if (t < NT - 1) asm volatile("s_waitcnt vmcnt(4)" ::: "memory");
    else            asm volatile("s_waitcnt vmcnt(0)" ::: "memory");
    asm volatile("s_barrier" ::: "memory");
    if (t + 2 < NT) stageT(t + 2);
    const unsigned short* Al = SH + (t % 3) * 8192;
    const unsigned short* Bl = Al + 4096;
    bf16x8 af[4], bfr[4];
#pragma unroll
    for (int mi = 0; mi < 4; ++mi) {
      int row = wr + mi * 16 + lr;
      af[mi] = *(const bf16x8*)&Al[row * 32 + ((lhi ^ ((row >> 1) & 3)) << 3)];
    }
#pragma unroll
    for (int ni = 0; ni < 4; ++ni) {
      int row = wc + ni * 16 + lr;
      bfr[ni] = *(const bf16x8*)&Bl[row * 32 + ((lhi ^ ((row >> 1) & 3)) << 3)];
    }
    __builtin_amdgcn_s_setprio(1);
#pragma unroll
    for (int mi = 0; mi < 4; ++mi)
#pragma unroll
      for (int ni = 0; ni < 4; ++ni)
        acc[mi][ni] = __builtin_amdgcn_mfma_f32_16x16x32_bf16(af[mi], bfr[ni], acc[mi][ni], 0, 0, 0);
    __builtin_amdgcn_s_setprio(0);
  }
#pragma unroll
  for (int mi = 0; mi < 4; ++mi) {
#pragma unroll
    for (int ni = 0; ni < 4; ++ni) {
#pragma unroll
      for (int j = 0; j < 4; ++j) {
        int row = bm + wr + mi * 16 + lhi * 4 + j;   // C/D layout (m89)
        int col = bn + wc + ni * 16 + lr;
        float v = acc[mi][ni][j];
        if (EPI == 0)
          ((float*)Cv)[(size_t)row * ldc + col] = v;
        if (EPI == 1)
          ((float*)Cv)[(size_t)row * ldc + col] = v + ((const float*)Xv)[(size_t)row * ldc + col];
      }
    }
  }
}

// ---------------- LM head GEMM: 256x256 tile, 8 waves, BK=32, 3-buffer pipeline ---
__global__ __launch_bounds__(512, 2) void lm256_kernel(
    const unsigned short* __restrict__ A, const unsigned short* __restrict__ B,
    float* __restrict__ C) {
  __shared__ __align__(16) unsigned short SH[3 * 16384];  // 3 x (A 256x32 | B 256x32)
  const int K = 1024, N = 32000, NT = 32;
  const int tid = threadIdx.x;
  const int wave = tid >> 6, lane = tid & 63;
  const int lr = lane & 15, lg = lane >> 4;
  const int wm = wave >> 2, wn = wave & 3;     // 2M x 4N waves, 128x64 each
  const int d = blockIdx.y * 8 + blockIdx.x;
  const int lgc = (d & 7) * 125 + (d >> 3);
  const int bm = (lgc & 7) * 256;
  const int bn = (lgc >> 3) * 256;
  const unsigned short* Ab = A + (size_t)bm * K;
  const unsigned short* Bb = B + (size_t)bn * K;

  auto stageM = [&](const unsigned short* gbase, unsigned short* lds, int k0) {
#pragma unroll
    for (int j = 0; j < 2; ++j) {
      const int r = j * 128 + wave * 16 + (lane >> 2);
      const int cg = (lane & 3) ^ ((r >> 1) & 3);
      const unsigned short* src = gbase + (size_t)r * K + k0 + cg * 8;
      __builtin_amdgcn_global_load_lds((const AS_G void*)src,
                                       (AS_L void*)(lds + (j * 128 + wave * 16) * 32), 16, 0, 0);
    }
  };
  auto stageT = [&](int tau) {
    unsigned short* base = SH + (tau % 3) * 16384;
    stageM(Ab, base, tau * 32);
    stageM(Bb, base + 8192, tau * 32);
  };

  f32x4v acc[8][4] = {};
  stageT(0);
  stageT(1);
  for (int t = 0; t < NT; ++t) {
    if (t < NT - 1) asm volatile("s_waitcnt vmcnt(4)" ::: "memory");
    else            asm volatile("s_waitcnt vmcnt(0)" ::: "memory");
    asm volatile("s_barrier" ::: "memory");
    if (t + 2 < NT) stageT(t + 2);
    const unsigned short* Al = SH + (t % 3) * 16384;
    const unsigned short* Bl = Al + 8192;
    bf16x8 bfr[4];
#pragma unroll
    for (int ni = 0; ni < 4; ++ni) {
      int row = wn * 64 + ni * 16 + lr;
      bfr[ni] = *(const bf16x8*)&Bl[row * 32 + ((lg ^ ((row >> 1) & 3)) << 3)];
    }
#pragma unroll
    for (int mi = 0; mi < 8; ++mi) {
      int row = wm * 128 + mi * 16 + lr;
      bf16x8 af = *(const bf16x8*)&Al[row * 32 + ((lg ^ ((row >> 1) & 3)) << 3)];
      __builtin_amdgcn_s_setprio(1);
#pragma unroll
      for (int ni = 0; ni < 4; ++ni)
        acc[mi][ni] = __builtin_amdgcn_mfma_f32_16x16x32_bf16(af, bfr[ni], acc[mi][ni], 0, 0, 0);
      __builtin_amdgcn_s_setprio(0);
    }
  }
#pragma unroll
  for (int mi = 0; mi < 8; ++mi)
#pragma unroll
    for (int ni = 0; ni < 4; ++ni)
#pragma unroll
      for (int jj = 0; jj < 4; ++jj) {
        int row = bm + wm * 128 + mi * 16 + lg * 4 + jj;
        int col = bn + wn * 64 + ni * 16 + lr;
        C[(size_t)row * N + col] = fast_softcap30(acc[mi][ni][jj]);
      }
}

// ---------------- fused QKV+OG GEMM (pipelined BK=32) ----------------
__global__ __launch_bounds__(256) void qkvo_kernel(
    const unsigned short* __restrict__ A, const unsigned short* __restrict__ Wq16,
    const unsigned short* __restrict__ Wk16, const unsigned short* __restrict__ Wv16,
    const unsigned short* __restrict__ Wog16,
    unsigned short* __restrict__ qb, unsigned short* __restrict__ kb,
    unsigned short* __restrict__ vTb, float* __restrict__ og) {
  __shared__ __align__(16) unsigned short SH[3 * 8192];  // 48 KB (also vT transpose buf)
  const int tid = threadIdx.x;
  const int wave = tid >> 6, lane = tid & 63;
  const int gx = gridDim.x;                 // 16 (M)
  const int nwg = gx * gridDim.y;           // 384
  const int dd = blockIdx.y * gx + blockIdx.x;
  const int qq = nwg >> 3;
  const int lgc = (dd & 7) * qq + (dd >> 3);
  const int bm = (lgc % gx) * 128;
  const int by = lgc / gx;
  const unsigned short* B;
  int bnl, mode;
  if (by < 4)       { B = Wq16;  bnl = by * 128;        mode = 0; }
  else if (by < 8)  { B = Wk16;  bnl = (by - 4) * 128;  mode = 1; }
  else if (by < 16) { B = Wv16;  bnl = (by - 8) * 128;  mode = 2; }
  else              { B = Wog16; bnl = (by - 16) * 128; mode = 3; }
  const int K = 1024;
  const int wr = (wave >> 1) * 64, wc = (wave & 1) * 64;
  const int lr = lane & 15, lhi = lane >> 4;
  const unsigned short* Ab = A + (size_t)bm * K;
  const unsigned short* Bb = B + (size_t)bnl * K;
  f32x4v acc[4][4] = {};

  auto stageT = [&](int tau) {
    unsigned short* base = SH + (tau % 3) * 8192;
    stage32(Ab, K, base, wave, lane, tau * 32);
    stage32(Bb, K, base + 4096, wave, lane, tau * 32);
  };

  const int NT = 32;
  stageT(0);
  stageT(1);
  for (int t = 0; t < NT; ++t) {
    if (t < NT - 1) asm volatile("s_waitcnt vmcnt(4)" ::: "memory");
    else            asm volatile("s_waitcnt vmcnt(0)" ::: "memory");
    asm volatile("s_barrier" ::: "memory");
    if (t + 2 < NT) stageT(t + 2);
    const unsigned short* Al = SH + (t % 3) * 8192;
    const unsigned short* Bl = Al + 4096;
    bf16x8 af[4], bfr[4];
#pragma unroll
    for (int mi = 0; mi < 4; ++mi) {
      int row = wr + mi * 16 + lr;
      af[mi] = *(const bf16x8*)&Al[row * 32 + ((lhi ^ ((row >> 1) & 3)) << 3)];
    }
#pragma unroll
    for (int ni = 0; ni < 4; ++ni) {
      int row = wc + ni * 16 + lr;
      bfr[ni] = *(const bf16x8*)&Bl[row * 32 + ((lhi ^ ((row >> 1) & 3)) << 3)];
    }
    __builtin_amdgcn_s_setprio(1);
#pragma unroll
    for (int mi = 0; mi < 4; ++mi)
#pragma unroll
      for (int ni = 0; ni < 4; ++ni)
        acc[mi][ni] = __builtin_amdgcn_mfma_f32_16x16x32_bf16(af[mi], bfr[ni], acc[mi][ni], 0, 0, 0);
    __builtin_amdgcn_s_setprio(0);
  }
  if (mode == 2) {
    __syncthreads();  // all waves done reading staging buffers before SH reuse
#pragma unroll
    for (int mi = 0; mi < 4; ++mi)
#pragma unroll
      for (int ni = 0; ni < 4; ++ni)
#pragma unroll
        for (int j = 0; j < 4; ++j) {
          int row = wr + mi * 16 + lhi * 4 + j;
          int col = wc + ni * 16 + lr;
          int byte = col * 256 + ((((row >> 3) ^ (col & 7)) << 4)) + (row & 7) * 2;
          *(unsigned short*)((char*)SH + byte) = bf_us(acc[mi][ni][j]);
        }
    __syncthreads();
#pragma unroll
    for (int i = 0; i < 8; ++i) {
      int c = i * 16 + (tid >> 4);
      int rg = tid & 15;
      u16x8 u = *(const u16x8*)((const char*)SH + c * 256 + ((rg ^ (c & 7)) << 4));
      *(u16x8*)(vTb + (size_t)(bnl + c) * S_LEN + bm + rg * 8) = u;
    }
  } else {
#pragma unroll
    for (int mi = 0; mi < 4; ++mi)
#pragma unroll
      for (int ni = 0; ni < 4; ++ni)
#pragma unroll
        for (int j = 0; j < 4; ++j) {
          int row = bm + wr + mi * 16 + lhi * 4 + j;
          int col = bnl + wc + ni * 16 + lr;
          if (mode == 0)      qb[(size_t)row * 512 + col] = bf_us(acc[mi][ni][j]);
          else if (mode == 1) kb[(size_t)row * 512 + col] = bf_us(acc[mi][ni][j]);
          else                og[(size_t)row * 1024 + col] = acc[mi][ni][j];
        }
  }
}

// ---------------- fused FFN gate+up GEMM (pipelined BK=32, 3 matrices) -------------
// 3 matrices x 8 KB/tile = 24 KB/buffer, 3 buffers = 72 KB. 6 loads/tile, 2 tiles
// in flight -> steady vmcnt(6) drains exactly tile t; tail vmcnt(0).
__global__ __launch_bounds__(256) void ffn_kernel(
    const unsigned short* __restrict__ A, const unsigned short* __restrict__ Bg,
    const unsigned short* __restrict__ Bu, unsigned short* __restrict__ Gb) {
  __shared__ __align__(16) unsigned short SH[3 * 12288];  // 72 KB
  const int K = 1024;
  const int tid = threadIdx.x;
  const int wave = tid >> 6, lane = tid & 63;
  const int gx = gridDim.x;                 // 16
  const int nwg = gx * gridDim.y;           // 352
  const int dd = blockIdx.y * gx + blockIdx.x;
  const int qq = nwg >> 3;
  const int lgc = (dd & 7) * qq + (dd >> 3);
  const int bm = (lgc % gx) * 128;
  const int bn = (lgc / gx) * 128;
  const int wr = (wave >> 1) * 64, wc = (wave & 1) * 64;
  const int lr = lane & 15, lhi = lane >> 4;
  const unsigned short* Ab = A + (size_t)bm * K;
  const unsigned short* Bgb = Bg + (size_t)bn * K;
  const unsigned short* Bub = Bu + (size_t)bn * K;
  f32x4v accg[4][4] = {};
  f32x4v accu[4][4] = {};

  auto stageT = [&](int tau) {
    unsigned short* base = SH + (tau % 3) * 12288;
    stage32(Ab, K, base, wave, lane, tau * 32);
    stage32(Bgb, K, base + 4096, wave, lane, tau * 32);
    stage32(Bub, K, base + 8192, wave, lane, tau * 32);
  };

  const int NT = 32;
  stageT(0);
  stageT(1);
  for (int t = 0; t < NT; ++t) {
    if (t < NT - 1) asm volatile("s_waitcnt vmcnt(6)" ::: "memory");
    else            asm volatile("s_waitcnt vmcnt(0)" ::: "memory");
    asm volatile("s_barrier" ::: "memory");
    if (t + 2 < NT) stageT(t + 2);
    const unsigned short* Al = SH + (t % 3) * 12288;
    const unsigned short* Bgl = Al + 4096;
    const unsigned short* Bul = Al + 8192;
    bf16x8 af[4], bg[4], bu[4];
#pragma unroll
    for (int mi = 0; mi < 4; ++mi) {
      int row = wr + mi * 16 + lr;
      af[mi] = *(const bf16x8*)&Al[row * 32 + ((lhi ^ ((row >> 1) & 3)) << 3)];
    }
#pragma unroll
    for (int ni = 0; ni < 4; ++ni) {
      int row = wc + ni * 16 + lr;
      int sw = ((lhi ^ ((row >> 1) & 3)) << 3);
      bg[ni] = *(const bf16x8*)&Bgl[row * 32 + sw];
      bu[ni] = *(const bf16x8*)&Bul[row * 32 + sw];
    }
    __builtin_amdgcn_s_setprio(1);
#pragma unroll
    for (int mi = 0; mi < 4; ++mi)
#pragma unroll
      for (int ni = 0; ni < 4; ++ni) {
        accg[mi][ni] = __builtin_amdgcn_mfma_f32_16x16x32_bf16(af[mi], bg[ni], accg[mi][ni], 0, 0, 0);
        accu[mi][ni] = __builtin_amdgcn_mfma_f32_16x16x32_bf16(af[mi], bu[ni], accu[mi][ni], 0, 0, 0);
      }
    __builtin_amdgcn_s_setprio(0);
  }
#pragma unroll
  for (int mi = 0; mi < 4; ++mi) {
#pragma unroll
    for (int ni = 0; ni < 4; ++ni) {
#pragma unroll
      for (int j = 0; j < 4; ++j) {
        int row = bm + wr + mi * 16 + lhi * 4 + j;
        int col = bn + wc + ni * 16 + lr;
        float g = accg[mi][ni][j];
        float sv = g * fast_sigmoid(g) * accu[mi][ni][j];
        Gb[(size_t)row * 2816 + col] = bf_us(sv);
      }
    }
  }
}

// ---------------- gate pre-activations (inline rmsnorm from f32 x) ----------------
__global__ __launch_bounds__(256) void gates_kernel(
    const float* __restrict__ x, const float* __restrict__ n1,
    const float* __restrict__ Wi, const float* __restrict__ bi,
    const float* __restrict__ Wf, const float* __restrict__ bfv,
    float* __restrict__ ipre, float* __restrict__ fpre) {
  int s = blockIdx.x;
  int head = threadIdx.x >> 6, lane = threadIdx.x & 63;
  const float* xr = x + (size_t)s * DMODEL;
  float xv[16];
  float ss = 0.f;
#pragma unroll
  for (int j = 0; j < 16; ++j) { xv[j] = xr[lane + j * 64]; ss += xv[j] * xv[j]; }
#pragma unroll
  for (int off = 32; off > 0; off >>= 1) ss += __shfl_xor(ss, off);
  float scale = rsqrtf(ss * (1.0f / DMODEL) + 1e-6f);
  const float* wi = Wi + head * DMODEL;
  const float* wf = Wf + head * DMODEL;
  float si = 0.f, sf = 0.f;
#pragma unroll
  for (int j = 0; j < 16; ++j) {
    int c = lane + j * 64;
    float xm = xv[j] * scale * n1[c];
    si += xm * wi[c];
    sf += xm * wf[c];
  }
#pragma unroll
  for (int off = 32; off > 0; off >>= 1) {
    si += __shfl_down(si, off);
    sf += __shfl_down(sf, off);
  }
  if (lane == 0) {
    ipre[head * S_LEN + s] = 15.0f * tanhf((si + bi[head]) * (1.0f / 15.0f));
    fpre[head * S_LEN + s] = 15.0f * tanhf((sf + bfv[head]) * (1.0f / 15.0f));
  }
}

// ---------------- per-head scan ----------------
__global__ __launch_bounds__(256) void scan_kernel(
    const float* __restrict__ ipre, const float* __restrict__ fpre,
    float* __restrict__ garr, float* __restrict__ Marr, float* __restrict__ earr) {
  const int h = threadIdx.x >> 6;
  const int lane = threadIdx.x & 63;
  const int base = h * S_LEN + lane * 32;
  float lf[32];
  float lsum = 0.f;
#pragma unroll
  for (int e = 0; e < 32; ++e) {
    float f = fpre[base + e];
    float v = fminf(f, 0.f) - log1pf(expf(-fabsf(f)));
    lf[e] = v;
    lsum += v;
  }
  float scan = lsum;
#pragma unroll
  for (int off = 1; off < 64; off <<= 1) {
    float t = __shfl_up(scan, off);
    if (lane >= off) scan += t;
  }
  float F0 = scan - lsum;
  float gv[32];
  float F = F0, lmax = -1e30f;
#pragma unroll
  for (int e = 0; e < 32; ++e) {
    F += lf[e];
    float g = ipre[base + e] - F;
    gv[e] = g;
    lmax = fmaxf(lmax, g);
    garr[base + e] = g;
  }
  float ms = lmax;
#pragma unroll
  for (int off = 1; off < 64; off <<= 1) {
    float t = __shfl_up(ms, off);
    if (lane >= off) ms = fmaxf(ms, t);
  }
  float em = __shfl_up(ms, 1);
  if (lane == 0) em = -1e30f;
  float run = em;
  F = F0;
#pragma unroll
  for (int e = 0; e < 32; ++e) {
    F += lf[e];
    run = fmaxf(run, gv[e]);
    Marr[base + e] = run;
    earr[base + e] = expf(-(F + run));
  }
}

// ---------------- mLSTM parallel, bf16 MFMA flash-style, s-split x4 ----------------
__global__ __launch_bounds__(256) void mlstm_mfma_kernel(
    const unsigned short* __restrict__ Q, const unsigned short* __restrict__ Kb,
    const unsigned short* __restrict__ vT, const float* __restrict__ garr,
    const float* __restrict__ Marr,
    float* __restrict__ hp, float* __restrict__ npart) {
  const int h = blockIdx.y;
  const int T = blockIdx.x;
  const int sp = blockIdx.z;
  float* hpart = hp + (size_t)sp * 2097152;
  const int tid = threadIdx.x;
  const int w = tid >> 6, l = tid & 63;
  const int lr = l & 15, lg = l >> 4;
  const int hbase = h * S_LEN;
  const int sr = tid >> 4;
  const int sc = tid & 15;

  __shared__ __align__(16) unsigned short Ks[64 * 128];
  __shared__ __align__(16) unsigned short Vs[256 * 64];
  __shared__ __align__(16) unsigned short Ps[64 * 64];

  bf16x8 qf[4];
  {
    const unsigned short* qrow = Q + (size_t)(T * 64 + w * 16 + lr) * 512 + h * 128 + lg * 8;
#pragma unroll
    for (int kt = 0; kt < 4; ++kt) {
      cvu c;
      c.u = *(const u16x8*)(qrow + kt * 32);
      qf[kt] = c.b;
    }
  }
  float Mt[4];
#pragma unroll
  for (int j = 0; j < 4; ++j) Mt[j] = Marr[hbase + T * 64 + w * 16 + lg * 4 + j];

  f32x4v pv[16] = {};
  float nacc[4] = {0.f, 0.f, 0.f, 0.f};
  const float rs = 0.08838834764831845f;  // 1/sqrt(128)

  for (int ch = sp; ch <= T; ch += 4) {
    const int s0 = ch * 64;
    __syncthreads();
#pragma unroll
    for (int i = 0; i < 4; ++i) {
      int r = i * 16 + sr;
      u16x8 u = *(const u16x8*)(Kb + (size_t)(s0 + r) * 512 + h * 128 + sc * 8);
      int byte = r * 256 + ((sc * 16) ^ ((r & 7) << 4));
      *(u16x8*)((char*)Ks + byte) = u;
    }
#pragma unroll
    for (int i = 0; i < 16; ++i) {
      int r = i * 16 + sr;
      u16x4 u = *(const u16x4*)(vT + (size_t)(h * 256 + r) * S_LEN + s0 + sc * 4);
      int byte = r * 128 + ((sc * 8) ^ ((r & 7) << 4));
      *(u16x4*)((char*)Vs + byte) = u;
    }
    __syncthreads();
    f32x4v sa[4] = {};
#pragma unroll
    for (int ni = 0; ni < 4; ++ni) {
#pragma unroll
      for (int kt = 0; kt < 4; ++kt) {
        int row = ni * 16 + lr;
        int byte = row * 256 + (((kt * 32 + lg * 8) * 2) ^ ((row & 7) << 4));
        bf16x8 kf = ld_bf8(Ks, byte);
        sa[ni] = __builtin_amdgcn_mfma_f32_16x16x32_bf16(qf[kt], kf, sa[ni], 0, 0, 0);
      }
    }
#pragma unroll
    for (int ni = 0; ni < 4; ++ni) {
      int sl = ni * 16 + lr;
      int sg = s0 + sl;
      float gv = garr[hbase + sg];
#pragma unroll
      for (int j = 0; j < 4; ++j) {
        int tloc = w * 16 + lg * 4 + j;
        int tg = T * 64 + tloc;
        float wgt = (sg <= tg) ? __expf(gv - Mt[j]) : 0.f;
        float val = sa[ni][j] * rs * wgt;
        nacc[j] += val;
        int byte = tloc * 128 + ((sl * 2) ^ ((tloc & 7) << 4));
        *(unsigned short*)((char*)Ps + byte) = bf_us(val);
      }
    }
#pragma unroll
    for (int kt2 = 0; kt2 < 2; ++kt2) {
      int tloc = w * 16 + lr;
      int sb = (kt2 * 32 + lg * 8) * 2;
      bf16x8 pa = ld_bf8(Ps, tloc * 128 + (sb ^ ((tloc & 7) << 4)));
#pragma unroll
      for (int nv = 0; nv < 16; ++nv) {
        int dv = nv * 16 + lr;
        bf16x8 vb = ld_bf8(Vs, dv * 128 + (sb ^ ((dv & 7) << 4)));
        pv[nv] = __builtin_amdgcn_mfma_f32_16x16x32_bf16(pa, vb, pv[nv], 0, 0, 0);
      }
    }
  }
#pragma unroll
  for (int j = 0; j < 4; ++j) {
#pragma unroll
    for (int off = 1; off < 16; off <<= 1) nacc[j] += __shfl_xor(nacc[j], off);
  }
#pragma unroll
  for (int j = 0; j < 4; ++j) {
    int tg = T * 64 + w * 16 + lg * 4 + j;
    if (lr == 0) npart[sp * 8192 + hbase + tg] = nacc[j];
    float* orow = hpart + (size_t)tg * DMODEL + h * 256;
#pragma unroll
    for (int nvt = 0; nvt < 16; ++nvt) orow[nvt * 16 + lr] = pv[nvt][j];
  }
}

// ---------------- combine(4) + multihead LayerNorm * mhw * sigmoid(og) -> bf16 ----
__global__ __launch_bounds__(256) void mhln_gate_kernel(
    const float* __restrict__ hp, const float* __restrict__ npart,
    const float* __restrict__ earr, const float* __restrict__ mhw,
    const float* __restrict__ og, unsigned short* __restrict__ gact) {
  int s = blockIdx.x;
  int head = threadIdx.x >> 6, lane = threadIdx.x & 63;
  float n = (npart[head * S_LEN + s] + npart[8192 + head * S_LEN + s]) +
            (npart[16384 + head * S_LEN + s] + npart[24576 + head * S_LEN + s]);
  float nvv = fmaxf(fabsf(n), earr[head * S_LEN + s]);
  float inv = 1.0f / (nvv + 1e-6f);
  const size_t base = (size_t)s * DMODEL + head * 256;
  float vq[4];
#pragma unroll
  for (int qy = 0; qy < 4; ++qy) {
    size_t o = base + qy * 64 + lane;
    vq[qy] = ((hp[o] + hp[o + 2097152]) + (hp[o + 4194304] + hp[o + 6291456])) * inv;
  }
  float sum = vq[0] + vq[1] + vq[2] + vq[3];
#pragma unroll
  for (int off = 32; off > 0; off >>= 1) sum += __shfl_xor(sum, off);
  float mu = sum * (1.0f / 256.0f);
  float d0 = vq[0] - mu, d1 = vq[1] - mu, d2 = vq[2] - mu, d3 = vq[3] - mu;
  float vs = d0 * d0 + d1 * d1 + d2 * d2 + d3 * d3;
#pragma unroll
  for (int off = 32; off > 0; off >>= 1) vs += __shfl_xor(vs, off);
  float rstd = rsqrtf(vs * (1.0f / 256.0f) + 1e-6f);
  float dn[4] = {d0, d1, d2, d3};
#pragma unroll
  for (int qy = 0; qy < 4; ++qy) {
    int c = head * 256 + qy * 64 + lane;
    float ov = og[(size_t)s * DMODEL + c];
    gact[(size_t)s * DMODEL + c] = bf_us(dn[qy] * rstd * mhw[c] * fast_sigmoid(ov));
  }
}

extern "C" void kernel_launch(void* const* d_in, const int* in_sizes, int n_in,
                              void* d_out, int out_size, void* d_ws, size_t ws_size,
                              hipStream_t stream) {
  (void)in_sizes; (void)n_in; (void)out_size; (void)ws_size;
  const int*   tok   = (const int*)d_in[0];
  const float* emb   = (const float*)d_in[1];
  const float* norm1 = (const float*)d_in[2];
  const float* Wq    = (const float*)d_in[3];
  const float* Wk    = (const float*)d_in[4];
  const float* Wv    = (const float*)d_in[5];
  const float* Wog   = (const float*)d_in[6];
  const float* Wi    = (const float*)d_in[7];
  const float* bi    = (const float*)d_in[8];
  const float* Wf    = (const float*)d_in[9];
  const float* bfp   = (const float*)d_in[10];
  const float* mhw   = (const float*)d_in[11];
  const float* Wout  = (const float*)d_in[12];
  const float* norm2 = (const float*)d_in[13];
  const float* Wg    = (const float*)d_in[14];
  const float* Wu    = (const float*)d_in[15];
  const float* Wd    = (const float*)d_in[16];
  const float* onw   = (const float*)d_in[17];
  const float* Wlm   = (const float*)d_in[18];

  char* wsb = (char*)d_ws;
  const size_t MB = 1ull << 20;
  float*          x    = (float*)wsb;                          // 8 MiB
  unsigned short* xmb  = (unsigned short*)(wsb + 8 * MB);      // 4 MiB
  float*          ipre = (float*)(wsb + 12 * MB);              // scalars region
  float*          fpre = ipre + 8192;
  float*          garr = fpre + 8192;
  float*          Marr = garr + 8192;
  float*          earr = Marr + 8192;
  float*          npart = earr + 8192;                         // 4 x 32 KiB
  unsigned short* W16  = (unsigned short*)(wsb + 13 * MB);     // 49 MiB -> ends 62
  const size_t OQ = 0, OKk = 524288, OV = 1048576, OOG = 2097152, OOUT = 3145728,
               OGt = 4194304, OU = 7077888, OD = 9961472;
  unsigned short* qb    = (unsigned short*)(wsb + 62 * MB);    // 2 MiB
  unsigned short* kb    = (unsigned short*)(wsb + 64 * MB);    // 2 MiB
  unsigned short* vTb   = (unsigned short*)(wsb + 66 * MB);    // 4 MiB
  float*          og    = (float*)(wsb + 70 * MB);             // 8 MiB
  float*          hp    = (float*)(wsb + 78 * MB);             // 4 x 8 MiB -> ends 110
  unsigned short* gact  = (unsigned short*)(wsb + 110 * MB);   // 4 MiB
  unsigned short* Gb16  = (unsigned short*)(wsb + 114 * MB);   // 11 MiB -> ends 125
  unsigned short* wlm16 = (unsigned short*)(wsb + 126 * MB);   // 62.5 MiB -> ends 188.5

  embed_kernel<<<2048, 256, 0, stream>>>(tok, emb, x);
  wcvt8_kernel<<<28544, 256, 0, stream>>>(Wq, Wk, Wv, Wog, Wout, Wg, Wu, Wd, Wlm,
                                          W16, wlm16);

  for (int l = 0; l < 2; ++l) {
    const unsigned short* Wl = W16 + (size_t)l * WLAYER;
    const float* n1   = norm1 + (size_t)l * 1024;
    const float* wiv  = Wi   + (size_t)l * 4 * 1024;
    const float* bil  = bi   + (size_t)l * 4;
    const float* wfv  = Wf   + (size_t)l * 4 * 1024;
    const float* bfl  = bfp  + (size_t)l * 4;
    const float* mhwl = mhw  + (size_t)l * 1024;
    const float* n2   = norm2 + (size_t)l * 1024;

    rmsnorm_kernel<<<2048, 256, 0, stream>>>(x, n1, xmb);
    qkvo_kernel<<<dim3(16, 24), 256, 0, stream>>>(xmb, Wl + OQ, Wl + OKk, Wl + OV,
                                                  Wl + OOG, qb, kb, vTb, og);
    gates_kernel<<<2048, 256, 0, stream>>>(x, n1, wiv, bil, wfv, bfl, ipre, fpre);
    scan_kernel<<<1, 256, 0, stream>>>(ipre, fpre, garr, Marr, earr);
    mlstm_mfma_kernel<<<dim3(32, 4, 4), 256, 0, stream>>>(qb, kb, vTb, garr, Marr,
                                                          hp, npart);
    mhln_gate_kernel<<<2048, 256, 0, stream>>>(hp, npart, earr, mhwl, og, gact);
    gemm_bb_kernel<1><<<dim3(16, 8), 256, 0, stream>>>(gact, Wl + OOUT, x, x, 1024, 1024);
    rmsnorm_kernel<<<2048, 256, 0, stream>>>(x, n2, xmb);
    ffn_kernel<<<dim3(16, 22), 256, 0, stream>>>(xmb, Wl + OGt, Wl + OU, Gb16);
    gemm_bb_kernel<1><<<dim3(16, 8), 256, 0, stream>>>(Gb16, Wl + OD, x, x, 2816, 1024);
  }

  rmsnorm_kernel<<<2048, 256, 0, stream>>>(x, onw, xmb);
  lm256_kernel<<<dim3(8, 125), 512, 0, stream>>>(xmb, wlm16, (float*)d_out);
}

// Round 18
// 683.218 us; speedup vs baseline: 1.2901x; 1.0600x over previous
//
#include <hip/hip_runtime.h>
#include <hip/hip_bf16.h>
#include <math.h>

// xLSTM-Large forward: S=2048, D=1024, NH=4 (Dqk=128, Dv=256), UP=2752, L=2, V=32000.
// All GEMMs on the proven BK=32 / 3-buffer / counted-vmcnt pipeline.
// This round: wout/down-proj moved to a 128x64-tile variant (256 blocks = 1/CU,
// full-GPU utilization; previously 128 blocks = half the CUs idle).

#define S_LEN 2048
#define DMODEL 1024
#define WLAYER 12845056  // elements per layer in W16

typedef __attribute__((ext_vector_type(8))) __bf16 bf16x8;
typedef __attribute__((ext_vector_type(8))) unsigned short u16x8;
typedef __attribute__((ext_vector_type(4))) unsigned short u16x4;
typedef __attribute__((ext_vector_type(4))) float f32x4v;

union cvu { u16x8 u; bf16x8 b; };

__device__ __forceinline__ unsigned short bf_us(float f) {
  union { __bf16 b; unsigned short u; } c;
  c.b = (__bf16)f;   // RNE, native v_cvt on gfx950
  return c.u;
}
__device__ __forceinline__ float us_f(unsigned short u) {
  union { __bf16 b; unsigned short u; } c;
  c.u = u;
  return (float)c.b;
}
__device__ __forceinline__ bf16x8 ld_bf8(const unsigned short* p, int byte_off) {
  cvu c;
  c.u = *(const u16x8*)((const char*)p + byte_off);
  return c.b;
}
__device__ __forceinline__ float fast_sigmoid(float v) {
  return 1.0f / (1.0f + __expf(-v));
}
__device__ __forceinline__ float fast_softcap30(float v) {
  float e = __expf(-fabsf(v) * (1.0f / 15.0f));  // e^{-2|v|/30}
  float t = (1.0f - e) / (1.0f + e);             // tanh(|v|/30)
  return copysignf(30.0f * t, v);
}

#define AS_G __attribute__((address_space(1)))
#define AS_L __attribute__((address_space(3)))

// Stage a 128x32 bf16 tile (8 KB) into linear LDS: 2 issues of 4 KB (64 rows).
// Source col-group pre-swizzled (cg ^= (row>>1)&3); matching XOR on read.
__device__ __forceinline__ void stage32(const unsigned short* gbase, int K,
                                        unsigned short* lds, int wave, int lane, int k0) {
#pragma unroll
  for (int j = 0; j < 2; ++j) {
    const int r = j * 64 + wave * 16 + (lane >> 2);
    const int cg = (lane & 3) ^ ((r >> 1) & 3);
    const unsigned short* src = gbase + (size_t)r * K + k0 + cg * 8;
    __builtin_amdgcn_global_load_lds((const AS_G void*)src,
                                     (AS_L void*)(lds + (j * 64 + wave * 16) * 32), 16, 0, 0);
  }
}

// Stage a 64x32 bf16 tile (4 KB) = exactly 1 issue for 256 threads.
__device__ __forceinline__ void stage32h(const unsigned short* gbase, int K,
                                         unsigned short* lds, int wave, int lane, int k0) {
  const int r = wave * 16 + (lane >> 2);
  const int cg = (lane & 3) ^ ((r >> 1) & 3);
  const unsigned short* src = gbase + (size_t)r * K + k0 + cg * 8;
  __builtin_amdgcn_global_load_lds((const AS_G void*)src,
                                   (AS_L void*)(lds + (wave * 16) * 32), 16, 0, 0);
}

// ---------------- embed ----------------
__global__ __launch_bounds__(256) void embed_kernel(
    const int* __restrict__ tok, const float* __restrict__ emb, float* __restrict__ x) {
  int s = blockIdx.x;
  int t = tok[s];
  const float4 v = *(const float4*)(emb + (size_t)t * DMODEL + threadIdx.x * 4);
  *(float4*)(x + (size_t)s * DMODEL + threadIdx.x * 4) = v;
}

// ---------------- rmsnorm (row = 1024): writes bf16 ----------------
__global__ __launch_bounds__(256) void rmsnorm_kernel(
    const float* __restrict__ x, const float* __restrict__ w,
    unsigned short* __restrict__ outb) {
  int s = blockIdx.x, tid = threadIdx.x;
  const float* xr = x + (size_t)s * DMODEL;
  float4 v = *(const float4*)(xr + tid * 4);
  float ss = v.x * v.x + v.y * v.y + v.z * v.z + v.w * v.w;
#pragma unroll
  for (int off = 32; off > 0; off >>= 1) ss += __shfl_down(ss, off);
  __shared__ float red[4];
  if ((tid & 63) == 0) red[tid >> 6] = ss;
  __syncthreads();
  float tot = red[0] + red[1] + red[2] + red[3];
  float scale = rsqrtf(tot * (1.0f / DMODEL) + 1e-6f);
  float4 wv = *(const float4*)(w + tid * 4);
  u16x4 ub;
  ub[0] = bf_us(v.x * scale * wv.x);
  ub[1] = bf_us(v.y * scale * wv.y);
  ub[2] = bf_us(v.z * scale * wv.z);
  ub[3] = bf_us(v.w * scale * wv.w);
  *(u16x4*)(outb + (size_t)s * DMODEL + tid * 4) = ub;
}

// ---------------- weight convert f32 -> bf16: both layers + LM head --------------
__global__ __launch_bounds__(256) void wcvt8_kernel(
    const float* __restrict__ Wq, const float* __restrict__ Wk,
    const float* __restrict__ Wv, const float* __restrict__ Wog,
    const float* __restrict__ Wout, const float* __restrict__ Wg,
    const float* __restrict__ Wu, const float* __restrict__ Wd,
    const float* __restrict__ Wlm,
    unsigned short* __restrict__ W, unsigned short* __restrict__ Wlm16) {
  const size_t de = ((size_t)blockIdx.x * 256 + threadIdx.x) * 8;
  if (de >= 2ull * WLAYER) {  // LM head region
    size_t i = de - 2ull * WLAYER;
    float4 a0 = *(const float4*)(Wlm + i);
    float4 a1 = *(const float4*)(Wlm + i + 4);
    u16x8 o;
    o[0] = bf_us(a0.x); o[1] = bf_us(a0.y); o[2] = bf_us(a0.z); o[3] = bf_us(a0.w);
    o[4] = bf_us(a1.x); o[5] = bf_us(a1.y); o[6] = bf_us(a1.z); o[7] = bf_us(a1.w);
    *(u16x8*)(Wlm16 + i) = o;
    return;
  }
  int e = (int)de, l = 0;
  if (e >= WLAYER) { l = 1; e -= WLAYER; }
  const float* src = nullptr;
  size_t idx = 0;
  if (e < 524288)       { src = Wq  + (size_t)l * 524288;  idx = e; }
  else if (e < 1048576) { src = Wk  + (size_t)l * 524288;  idx = e - 524288; }
  else if (e < 2097152) { src = Wv  + (size_t)l * 1048576; idx = e - 1048576; }
  else if (e < 3145728) { src = Wog + (size_t)l * 1048576; idx = e - 2097152; }
  else if (e < 4194304) { src = Wout + (size_t)l * 1048576; idx = e - 3145728; }
  else if (e < 7077888) {
    int t = e - 4194304, row = t >> 10;
    if (row < 2752) { src = Wg + (size_t)l * 2818048; idx = t; }
  } else if (e < 9961472) {
    int t = e - 7077888, row = t >> 10;
    if (row < 2752) { src = Wu + (size_t)l * 2818048; idx = t; }
  } else {
    int t = e - 9961472, row = t / 2816, col = t - row * 2816;
    if (col < 2752) { src = Wd + (size_t)l * 2818048; idx = row * 2752 + col; }
  }
  u16x8 o;
  if (src) {
    float4 a0 = *(const float4*)(src + idx);
    float4 a1 = *(const float4*)(src + idx + 4);
    o[0] = bf_us(a0.x); o[1] = bf_us(a0.y); o[2] = bf_us(a0.z); o[3] = bf_us(a0.w);
    o[4] = bf_us(a1.x); o[5] = bf_us(a1.y); o[6] = bf_us(a1.z); o[7] = bf_us(a1.w);
  } else {
#pragma unroll
    for (int k = 0; k < 8; ++k) o[k] = 0;
  }
  *(u16x8*)(W + de) = o;
}

// ---------------- GEMM: 128x64 tile, BK=32, 3-buffer pipeline -----------------
// 256 blocks for N=1024 outputs -> 1 block/CU (full GPU). 4 waves as 2M x 2N
// (per-wave 64x32, acc[4][2], 8 MFMA/K-tile). 3 loads/tile (A 2 + B 1):
// steady vmcnt(3) drains exactly tile t; tail vmcnt(0). 36 KB LDS, buffer t%3.
// EPI: 1 f32 acc+X residual
template <int EPI>
__global__ __launch_bounds__(256) void gemm_bn64_kernel(
    const unsigned short* __restrict__ A, const unsigned short* __restrict__ B,
    const void* Xv, void* Cv, int K, int ldc) {
  __shared__ __align__(16) unsigned short SH[3 * 6144];  // 3 x (A 128x32 | B 64x32)
  const int tid = threadIdx.x;
  const int wave = tid >> 6, lane = tid & 63;
  const int gx = gridDim.x;
  const int nwg = gx * gridDim.y;
  const int d = blockIdx.y * gx + blockIdx.x;
  const int q = nwg >> 3;
  const int lgc = (d & 7) * q + (d >> 3);
  const int bm = (lgc % gx) * 128, bn = (lgc / gx) * 64;
  const int wr = (wave >> 1) * 64, wc = (wave & 1) * 32;
  const int lr = lane & 15, lhi = lane >> 4;
  const unsigned short* Ab = A + (size_t)bm * K;
  const unsigned short* Bb = B + (size_t)bn * K;
  f32x4v acc[4][2] = {};

  auto stageT = [&](int tau) {
    unsigned short* base = SH + (tau % 3) * 6144;
    stage32(Ab, K, base, wave, lane, tau * 32);
    stage32h(Bb, K, base + 4096, wave, lane, tau * 32);
  };

  const int NT = K >> 5;
  stageT(0);
  stageT(1);
  for (int t = 0; t < NT; ++t) {
    if (t < NT - 1) asm volatile("s_waitcnt vmcnt(3)" ::: "memory");
    else            asm volatile("s_waitcnt vmcnt(0)" ::: "memory");
    asm volatile("s_barrier" ::: "memory");
    if (t + 2 < NT) stageT(t + 2);
    const unsigned short* Al = SH + (t % 3) * 6144;
    const unsigned short* Bl = Al + 4096;
    bf16x8 af[4], bfr[2];
#pragma unroll
    for (int mi = 0; mi < 4; ++mi) {
      int row = wr + mi * 16 + lr;
      af[mi] = *(const bf16x8*)&Al[row * 32 + ((lhi ^ ((row >> 1) & 3)) << 3)];
    }
#pragma unroll
    for (int ni = 0; ni < 2; ++ni) {
      int row = wc + ni * 16 + lr;
      bfr[ni] = *(const bf16x8*)&Bl[row * 32 + ((lhi ^ ((row >> 1) & 3)) << 3)];
    }
    __builtin_amdgcn_s_setprio(1);
#pragma unroll
    for (int mi = 0; mi < 4; ++mi)
#pragma unroll
      for (int ni = 0; ni < 2; ++ni)
        acc[mi][ni] = __builtin_amdgcn_mfma_f32_16x16x32_bf16(af[mi], bfr[ni], acc[mi][ni], 0, 0, 0);
    __builtin_amdgcn_s_setprio(0);
  }
#pragma unroll
  for (int mi = 0; mi < 4; ++mi) {
#pragma unroll
    for (int ni = 0; ni < 2; ++ni) {
#pragma unroll
      for (int j = 0; j < 4; ++j) {
        int row = bm + wr + mi * 16 + lhi * 4 + j;   // C/D layout (m89)
        int col = bn + wc + ni * 16 + lr;
        float v = acc[mi][ni][j];
        if (EPI == 1)
          ((float*)Cv)[(size_t)row * ldc + col] = v + ((const float*)Xv)[(size_t)row * ldc + col];
      }
    }
  }
}

// ---------------- LM head GEMM: 256x256 tile, 8 waves, BK=32, 3-buffer pipeline ---
__global__ __launch_bounds__(512, 2) void lm256_kernel(
    const unsigned short* __restrict__ A, const unsigned short* __restrict__ B,
    float* __restrict__ C) {
  __shared__ __align__(16) unsigned short SH[3 * 16384];  // 3 x (A 256x32 | B 256x32)
  const int K = 1024, N = 32000, NT = 32;
  const int tid = threadIdx.x;
  const int wave = tid >> 6, lane = tid & 63;
  const int lr = lane & 15, lg = lane >> 4;
  const int wm = wave >> 2, wn = wave & 3;     // 2M x 4N waves, 128x64 each
  const int d = blockIdx.y * 8 + blockIdx.x;
  const int lgc = (d & 7) * 125 + (d >> 3);
  const int bm = (lgc & 7) * 256;
  const int bn = (lgc >> 3) * 256;
  const unsigned short* Ab = A + (size_t)bm * K;
  const unsigned short* Bb = B + (size_t)bn * K;

  auto stageM = [&](const unsigned short* gbase, unsigned short* lds, int k0) {
#pragma unroll
    for (int j = 0; j < 2; ++j) {
      const int r = j * 128 + wave * 16 + (lane >> 2);
      const int cg = (lane & 3) ^ ((r >> 1) & 3);
      const unsigned short* src = gbase + (size_t)r * K + k0 + cg * 8;
      __builtin_amdgcn_global_load_lds((const AS_G void*)src,
                                       (AS_L void*)(lds + (j * 128 + wave * 16) * 32), 16, 0, 0);
    }
  };
  auto stageT = [&](int tau) {
    unsigned short* base = SH + (tau % 3) * 16384;
    stageM(Ab, base, tau * 32);
    stageM(Bb, base + 8192, tau * 32);
  };

  f32x4v acc[8][4] = {};
  stageT(0);
  stageT(1);
  for (int t = 0; t < NT; ++t) {
    if (t < NT - 1) asm volatile("s_waitcnt vmcnt(4)" ::: "memory");
    else            asm volatile("s_waitcnt vmcnt(0)" ::: "memory");
    asm volatile("s_barrier" ::: "memory");
    if (t + 2 < NT) stageT(t + 2);
    const unsigned short* Al = SH + (t % 3) * 16384;
    const unsigned short* Bl = Al + 8192;
    bf16x8 bfr[4];
#pragma unroll
    for (int ni = 0; ni < 4; ++ni) {
      int row = wn * 64 + ni * 16 + lr;
      bfr[ni] = *(const bf16x8*)&Bl[row * 32 + ((lg ^ ((row >> 1) & 3)) << 3)];
    }
#pragma unroll
    for (int mi = 0; mi < 8; ++mi) {
      int row = wm * 128 + mi * 16 + lr;
      bf16x8 af = *(const bf16x8*)&Al[row * 32 + ((lg ^ ((row >> 1) & 3)) << 3)];
      __builtin_amdgcn_s_setprio(1);
#pragma unroll
      for (int ni = 0; ni < 4; ++ni)
        acc[mi][ni] = __builtin_amdgcn_mfma_f32_16x16x32_bf16(af, bfr[ni], acc[mi][ni], 0, 0, 0);
      __builtin_amdgcn_s_setprio(0);
    }
  }
#pragma unroll
  for (int mi = 0; mi < 8; ++mi)
#pragma unroll
    for (int ni = 0; ni < 4; ++ni)
#pragma unroll
      for (int jj = 0; jj < 4; ++jj) {
        int row = bm + wm * 128 + mi * 16 + lg * 4 + jj;
        int col = bn + wn * 64 + ni * 16 + lr;
        C[(size_t)row * N + col] = fast_softcap30(acc[mi][ni][jj]);
      }
}

// ---------------- fused QKV+OG GEMM (pipelined BK=32) ----------------
__global__ __launch_bounds__(256) void qkvo_kernel(
    const unsigned short* __restrict__ A, const unsigned short* __restrict__ Wq16,
    const unsigned short* __restrict__ Wk16, const unsigned short* __restrict__ Wv16,
    const unsigned short* __restrict__ Wog16,
    unsigned short* __restrict__ qb, unsigned short* __restrict__ kb,
    unsigned short* __restrict__ vTb, float* __restrict__ og) {
  __shared__ __align__(16) unsigned short SH[3 * 8192];  // 48 KB (also vT transpose buf)
  const int tid = threadIdx.x;
  const int wave = tid >> 6, lane = tid & 63;
  const int gx = gridDim.x;                 // 16 (M)
  const int nwg = gx * gridDim.y;           // 384
  const int dd = blockIdx.y * gx + blockIdx.x;
  const int qq = nwg >> 3;
  const int lgc = (dd & 7) * qq + (dd >> 3);
  const int bm = (lgc % gx) * 128;
  const int by = lgc / gx;
  const unsigned short* B;
  int bnl, mode;
  if (by < 4)       { B = Wq16;  bnl = by * 128;        mode = 0; }
  else if (by < 8)  { B = Wk16;  bnl = (by - 4) * 128;  mode = 1; }
  else if (by < 16) { B = Wv16;  bnl = (by - 8) * 128;  mode = 2; }
  else              { B = Wog16; bnl = (by - 16) * 128; mode = 3; }
  const int K = 1024;
  const int wr = (wave >> 1) * 64, wc = (wave & 1) * 64;
  const int lr = lane & 15, lhi = lane >> 4;
  const unsigned short* Ab = A + (size_t)bm * K;
  const unsigned short* Bb = B + (size_t)bnl * K;
  f32x4v acc[4][4] = {};

  auto stageT = [&](int tau) {
    unsigned short* base = SH + (tau % 3) * 8192;
    stage32(Ab, K, base, wave, lane, tau * 32);
    stage32(Bb, K, base + 4096, wave, lane, tau * 32);
  };

  const int NT = 32;
  stageT(0);
  stageT(1);
  for (int t = 0; t < NT; ++t) {
    if (t < NT - 1) asm volatile("s_waitcnt vmcnt(4)" ::: "memory");
    else            asm volatile("s_waitcnt vmcnt(0)" ::: "memory");
    asm volatile("s_barrier" ::: "memory");
    if (t + 2 < NT) stageT(t + 2);
    const unsigned short* Al = SH + (t % 3) * 8192;
    const unsigned short* Bl = Al + 4096;
    bf16x8 af[4], bfr[4];
#pragma unroll
    for (int mi = 0; mi < 4; ++mi) {
      int row = wr + mi * 16 + lr;
      af[mi] = *(const bf16x8*)&Al[row * 32 + ((lhi ^ ((row >> 1) & 3)) << 3)];
    }
#pragma unroll
    for (int ni = 0; ni < 4; ++ni) {
      int row = wc + ni * 16 + lr;
      bfr[ni] = *(const bf16x8*)&Bl[row * 32 + ((lhi ^ ((row >> 1) & 3)) << 3)];
    }
    __builtin_amdgcn_s_setprio(1);
#pragma unroll
    for (int mi = 0; mi < 4; ++mi)
#pragma unroll
      for (int ni = 0; ni < 4; ++ni)
        acc[mi][ni] = __builtin_amdgcn_mfma_f32_16x16x32_bf16(af[mi], bfr[ni], acc[mi][ni], 0, 0, 0);
    __builtin_amdgcn_s_setprio(0);
  }
  if (mode == 2) {
    __syncthreads();  // all waves done reading staging buffers before SH reuse
#pragma unroll
    for (int mi = 0; mi < 4; ++mi)
#pragma unroll
      for (int ni = 0; ni < 4; ++ni)
#pragma unroll
        for (int j = 0; j < 4; ++j) {
          int row = wr + mi * 16 + lhi * 4 + j;
          int col = wc + ni * 16 + lr;
          int byte = col * 256 + ((((row >> 3) ^ (col & 7)) << 4)) + (row & 7) * 2;
          *(unsigned short*)((char*)SH + byte) = bf_us(acc[mi][ni][j]);
        }
    __syncthreads();
#pragma unroll
    for (int i = 0; i < 8; ++i) {
      int c = i * 16 + (tid >> 4);
      int rg = tid & 15;
      u16x8 u = *(const u16x8*)((const char*)SH + c * 256 + ((rg ^ (c & 7)) << 4));
      *(u16x8*)(vTb + (size_t)(bnl + c) * S_LEN + bm + rg * 8) = u;
    }
  } else {
#pragma unroll
    for (int mi = 0; mi < 4; ++mi)
#pragma unroll
      for (int ni = 0; ni < 4; ++ni)
#pragma unroll
        for (int j = 0; j < 4; ++j) {
          int row = bm + wr + mi * 16 + lhi * 4 + j;
          int col = bnl + wc + ni * 16 + lr;
          if (mode == 0)      qb[(size_t)row * 512 + col] = bf_us(acc[mi][ni][j]);
          else if (mode == 1) kb[(size_t)row * 512 + col] = bf_us(acc[mi][ni][j]);
          else                og[(size_t)row * 1024 + col] = acc[mi][ni][j];
        }
  }
}

// ---------------- fused FFN gate+up GEMM (pipelined BK=32, 3 matrices) -------------
__global__ __launch_bounds__(256) void ffn_kernel(
    const unsigned short* __restrict__ A, const unsigned short* __restrict__ Bg,
    const unsigned short* __restrict__ Bu, unsigned short* __restrict__ Gb) {
  __shared__ __align__(16) unsigned short SH[3 * 12288];  // 72 KB
  const int K = 1024;
  const int tid = threadIdx.x;
  const int wave = tid >> 6, lane = tid & 63;
  const int gx = gridDim.x;                 // 16
  const int nwg = gx * gridDim.y;           // 352
  const int dd = blockIdx.y * gx + blockIdx.x;
  const int qq = nwg >> 3;
  const int lgc = (dd & 7) * qq + (dd >> 3);
  const int bm = (lgc % gx) * 128;
  const int bn = (lgc / gx) * 128;
  const int wr = (wave >> 1) * 64, wc = (wave & 1) * 64;
  const int lr = lane & 15, lhi = lane >> 4;
  const unsigned short* Ab = A + (size_t)bm * K;
  const unsigned short* Bgb = Bg + (size_t)bn * K;
  const unsigned short* Bub = Bu + (size_t)bn * K;
  f32x4v accg[4][4] = {};
  f32x4v accu[4][4] = {};

  auto stageT = [&](int tau) {
    unsigned short* base = SH + (tau % 3) * 12288;
    stage32(Ab, K, base, wave, lane, tau * 32);
    stage32(Bgb, K, base + 4096, wave, lane, tau * 32);
    stage32(Bub, K, base + 8192, wave, lane, tau * 32);
  };

  const int NT = 32;
  stageT(0);
  stageT(1);
  for (int t = 0; t < NT; ++t) {
    if (t < NT - 1) asm volatile("s_waitcnt vmcnt(6)" ::: "memory");
    else            asm volatile("s_waitcnt vmcnt(0)" ::: "memory");
    asm volatile("s_barrier" ::: "memory");
    if (t + 2 < NT) stageT(t + 2);
    const unsigned short* Al = SH + (t % 3) * 12288;
    const unsigned short* Bgl = Al + 4096;
    const unsigned short* Bul = Al + 8192;
    bf16x8 af[4], bg[4], bu[4];
#pragma unroll
    for (int mi = 0; mi < 4; ++mi) {
      int row = wr + mi * 16 + lr;
      af[mi] = *(const bf16x8*)&Al[row * 32 + ((lhi ^ ((row >> 1) & 3)) << 3)];
    }
#pragma unroll
    for (int ni = 0; ni < 4; ++ni) {
      int row = wc + ni * 16 + lr;
      int sw = ((lhi ^ ((row >> 1) & 3)) << 3);
      bg[ni] = *(const bf16x8*)&Bgl[row * 32 + sw];
      bu[ni] = *(const bf16x8*)&Bul[row * 32 + sw];
    }
    __builtin_amdgcn_s_setprio(1);
#pragma unroll
    for (int mi = 0; mi < 4; ++mi)
#pragma unroll
      for (int ni = 0; ni < 4; ++ni) {
        accg[mi][ni] = __builtin_amdgcn_mfma_f32_16x16x32_bf16(af[mi], bg[ni], accg[mi][ni], 0, 0, 0);
        accu[mi][ni] = __builtin_amdgcn_mfma_f32_16x16x32_bf16(af[mi], bu[ni], accu[mi][ni], 0, 0, 0);
      }
    __builtin_amdgcn_s_setprio(0);
  }
#pragma unroll
  for (int mi = 0; mi < 4; ++mi) {
#pragma unroll
    for (int ni = 0; ni < 4; ++ni) {
#pragma unroll
      for (int j = 0; j < 4; ++j) {
        int row = bm + wr + mi * 16 + lhi * 4 + j;
        int col = bn + wc + ni * 16 + lr;
        float g = accg[mi][ni][j];
        float sv = g * fast_sigmoid(g) * accu[mi][ni][j];
        Gb[(size_t)row * 2816 + col] = bf_us(sv);
      }
    }
  }
}

// ---------------- gate pre-activations (inline rmsnorm from f32 x) ----------------
__global__ __launch_bounds__(256) void gates_kernel(
    const float* __restrict__ x, const float* __restrict__ n1,
    const float* __restrict__ Wi, const float* __restrict__ bi,
    const float* __restrict__ Wf, const float* __restrict__ bfv,
    float* __restrict__ ipre, float* __restrict__ fpre) {
  int s = blockIdx.x;
  int head = threadIdx.x >> 6, lane = threadIdx.x & 63;
  const float* xr = x + (size_t)s * DMODEL;
  float xv[16];
  float ss = 0.f;
#pragma unroll
  for (int j = 0; j < 16; ++j) { xv[j] = xr[lane + j * 64]; ss += xv[j] * xv[j]; }
#pragma unroll
  for (int off = 32; off > 0; off >>= 1) ss += __shfl_xor(ss, off);
  float scale = rsqrtf(ss * (1.0f / DMODEL) + 1e-6f);
  const float* wi = Wi + head * DMODEL;
  const float* wf = Wf + head * DMODEL;
  float si = 0.f, sf = 0.f;
#pragma unroll
  for (int j = 0; j < 16; ++j) {
    int c = lane + j * 64;
    float xm = xv[j] * scale * n1[c];
    si += xm * wi[c];
    sf += xm * wf[c];
  }
#pragma unroll
  for (int off = 32; off > 0; off >>= 1) {
    si += __shfl_down(si, off);
    sf += __shfl_down(sf, off);
  }
  if (lane == 0) {
    ipre[head * S_LEN + s] = 15.0f * tanhf((si + bi[head]) * (1.0f / 15.0f));
    fpre[head * S_LEN + s] = 15.0f * tanhf((sf + bfv[head]) * (1.0f / 15.0f));
  }
}

// ---------------- per-head scan ----------------
__global__ __launch_bounds__(256) void scan_kernel(
    const float* __restrict__ ipre, const float* __restrict__ fpre,
    float* __restrict__ garr, float* __restrict__ Marr, float* __restrict__ earr) {
  const int h = threadIdx.x >> 6;
  const int lane = threadIdx.x & 63;
  const int base = h * S_LEN + lane * 32;
  float lf[32];
  float lsum = 0.f;
#pragma unroll
  for (int e = 0; e < 32; ++e) {
    float f = fpre[base + e];
    float v = fminf(f, 0.f) - log1pf(expf(-fabsf(f)));
    lf[e] = v;
    lsum += v;
  }
  float scan = lsum;
#pragma unroll
  for (int off = 1; off < 64; off <<= 1) {
    float t = __shfl_up(scan, off);
    if (lane >= off) scan += t;
  }
  float F0 = scan - lsum;
  float gv[32];
  float F = F0, lmax = -1e30f;
#pragma unroll
  for (int e = 0; e < 32; ++e) {
    F += lf[e];
    float g = ipre[base + e] - F;
    gv[e] = g;
    lmax = fmaxf(lmax, g);
    garr[base + e] = g;
  }
  float ms = lmax;
#pragma unroll
  for (int off = 1; off < 64; off <<= 1) {
    float t = __shfl_up(ms, off);
    if (lane >= off) ms = fmaxf(ms, t);
  }
  float em = __shfl_up(ms, 1);
  if (lane == 0) em = -1e30f;
  float run = em;
  F = F0;
#pragma unroll
  for (int e = 0; e < 32; ++e) {
    F += lf[e];
    run = fmaxf(run, gv[e]);
    Marr[base + e] = run;
    earr[base + e] = expf(-(F + run));
  }
}

// ---------------- mLSTM parallel, bf16 MFMA flash-style, s-split x4 ----------------
__global__ __launch_bounds__(256) void mlstm_mfma_kernel(
    const unsigned short* __restrict__ Q, const unsigned short* __restrict__ Kb,
    const unsigned short* __restrict__ vT, const float* __restrict__ garr,
    const float* __restrict__ Marr,
    float* __restrict__ hp, float* __restrict__ npart) {
  const int h = blockIdx.y;
  const int T = blockIdx.x;
  const int sp = blockIdx.z;
  float* hpart = hp + (size_t)sp * 2097152;
  const int tid = threadIdx.x;
  const int w = tid >> 6, l = tid & 63;
  const int lr = l & 15, lg = l >> 4;
  const int hbase = h * S_LEN;
  const int sr = tid >> 4;
  const int sc = tid & 15;

  __shared__ __align__(16) unsigned short Ks[64 * 128];
  __shared__ __align__(16) unsigned short Vs[256 * 64];
  __shared__ __align__(16) unsigned short Ps[64 * 64];

  bf16x8 qf[4];
  {
    const unsigned short* qrow = Q + (size_t)(T * 64 + w * 16 + lr) * 512 + h * 128 + lg * 8;
#pragma unroll
    for (int kt = 0; kt < 4; ++kt) {
      cvu c;
      c.u = *(const u16x8*)(qrow + kt * 32);
      qf[kt] = c.b;
    }
  }
  float Mt[4];
#pragma unroll
  for (int j = 0; j < 4; ++j) Mt[j] = Marr[hbase + T * 64 + w * 16 + lg * 4 + j];

  f32x4v pv[16] = {};
  float nacc[4] = {0.f, 0.f, 0.f, 0.f};
  const float rs = 0.08838834764831845f;  // 1/sqrt(128)

  for (int ch = sp; ch <= T; ch += 4) {
    const int s0 = ch * 64;
    __syncthreads();
#pragma unroll
    for (int i = 0; i < 4; ++i) {
      int r = i * 16 + sr;
      u16x8 u = *(const u16x8*)(Kb + (size_t)(s0 + r) * 512 + h * 128 + sc * 8);
      int byte = r * 256 + ((sc * 16) ^ ((r & 7) << 4));
      *(u16x8*)((char*)Ks + byte) = u;
    }
#pragma unroll
    for (int i = 0; i < 16; ++i) {
      int r = i * 16 + sr;
      u16x4 u = *(const u16x4*)(vT + (size_t)(h * 256 + r) * S_LEN + s0 + sc * 4);
      int byte = r * 128 + ((sc * 8) ^ ((r & 7) << 4));
      *(u16x4*)((char*)Vs + byte) = u;
    }
    __syncthreads();
    f32x4v sa[4] = {};
#pragma unroll
    for (int ni = 0; ni < 4; ++ni) {
#pragma unroll
      for (int kt = 0; kt < 4; ++kt) {
        int row = ni * 16 + lr;
        int byte = row * 256 + (((kt * 32 + lg * 8) * 2) ^ ((row & 7) << 4));
        bf16x8 kf = ld_bf8(Ks, byte);
        sa[ni] = __builtin_amdgcn_mfma_f32_16x16x32_bf16(qf[kt], kf, sa[ni], 0, 0, 0);
      }
    }
#pragma unroll
    for (int ni = 0; ni < 4; ++ni) {
      int sl = ni * 16 + lr;
      int sg = s0 + sl;
      float gv = garr[hbase + sg];
#pragma unroll
      for (int j = 0; j < 4; ++j) {
        int tloc = w * 16 + lg * 4 + j;
        int tg = T * 64 + tloc;
        float wgt = (sg <= tg) ? __expf(gv - Mt[j]) : 0.f;
        float val = sa[ni][j] * rs * wgt;
        nacc[j] += val;
        int byte = tloc * 128 + ((sl * 2) ^ ((tloc & 7) << 4));
        *(unsigned short*)((char*)Ps + byte) = bf_us(val);
      }
    }
#pragma unroll
    for (int kt2 = 0; kt2 < 2; ++kt2) {
      int tloc = w * 16 + lr;
      int sb = (kt2 * 32 + lg * 8) * 2;
      bf16x8 pa = ld_bf8(Ps, tloc * 128 + (sb ^ ((tloc & 7) << 4)));
#pragma unroll
      for (int nv = 0; nv < 16; ++nv) {
        int dv = nv * 16 + lr;
        bf16x8 vb = ld_bf8(Vs, dv * 128 + (sb ^ ((dv & 7) << 4)));
        pv[nv] = __builtin_amdgcn_mfma_f32_16x16x32_bf16(pa, vb, pv[nv], 0, 0, 0);
      }
    }
  }
#pragma unroll
  for (int j = 0; j < 4; ++j) {
#pragma unroll
    for (int off = 1; off < 16; off <<= 1) nacc[j] += __shfl_xor(nacc[j], off);
  }
#pragma unroll
  for (int j = 0; j < 4; ++j) {
    int tg = T * 64 + w * 16 + lg * 4 + j;
    if (lr == 0) npart[sp * 8192 + hbase + tg] = nacc[j];
    float* orow = hpart + (size_t)tg * DMODEL + h * 256;
#pragma unroll
    for (int nvt = 0; nvt < 16; ++nvt) orow[nvt * 16 + lr] = pv[nvt][j];
  }
}

// ---------------- combine(4) + multihead LayerNorm * mhw * sigmoid(og) -> bf16 ----
__global__ __launch_bounds__(256) void mhln_gate_kernel(
    const float* __restrict__ hp, const float* __restrict__ npart,
    const float* __restrict__ earr, const float* __restrict__ mhw,
    const float* __restrict__ og, unsigned short* __restrict__ gact) {
  int s = blockIdx.x;
  int head = threadIdx.x >> 6, lane = threadIdx.x & 63;
  float n = (npart[head * S_LEN + s] + npart[8192 + head * S_LEN + s]) +
            (npart[16384 + head * S_LEN + s] + npart[24576 + head * S_LEN + s]);
  float nvv = fmaxf(fabsf(n), earr[head * S_LEN + s]);
  float inv = 1.0f / (nvv + 1e-6f);
  const size_t base = (size_t)s * DMODEL + head * 256;
  float vq[4];
#pragma unroll
  for (int qy = 0; qy < 4; ++qy) {
    size_t o = base + qy * 64 + lane;
    vq[qy] = ((hp[o] + hp[o + 2097152]) + (hp[o + 4194304] + hp[o + 6291456])) * inv;
  }
  float sum = vq[0] + vq[1] + vq[2] + vq[3];
#pragma unroll
  for (int off = 32; off > 0; off >>= 1) sum += __shfl_xor(sum, off);
  float mu = sum * (1.0f / 256.0f);
  float d0 = vq[0] - mu, d1 = vq[1] - mu, d2 = vq[2] - mu, d3 = vq[3] - mu;
  float vs = d0 * d0 + d1 * d1 + d2 * d2 + d3 * d3;
#pragma unroll
  for (int off = 32; off > 0; off >>= 1) vs += __shfl_xor(vs, off);
  float rstd = rsqrtf(vs * (1.0f / 256.0f) + 1e-6f);
  float dn[4] = {d0, d1, d2, d3};
#pragma unroll
  for (int qy = 0; qy < 4; ++qy) {
    int c = head * 256 + qy * 64 + lane;
    float ov = og[(size_t)s * DMODEL + c];
    gact[(size_t)s * DMODEL + c] = bf_us(dn[qy] * rstd * mhw[c] * fast_sigmoid(ov));
  }
}

extern "C" void kernel_launch(void* const* d_in, const int* in_sizes, int n_in,
                              void* d_out, int out_size, void* d_ws, size_t ws_size,
                              hipStream_t stream) {
  (void)in_sizes; (void)n_in; (void)out_size; (void)ws_size;
  const int*   tok   = (const int*)d_in[0];
  const float* emb   = (const float*)d_in[1];
  const float* norm1 = (const float*)d_in[2];
  const float* Wq    = (const float*)d_in[3];
  const float* Wk    = (const float*)d_in[4];
  const float* Wv    = (const float*)d_in[5];
  const float* Wog   = (const float*)d_in[6];
  const float* Wi    = (const float*)d_in[7];
  const float* bi    = (const float*)d_in[8];
  const float* Wf    = (const float*)d_in[9];
  const float* bfp   = (const float*)d_in[10];
  const float* mhw   = (const float*)d_in[11];
  const float* Wout  = (const float*)d_in[12];
  const float* norm2 = (const float*)d_in[13];
  const float* Wg    = (const float*)d_in[14];
  const float* Wu    = (const float*)d_in[15];
  const float* Wd    = (const float*)d_in[16];
  const float* onw   = (const float*)d_in[17];
  const float* Wlm   = (const float*)d_in[18];

  char* wsb = (char*)d_ws;
  const size_t MB = 1ull << 20;
  float*          x    = (float*)wsb;                          // 8 MiB
  unsigned short* xmb  = (unsigned short*)(wsb + 8 * MB);      // 4 MiB
  float*          ipre = (float*)(wsb + 12 * MB);              // scalars region
  float*          fpre = ipre + 8192;
  float*          garr = fpre + 8192;
  float*          Marr = garr + 8192;
  float*          earr = Marr + 8192;
  float*          npart = earr + 8192;                         // 4 x 32 KiB
  unsigned short* W16  = (unsigned short*)(wsb + 13 * MB);     // 49 MiB -> ends 62
  const size_t OQ = 0, OKk = 524288, OV = 1048576, OOG = 2097152, OOUT = 3145728,
               OGt = 4194304, OU = 7077888, OD = 9961472;
  unsigned short* qb    = (unsigned short*)(wsb + 62 * MB);    // 2 MiB
  unsigned short* kb    = (unsigned short*)(wsb + 64 * MB);    // 2 MiB
  unsigned short* vTb   = (unsigned short*)(wsb + 66 * MB);    // 4 MiB
  float*          og    = (float*)(wsb + 70 * MB);             // 8 MiB
  float*          hp    = (float*)(wsb + 78 * MB);             // 4 x 8 MiB -> ends 110
  unsigned short* gact  = (unsigned short*)(wsb + 110 * MB);   // 4 MiB
  unsigned short* Gb16  = (unsigned short*)(wsb + 114 * MB);   // 11 MiB -> ends 125
  unsigned short* wlm16 = (unsigned short*)(wsb + 126 * MB);   // 62.5 MiB -> ends 188.5

  embed_kernel<<<2048, 256, 0, stream>>>(tok, emb, x);
  wcvt8_kernel<<<28544, 256, 0, stream>>>(Wq, Wk, Wv, Wog, Wout, Wg, Wu, Wd, Wlm,
                                          W16, wlm16);

  for (int l = 0; l < 2; ++l) {
    const unsigned short* Wl = W16 + (size_t)l * WLAYER;
    const float* n1   = norm1 + (size_t)l * 1024;
    const float* wiv  = Wi   + (size_t)l * 4 * 1024;
    const float* bil  = bi   + (size_t)l * 4;
    const float* wfv  = Wf   + (size_t)l * 4 * 1024;
    const float* bfl  = bfp  + (size_t)l * 4;
    const float* mhwl = mhw  + (size_t)l * 1024;
    const float* n2   = norm2 + (size_t)l * 1024;

    rmsnorm_kernel<<<2048, 256, 0, stream>>>(x, n1, xmb);
    qkvo_kernel<<<dim3(16, 24), 256, 0, stream>>>(xmb, Wl + OQ, Wl + OKk, Wl + OV,
                                                  Wl + OOG, qb, kb, vTb, og);
    gates_kernel<<<2048, 256, 0, stream>>>(x, n1, wiv, bil, wfv, bfl, ipre, fpre);
    scan_kernel<<<1, 256, 0, stream>>>(ipre, fpre, garr, Marr, earr);
    mlstm_mfma_kernel<<<dim3(32, 4, 4), 256, 0, stream>>>(qb, kb, vTb, garr, Marr,
                                                          hp, npart);
    mhln_gate_kernel<<<2048, 256, 0, stream>>>(hp, npart, earr, mhwl, og, gact);
    gemm_bn64_kernel<1><<<dim3(16, 16), 256, 0, stream>>>(gact, Wl + OOUT, x, x, 1024, 1024);
    rmsnorm_kernel<<<2048, 256, 0, stream>>>(x, n2, xmb);
    ffn_kernel<<<dim3(16, 22), 256, 0, stream>>>(xmb, Wl + OGt, Wl + OU, Gb16);
    gemm_bn64_kernel<1><<<dim3(16, 16), 256, 0, stream>>>(Gb16, Wl + OD, x, x, 2816, 1024);
  }

  rmsnorm_kernel<<<2048, 256, 0, stream>>>(x, onw, xmb);
  lm256_kernel<<<dim3(8, 125), 512, 0, stream>>>(xmb, wlm16, (float*)d_out);
}

// Round 19
// 650.917 us; speedup vs baseline: 1.3541x; 1.0496x over previous
//
#include <hip/hip_runtime.h>
#include <hip/hip_bf16.h>
#include <math.h>

// xLSTM-Large forward: S=2048, D=1024, NH=4 (Dqk=128, Dv=256), UP=2752, L=2, V=32000.
// All GEMMs on the proven BK=32 / 3-buffer / counted-vmcnt pipeline.
// This round: ffn moved to 128x64 tiles (704 blocks = 2.75/CU, 48 KB LDS ->
// 3 blocks/CU co-resident; previously 352 blocks = imbalanced 1.375/CU).

#define S_LEN 2048
#define DMODEL 1024
#define WLAYER 12845056  // elements per layer in W16

typedef __attribute__((ext_vector_type(8))) __bf16 bf16x8;
typedef __attribute__((ext_vector_type(8))) unsigned short u16x8;
typedef __attribute__((ext_vector_type(4))) unsigned short u16x4;
typedef __attribute__((ext_vector_type(4))) float f32x4v;

union cvu { u16x8 u; bf16x8 b; };

__device__ __forceinline__ unsigned short bf_us(float f) {
  union { __bf16 b; unsigned short u; } c;
  c.b = (__bf16)f;   // RNE, native v_cvt on gfx950
  return c.u;
}
__device__ __forceinline__ float us_f(unsigned short u) {
  union { __bf16 b; unsigned short u; } c;
  c.u = u;
  return (float)c.b;
}
__device__ __forceinline__ bf16x8 ld_bf8(const unsigned short* p, int byte_off) {
  cvu c;
  c.u = *(const u16x8*)((const char*)p + byte_off);
  return c.b;
}
__device__ __forceinline__ float fast_sigmoid(float v) {
  return 1.0f / (1.0f + __expf(-v));
}
__device__ __forceinline__ float fast_softcap30(float v) {
  float e = __expf(-fabsf(v) * (1.0f / 15.0f));  // e^{-2|v|/30}
  float t = (1.0f - e) / (1.0f + e);             // tanh(|v|/30)
  return copysignf(30.0f * t, v);
}

#define AS_G __attribute__((address_space(1)))
#define AS_L __attribute__((address_space(3)))

// Stage a 128x32 bf16 tile (8 KB) into linear LDS: 2 issues of 4 KB (64 rows).
// Source col-group pre-swizzled (cg ^= (row>>1)&3); matching XOR on read.
__device__ __forceinline__ void stage32(const unsigned short* gbase, int K,
                                        unsigned short* lds, int wave, int lane, int k0) {
#pragma unroll
  for (int j = 0; j < 2; ++j) {
    const int r = j * 64 + wave * 16 + (lane >> 2);
    const int cg = (lane & 3) ^ ((r >> 1) & 3);
    const unsigned short* src = gbase + (size_t)r * K + k0 + cg * 8;
    __builtin_amdgcn_global_load_lds((const AS_G void*)src,
                                     (AS_L void*)(lds + (j * 64 + wave * 16) * 32), 16, 0, 0);
  }
}

// Stage a 64x32 bf16 tile (4 KB) = exactly 1 issue for 256 threads.
__device__ __forceinline__ void stage32h(const unsigned short* gbase, int K,
                                         unsigned short* lds, int wave, int lane, int k0) {
  const int r = wave * 16 + (lane >> 2);
  const int cg = (lane & 3) ^ ((r >> 1) & 3);
  const unsigned short* src = gbase + (size_t)r * K + k0 + cg * 8;
  __builtin_amdgcn_global_load_lds((const AS_G void*)src,
                                   (AS_L void*)(lds + (wave * 16) * 32), 16, 0, 0);
}

// ---------------- embed ----------------
__global__ __launch_bounds__(256) void embed_kernel(
    const int* __restrict__ tok, const float* __restrict__ emb, float* __restrict__ x) {
  int s = blockIdx.x;
  int t = tok[s];
  const float4 v = *(const float4*)(emb + (size_t)t * DMODEL + threadIdx.x * 4);
  *(float4*)(x + (size_t)s * DMODEL + threadIdx.x * 4) = v;
}

// ---------------- rmsnorm (row = 1024): writes bf16 ----------------
__global__ __launch_bounds__(256) void rmsnorm_kernel(
    const float* __restrict__ x, const float* __restrict__ w,
    unsigned short* __restrict__ outb) {
  int s = blockIdx.x, tid = threadIdx.x;
  const float* xr = x + (size_t)s * DMODEL;
  float4 v = *(const float4*)(xr + tid * 4);
  float ss = v.x * v.x + v.y * v.y + v.z * v.z + v.w * v.w;
#pragma unroll
  for (int off = 32; off > 0; off >>= 1) ss += __shfl_down(ss, off);
  __shared__ float red[4];
  if ((tid & 63) == 0) red[tid >> 6] = ss;
  __syncthreads();
  float tot = red[0] + red[1] + red[2] + red[3];
  float scale = rsqrtf(tot * (1.0f / DMODEL) + 1e-6f);
  float4 wv = *(const float4*)(w + tid * 4);
  u16x4 ub;
  ub[0] = bf_us(v.x * scale * wv.x);
  ub[1] = bf_us(v.y * scale * wv.y);
  ub[2] = bf_us(v.z * scale * wv.z);
  ub[3] = bf_us(v.w * scale * wv.w);
  *(u16x4*)(outb + (size_t)s * DMODEL + tid * 4) = ub;
}

// ---------------- weight convert f32 -> bf16: both layers + LM head --------------
__global__ __launch_bounds__(256) void wcvt8_kernel(
    const float* __restrict__ Wq, const float* __restrict__ Wk,
    const float* __restrict__ Wv, const float* __restrict__ Wog,
    const float* __restrict__ Wout, const float* __restrict__ Wg,
    const float* __restrict__ Wu, const float* __restrict__ Wd,
    const float* __restrict__ Wlm,
    unsigned short* __restrict__ W, unsigned short* __restrict__ Wlm16) {
  const size_t de = ((size_t)blockIdx.x * 256 + threadIdx.x) * 8;
  if (de >= 2ull * WLAYER) {  // LM head region
    size_t i = de - 2ull * WLAYER;
    float4 a0 = *(const float4*)(Wlm + i);
    float4 a1 = *(const float4*)(Wlm + i + 4);
    u16x8 o;
    o[0] = bf_us(a0.x); o[1] = bf_us(a0.y); o[2] = bf_us(a0.z); o[3] = bf_us(a0.w);
    o[4] = bf_us(a1.x); o[5] = bf_us(a1.y); o[6] = bf_us(a1.z); o[7] = bf_us(a1.w);
    *(u16x8*)(Wlm16 + i) = o;
    return;
  }
  int e = (int)de, l = 0;
  if (e >= WLAYER) { l = 1; e -= WLAYER; }
  const float* src = nullptr;
  size_t idx = 0;
  if (e < 524288)       { src = Wq  + (size_t)l * 524288;  idx = e; }
  else if (e < 1048576) { src = Wk  + (size_t)l * 524288;  idx = e - 524288; }
  else if (e < 2097152) { src = Wv  + (size_t)l * 1048576; idx = e - 1048576; }
  else if (e < 3145728) { src = Wog + (size_t)l * 1048576; idx = e - 2097152; }
  else if (e < 4194304) { src = Wout + (size_t)l * 1048576; idx = e - 3145728; }
  else if (e < 7077888) {
    int t = e - 4194304, row = t >> 10;
    if (row < 2752) { src = Wg + (size_t)l * 2818048; idx = t; }
  } else if (e < 9961472) {
    int t = e - 7077888, row = t >> 10;
    if (row < 2752) { src = Wu + (size_t)l * 2818048; idx = t; }
  } else {
    int t = e - 9961472, row = t / 2816, col = t - row * 2816;
    if (col < 2752) { src = Wd + (size_t)l * 2818048; idx = row * 2752 + col; }
  }
  u16x8 o;
  if (src) {
    float4 a0 = *(const float4*)(src + idx);
    float4 a1 = *(const float4*)(src + idx + 4);
    o[0] = bf_us(a0.x); o[1] = bf_us(a0.y); o[2] = bf_us(a0.z); o[3] = bf_us(a0.w);
    o[4] = bf_us(a1.x); o[5] = bf_us(a1.y); o[6] = bf_us(a1.z); o[7] = bf_us(a1.w);
  } else {
#pragma unroll
    for (int k = 0; k < 8; ++k) o[k] = 0;
  }
  *(u16x8*)(W + de) = o;
}

// ---------------- GEMM: 128x64 tile, BK=32, 3-buffer pipeline -----------------
// 256 blocks for N=1024 outputs -> 1 block/CU (full GPU). 4 waves as 2M x 2N
// (per-wave 64x32, acc[4][2], 8 MFMA/K-tile). 3 loads/tile (A 2 + B 1):
// steady vmcnt(3) drains exactly tile t; tail vmcnt(0). 36 KB LDS, buffer t%3.
// EPI: 1 f32 acc+X residual
template <int EPI>
__global__ __launch_bounds__(256) void gemm_bn64_kernel(
    const unsigned short* __restrict__ A, const unsigned short* __restrict__ B,
    const void* Xv, void* Cv, int K, int ldc) {
  __shared__ __align__(16) unsigned short SH[3 * 6144];  // 3 x (A 128x32 | B 64x32)
  const int tid = threadIdx.x;
  const int wave = tid >> 6, lane = tid & 63;
  const int gx = gridDim.x;
  const int nwg = gx * gridDim.y;
  const int d = blockIdx.y * gx + blockIdx.x;
  const int q = nwg >> 3;
  const int lgc = (d & 7) * q + (d >> 3);
  const int bm = (lgc % gx) * 128, bn = (lgc / gx) * 64;
  const int wr = (wave >> 1) * 64, wc = (wave & 1) * 32;
  const int lr = lane & 15, lhi = lane >> 4;
  const unsigned short* Ab = A + (size_t)bm * K;
  const unsigned short* Bb = B + (size_t)bn * K;
  f32x4v acc[4][2] = {};

  auto stageT = [&](int tau) {
    unsigned short* base = SH + (tau % 3) * 6144;
    stage32(Ab, K, base, wave, lane, tau * 32);
    stage32h(Bb, K, base + 4096, wave, lane, tau * 32);
  };

  const int NT = K >> 5;
  stageT(0);
  stageT(1);
  for (int t = 0; t < NT; ++t) {
    if (t < NT - 1) asm volatile("s_waitcnt vmcnt(3)" ::: "memory");
    else            asm volatile("s_waitcnt vmcnt(0)" ::: "memory");
    asm volatile("s_barrier" ::: "memory");
    if (t + 2 < NT) stageT(t + 2);
    const unsigned short* Al = SH + (t % 3) * 6144;
    const unsigned short* Bl = Al + 4096;
    bf16x8 af[4], bfr[2];
#pragma unroll
    for (int mi = 0; mi < 4; ++mi) {
      int row = wr + mi * 16 + lr;
      af[mi] = *(const bf16x8*)&Al[row * 32 + ((lhi ^ ((row >> 1) & 3)) << 3)];
    }
#pragma unroll
    for (int ni = 0; ni < 2; ++ni) {
      int row = wc + ni * 16 + lr;
      bfr[ni] = *(const bf16x8*)&Bl[row * 32 + ((lhi ^ ((row >> 1) & 3)) << 3)];
    }
    __builtin_amdgcn_s_setprio(1);
#pragma unroll
    for (int mi = 0; mi < 4; ++mi)
#pragma unroll
      for (int ni = 0; ni < 2; ++ni)
        acc[mi][ni] = __builtin_amdgcn_mfma_f32_16x16x32_bf16(af[mi], bfr[ni], acc[mi][ni], 0, 0, 0);
    __builtin_amdgcn_s_setprio(0);
  }
#pragma unroll
  for (int mi = 0; mi < 4; ++mi) {
#pragma unroll
    for (int ni = 0; ni < 2; ++ni) {
#pragma unroll
      for (int j = 0; j < 4; ++j) {
        int row = bm + wr + mi * 16 + lhi * 4 + j;   // C/D layout (m89)
        int col = bn + wc + ni * 16 + lr;
        float v = acc[mi][ni][j];
        if (EPI == 1)
          ((float*)Cv)[(size_t)row * ldc + col] = v + ((const float*)Xv)[(size_t)row * ldc + col];
      }
    }
  }
}

// ---------------- LM head GEMM: 256x256 tile, 8 waves, BK=32, 3-buffer pipeline ---
__global__ __launch_bounds__(512, 2) void lm256_kernel(
    const unsigned short* __restrict__ A, const unsigned short* __restrict__ B,
    float* __restrict__ C) {
  __shared__ __align__(16) unsigned short SH[3 * 16384];  // 3 x (A 256x32 | B 256x32)
  const int K = 1024, N = 32000, NT = 32;
  const int tid = threadIdx.x;
  const int wave = tid >> 6, lane = tid & 63;
  const int lr = lane & 15, lg = lane >> 4;
  const int wm = wave >> 2, wn = wave & 3;     // 2M x 4N waves, 128x64 each
  const int d = blockIdx.y * 8 + blockIdx.x;
  const int lgc = (d & 7) * 125 + (d >> 3);
  const int bm = (lgc & 7) * 256;
  const int bn = (lgc >> 3) * 256;
  const unsigned short* Ab = A + (size_t)bm * K;
  const unsigned short* Bb = B + (size_t)bn * K;

  auto stageM = [&](const unsigned short* gbase, unsigned short* lds, int k0) {
#pragma unroll
    for (int j = 0; j < 2; ++j) {
      const int r = j * 128 + wave * 16 + (lane >> 2);
      const int cg = (lane & 3) ^ ((r >> 1) & 3);
      const unsigned short* src = gbase + (size_t)r * K + k0 + cg * 8;
      __builtin_amdgcn_global_load_lds((const AS_G void*)src,
                                       (AS_L void*)(lds + (j * 128 + wave * 16) * 32), 16, 0, 0);
    }
  };
  auto stageT = [&](int tau) {
    unsigned short* base = SH + (tau % 3) * 16384;
    stageM(Ab, base, tau * 32);
    stageM(Bb, base + 8192, tau * 32);
  };

  f32x4v acc[8][4] = {};
  stageT(0);
  stageT(1);
  for (int t = 0; t < NT; ++t) {
    if (t < NT - 1) asm volatile("s_waitcnt vmcnt(4)" ::: "memory");
    else            asm volatile("s_waitcnt vmcnt(0)" ::: "memory");
    asm volatile("s_barrier" ::: "memory");
    if (t + 2 < NT) stageT(t + 2);
    const unsigned short* Al = SH + (t % 3) * 16384;
    const unsigned short* Bl = Al + 8192;
    bf16x8 bfr[4];
#pragma unroll
    for (int ni = 0; ni < 4; ++ni) {
      int row = wn * 64 + ni * 16 + lr;
      bfr[ni] = *(const bf16x8*)&Bl[row * 32 + ((lg ^ ((row >> 1) & 3)) << 3)];
    }
#pragma unroll
    for (int mi = 0; mi < 8; ++mi) {
      int row = wm * 128 + mi * 16 + lr;
      bf16x8 af = *(const bf16x8*)&Al[row * 32 + ((lg ^ ((row >> 1) & 3)) << 3)];
      __builtin_amdgcn_s_setprio(1);
#pragma unroll
      for (int ni = 0; ni < 4; ++ni)
        acc[mi][ni] = __builtin_amdgcn_mfma_f32_16x16x32_bf16(af, bfr[ni], acc[mi][ni], 0, 0, 0);
      __builtin_amdgcn_s_setprio(0);
    }
  }
#pragma unroll
  for (int mi = 0; mi < 8; ++mi)
#pragma unroll
    for (int ni = 0; ni < 4; ++ni)
#pragma unroll
      for (int jj = 0; jj < 4; ++jj) {
        int row = bm + wm * 128 + mi * 16 + lg * 4 + jj;
        int col = bn + wn * 64 + ni * 16 + lr;
        C[(size_t)row * N + col] = fast_softcap30(acc[mi][ni][jj]);
      }
}

// ---------------- fused QKV+OG GEMM (pipelined BK=32) ----------------
__global__ __launch_bounds__(256) void qkvo_kernel(
    const unsigned short* __restrict__ A, const unsigned short* __restrict__ Wq16,
    const unsigned short* __restrict__ Wk16, const unsigned short* __restrict__ Wv16,
    const unsigned short* __restrict__ Wog16,
    unsigned short* __restrict__ qb, unsigned short* __restrict__ kb,
    unsigned short* __restrict__ vTb, float* __restrict__ og) {
  __shared__ __align__(16) unsigned short SH[3 * 8192];  // 48 KB (also vT transpose buf)
  const int tid = threadIdx.x;
  const int wave = tid >> 6, lane = tid & 63;
  const int gx = gridDim.x;                 // 16 (M)
  const int nwg = gx * gridDim.y;           // 384
  const int dd = blockIdx.y * gx + blockIdx.x;
  const int qq = nwg >> 3;
  const int lgc = (dd & 7) * qq + (dd >> 3);
  const int bm = (lgc % gx) * 128;
  const int by = lgc / gx;
  const unsigned short* B;
  int bnl, mode;
  if (by < 4)       { B = Wq16;  bnl = by * 128;        mode = 0; }
  else if (by < 8)  { B = Wk16;  bnl = (by - 4) * 128;  mode = 1; }
  else if (by < 16) { B = Wv16;  bnl = (by - 8) * 128;  mode = 2; }
  else              { B = Wog16; bnl = (by - 16) * 128; mode = 3; }
  const int K = 1024;
  const int wr = (wave >> 1) * 64, wc = (wave & 1) * 64;
  const int lr = lane & 15, lhi = lane >> 4;
  const unsigned short* Ab = A + (size_t)bm * K;
  const unsigned short* Bb = B + (size_t)bnl * K;
  f32x4v acc[4][4] = {};

  auto stageT = [&](int tau) {
    unsigned short* base = SH + (tau % 3) * 8192;
    stage32(Ab, K, base, wave, lane, tau * 32);
    stage32(Bb, K, base + 4096, wave, lane, tau * 32);
  };

  const int NT = 32;
  stageT(0);
  stageT(1);
  for (int t = 0; t < NT; ++t) {
    if (t < NT - 1) asm volatile("s_waitcnt vmcnt(4)" ::: "memory");
    else            asm volatile("s_waitcnt vmcnt(0)" ::: "memory");
    asm volatile("s_barrier" ::: "memory");
    if (t + 2 < NT) stageT(t + 2);
    const unsigned short* Al = SH + (t % 3) * 8192;
    const unsigned short* Bl = Al + 4096;
    bf16x8 af[4], bfr[4];
#pragma unroll
    for (int mi = 0; mi < 4; ++mi) {
      int row = wr + mi * 16 + lr;
      af[mi] = *(const bf16x8*)&Al[row * 32 + ((lhi ^ ((row >> 1) & 3)) << 3)];
    }
#pragma unroll
    for (int ni = 0; ni < 4; ++ni) {
      int row = wc + ni * 16 + lr;
      bfr[ni] = *(const bf16x8*)&Bl[row * 32 + ((lhi ^ ((row >> 1) & 3)) << 3)];
    }
    __builtin_amdgcn_s_setprio(1);
#pragma unroll
    for (int mi = 0; mi < 4; ++mi)
#pragma unroll
      for (int ni = 0; ni < 4; ++ni)
        acc[mi][ni] = __builtin_amdgcn_mfma_f32_16x16x32_bf16(af[mi], bfr[ni], acc[mi][ni], 0, 0, 0);
    __builtin_amdgcn_s_setprio(0);
  }
  if (mode == 2) {
    __syncthreads();  // all waves done reading staging buffers before SH reuse
#pragma unroll
    for (int mi = 0; mi < 4; ++mi)
#pragma unroll
      for (int ni = 0; ni < 4; ++ni)
#pragma unroll
        for (int j = 0; j < 4; ++j) {
          int row = wr + mi * 16 + lhi * 4 + j;
          int col = wc + ni * 16 + lr;
          int byte = col * 256 + ((((row >> 3) ^ (col & 7)) << 4)) + (row & 7) * 2;
          *(unsigned short*)((char*)SH + byte) = bf_us(acc[mi][ni][j]);
        }
    __syncthreads();
#pragma unroll
    for (int i = 0; i < 8; ++i) {
      int c = i * 16 + (tid >> 4);
      int rg = tid & 15;
      u16x8 u = *(const u16x8*)((const char*)SH + c * 256 + ((rg ^ (c & 7)) << 4));
      *(u16x8*)(vTb + (size_t)(bnl + c) * S_LEN + bm + rg * 8) = u;
    }
  } else {
#pragma unroll
    for (int mi = 0; mi < 4; ++mi)
#pragma unroll
      for (int ni = 0; ni < 4; ++ni)
#pragma unroll
        for (int j = 0; j < 4; ++j) {
          int row = bm + wr + mi * 16 + lhi * 4 + j;
          int col = bnl + wc + ni * 16 + lr;
          if (mode == 0)      qb[(size_t)row * 512 + col] = bf_us(acc[mi][ni][j]);
          else if (mode == 1) kb[(size_t)row * 512 + col] = bf_us(acc[mi][ni][j]);
          else                og[(size_t)row * 1024 + col] = acc[mi][ni][j];
        }
  }
}

// ---------------- fused FFN gate+up GEMM: 128x64 tiles, BK=32, 3-buffer ------------
// Grid 16x44 = 704 blocks (2.75/CU); per buffer A 8KB + Bg 4KB + Bu 4KB = 16 KB,
// x3 = 48 KB -> 3 blocks/CU. 4 loads/tile -> steady vmcnt(4); tail vmcnt(0).
// 4 waves as 2M x 2N (per-wave 64x32); 16 MFMA/tile (8 g + 8 u).
__global__ __launch_bounds__(256) void ffn_kernel(
    const unsigned short* __restrict__ A, const unsigned short* __restrict__ Bg,
    const unsigned short* __restrict__ Bu, unsigned short* __restrict__ Gb) {
  __shared__ __align__(16) unsigned short SH[3 * 8192];  // 48 KB
  const int K = 1024;
  const int tid = threadIdx.x;
  const int wave = tid >> 6, lane = tid & 63;
  const int gx = gridDim.x;                 // 16
  const int nwg = gx * gridDim.y;           // 704
  const int dd = blockIdx.y * gx + blockIdx.x;
  const int qq = nwg >> 3;
  const int lgc = (dd & 7) * qq + (dd >> 3);
  const int bm = (lgc % gx) * 128;
  const int bn = (lgc / gx) * 64;
  const int wr = (wave >> 1) * 64, wc = (wave & 1) * 32;
  const int lr = lane & 15, lhi = lane >> 4;
  const unsigned short* Ab = A + (size_t)bm * K;
  const unsigned short* Bgb = Bg + (size_t)bn * K;
  const unsigned short* Bub = Bu + (size_t)bn * K;
  f32x4v accg[4][2] = {};
  f32x4v accu[4][2] = {};

  auto stageT = [&](int tau) {
    unsigned short* base = SH + (tau % 3) * 8192;
    stage32(Ab, K, base, wave, lane, tau * 32);
    stage32h(Bgb, K, base + 4096, wave, lane, tau * 32);
    stage32h(Bub, K, base + 6144, wave, lane, tau * 32);
  };

  const int NT = 32;
  stageT(0);
  stageT(1);
  for (int t = 0; t < NT; ++t) {
    if (t < NT - 1) asm volatile("s_waitcnt vmcnt(4)" ::: "memory");
    else            asm volatile("s_waitcnt vmcnt(0)" ::: "memory");
    asm volatile("s_barrier" ::: "memory");
    if (t + 2 < NT) stageT(t + 2);
    const unsigned short* Al = SH + (t % 3) * 8192;
    const unsigned short* Bgl = Al + 4096;
    const unsigned short* Bul = Al + 6144;
    bf16x8 af[4], bg[2], bu[2];
#pragma unroll
    for (int mi = 0; mi < 4; ++mi) {
      int row = wr + mi * 16 + lr;
      af[mi] = *(const bf16x8*)&Al[row * 32 + ((lhi ^ ((row >> 1) & 3)) << 3)];
    }
#pragma unroll
    for (int ni = 0; ni < 2; ++ni) {
      int row = wc + ni * 16 + lr;
      int sw = ((lhi ^ ((row >> 1) & 3)) << 3);
      bg[ni] = *(const bf16x8*)&Bgl[row * 32 + sw];
      bu[ni] = *(const bf16x8*)&Bul[row * 32 + sw];
    }
    __builtin_amdgcn_s_setprio(1);
#pragma unroll
    for (int mi = 0; mi < 4; ++mi)
#pragma unroll
      for (int ni = 0; ni < 2; ++ni) {
        accg[mi][ni] = __builtin_amdgcn_mfma_f32_16x16x32_bf16(af[mi], bg[ni], accg[mi][ni], 0, 0, 0);
        accu[mi][ni] = __builtin_amdgcn_mfma_f32_16x16x32_bf16(af[mi], bu[ni], accu[mi][ni], 0, 0, 0);
      }
    __builtin_amdgcn_s_setprio(0);
  }
#pragma unroll
  for (int mi = 0; mi < 4; ++mi) {
#pragma unroll
    for (int ni = 0; ni < 2; ++ni) {
#pragma unroll
      for (int j = 0; j < 4; ++j) {
        int row = bm + wr + mi * 16 + lhi * 4 + j;
        int col = bn + wc + ni * 16 + lr;
        float g = accg[mi][ni][j];
        float sv = g * fast_sigmoid(g) * accu[mi][ni][j];
        Gb[(size_t)row * 2816 + col] = bf_us(sv);
      }
    }
  }
}

// ---------------- gate pre-activations (inline rmsnorm from f32 x) ----------------
__global__ __launch_bounds__(256) void gates_kernel(
    const float* __restrict__ x, const float* __restrict__ n1,
    const float* __restrict__ Wi, const float* __restrict__ bi,
    const float* __restrict__ Wf, const float* __restrict__ bfv,
    float* __restrict__ ipre, float* __restrict__ fpre) {
  int s = blockIdx.x;
  int head = threadIdx.x >> 6, lane = threadIdx.x & 63;
  const float* xr = x + (size_t)s * DMODEL;
  float xv[16];
  float ss = 0.f;
#pragma unroll
  for (int j = 0; j < 16; ++j) { xv[j] = xr[lane + j * 64]; ss += xv[j] * xv[j]; }
#pragma unroll
  for (int off = 32; off > 0; off >>= 1) ss += __shfl_xor(ss, off);
  float scale = rsqrtf(ss * (1.0f / DMODEL) + 1e-6f);
  const float* wi = Wi + head * DMODEL;
  const float* wf = Wf + head * DMODEL;
  float si = 0.f, sf = 0.f;
#pragma unroll
  for (int j = 0; j < 16; ++j) {
    int c = lane + j * 64;
    float xm = xv[j] * scale * n1[c];
    si += xm * wi[c];
    sf += xm * wf[c];
  }
#pragma unroll
  for (int off = 32; off > 0; off >>= 1) {
    si += __shfl_down(si, off);
    sf += __shfl_down(sf, off);
  }
  if (lane == 0) {
    ipre[head * S_LEN + s] = 15.0f * tanhf((si + bi[head]) * (1.0f / 15.0f));
    fpre[head * S_LEN + s] = 15.0f * tanhf((sf + bfv[head]) * (1.0f / 15.0f));
  }
}

// ---------------- per-head scan ----------------
__global__ __launch_bounds__(256) void scan_kernel(
    const float* __restrict__ ipre, const float* __restrict__ fpre,
    float* __restrict__ garr, float* __restrict__ Marr, float* __restrict__ earr) {
  const int h = threadIdx.x >> 6;
  const int lane = threadIdx.x & 63;
  const int base = h * S_LEN + lane * 32;
  float lf[32];
  float lsum = 0.f;
#pragma unroll
  for (int e = 0; e < 32; ++e) {
    float f = fpre[base + e];
    float v = fminf(f, 0.f) - log1pf(expf(-fabsf(f)));
    lf[e] = v;
    lsum += v;
  }
  float scan = lsum;
#pragma unroll
  for (int off = 1; off < 64; off <<= 1) {
    float t = __shfl_up(scan, off);
    if (lane >= off) scan += t;
  }
  float F0 = scan - lsum;
  float gv[32];
  float F = F0, lmax = -1e30f;
#pragma unroll
  for (int e = 0; e < 32; ++e) {
    F += lf[e];
    float g = ipre[base + e] - F;
    gv[e] = g;
    lmax = fmaxf(lmax, g);
    garr[base + e] = g;
  }
  float ms = lmax;
#pragma unroll
  for (int off = 1; off < 64; off <<= 1) {
    float t = __shfl_up(ms, off);
    if (lane >= off) ms = fmaxf(ms, t);
  }
  float em = __shfl_up(ms, 1);
  if (lane == 0) em = -1e30f;
  float run = em;
  F = F0;
#pragma unroll
  for (int e = 0; e < 32; ++e) {
    F += lf[e];
    run = fmaxf(run, gv[e]);
    Marr[base + e] = run;
    earr[base + e] = expf(-(F + run));
  }
}

// ---------------- mLSTM parallel, bf16 MFMA flash-style, s-split x4 ----------------
__global__ __launch_bounds__(256) void mlstm_mfma_kernel(
    const unsigned short* __restrict__ Q, const unsigned short* __restrict__ Kb,
    const unsigned short* __restrict__ vT, const float* __restrict__ garr,
    const float* __restrict__ Marr,
    float* __restrict__ hp, float* __restrict__ npart) {
  const int h = blockIdx.y;
  const int T = blockIdx.x;
  const int sp = blockIdx.z;
  float* hpart = hp + (size_t)sp * 2097152;
  const int tid = threadIdx.x;
  const int w = tid >> 6, l = tid & 63;
  const int lr = l & 15, lg = l >> 4;
  const int hbase = h * S_LEN;
  const int sr = tid >> 4;
  const int sc = tid & 15;

  __shared__ __align__(16) unsigned short Ks[64 * 128];
  __shared__ __align__(16) unsigned short Vs[256 * 64];
  __shared__ __align__(16) unsigned short Ps[64 * 64];

  bf16x8 qf[4];
  {
    const unsigned short* qrow = Q + (size_t)(T * 64 + w * 16 + lr) * 512 + h * 128 + lg * 8;
#pragma unroll
    for (int kt = 0; kt < 4; ++kt) {
      cvu c;
      c.u = *(const u16x8*)(qrow + kt * 32);
      qf[kt] = c.b;
    }
  }
  float Mt[4];
#pragma unroll
  for (int j = 0; j < 4; ++j) Mt[j] = Marr[hbase + T * 64 + w * 16 + lg * 4 + j];

  f32x4v pv[16] = {};
  float nacc[4] = {0.f, 0.f, 0.f, 0.f};
  const float rs = 0.08838834764831845f;  // 1/sqrt(128)

  for (int ch = sp; ch <= T; ch += 4) {
    const int s0 = ch * 64;
    __syncthreads();
#pragma unroll
    for (int i = 0; i < 4; ++i) {
      int r = i * 16 + sr;
      u16x8 u = *(const u16x8*)(Kb + (size_t)(s0 + r) * 512 + h * 128 + sc * 8);
      int byte = r * 256 + ((sc * 16) ^ ((r & 7) << 4));
      *(u16x8*)((char*)Ks + byte) = u;
    }
#pragma unroll
    for (int i = 0; i < 16; ++i) {
      int r = i * 16 + sr;
      u16x4 u = *(const u16x4*)(vT + (size_t)(h * 256 + r) * S_LEN + s0 + sc * 4);
      int byte = r * 128 + ((sc * 8) ^ ((r & 7) << 4));
      *(u16x4*)((char*)Vs + byte) = u;
    }
    __syncthreads();
    f32x4v sa[4] = {};
#pragma unroll
    for (int ni = 0; ni < 4; ++ni) {
#pragma unroll
      for (int kt = 0; kt < 4; ++kt) {
        int row = ni * 16 + lr;
        int byte = row * 256 + (((kt * 32 + lg * 8) * 2) ^ ((row & 7) << 4));
        bf16x8 kf = ld_bf8(Ks, byte);
        sa[ni] = __builtin_amdgcn_mfma_f32_16x16x32_bf16(qf[kt], kf, sa[ni], 0, 0, 0);
      }
    }
#pragma unroll
    for (int ni = 0; ni < 4; ++ni) {
      int sl = ni * 16 + lr;
      int sg = s0 + sl;
      float gv = garr[hbase + sg];
#pragma unroll
      for (int j = 0; j < 4; ++j) {
        int tloc = w * 16 + lg * 4 + j;
        int tg = T * 64 + tloc;
        float wgt = (sg <= tg) ? __expf(gv - Mt[j]) : 0.f;
        float val = sa[ni][j] * rs * wgt;
        nacc[j] += val;
        int byte = tloc * 128 + ((sl * 2) ^ ((tloc & 7) << 4));
        *(unsigned short*)((char*)Ps + byte) = bf_us(val);
      }
    }
#pragma unroll
    for (int kt2 = 0; kt2 < 2; ++kt2) {
      int tloc = w * 16 + lr;
      int sb = (kt2 * 32 + lg * 8) * 2;
      bf16x8 pa = ld_bf8(Ps, tloc * 128 + (sb ^ ((tloc & 7) << 4)));
#pragma unroll
      for (int nv = 0; nv < 16; ++nv) {
        int dv = nv * 16 + lr;
        bf16x8 vb = ld_bf8(Vs, dv * 128 + (sb ^ ((dv & 7) << 4)));
        pv[nv] = __builtin_amdgcn_mfma_f32_16x16x32_bf16(pa, vb, pv[nv], 0, 0, 0);
      }
    }
  }
#pragma unroll
  for (int j = 0; j < 4; ++j) {
#pragma unroll
    for (int off = 1; off < 16; off <<= 1) nacc[j] += __shfl_xor(nacc[j], off);
  }
#pragma unroll
  for (int j = 0; j < 4; ++j) {
    int tg = T * 64 + w * 16 + lg * 4 + j;
    if (lr == 0) npart[sp * 8192 + hbase + tg] = nacc[j];
    float* orow = hpart + (size_t)tg * DMODEL + h * 256;
#pragma unroll
    for (int nvt = 0; nvt < 16; ++nvt) orow[nvt * 16 + lr] = pv[nvt][j];
  }
}

// ---------------- combine(4) + multihead LayerNorm * mhw * sigmoid(og) -> bf16 ----
__global__ __launch_bounds__(256) void mhln_gate_kernel(
    const float* __restrict__ hp, const float* __restrict__ npart,
    const float* __restrict__ earr, const float* __restrict__ mhw,
    const float* __restrict__ og, unsigned short* __restrict__ gact) {
  int s = blockIdx.x;
  int head = threadIdx.x >> 6, lane = threadIdx.x & 63;
  float n = (npart[head * S_LEN + s] + npart[8192 + head * S_LEN + s]) +
            (npart[16384 + head * S_LEN + s] + npart[24576 + head * S_LEN + s]);
  float nvv = fmaxf(fabsf(n), earr[head * S_LEN + s]);
  float inv = 1.0f / (nvv + 1e-6f);
  const size_t base = (size_t)s * DMODEL + head * 256;
  float vq[4];
#pragma unroll
  for (int qy = 0; qy < 4; ++qy) {
    size_t o = base + qy * 64 + lane;
    vq[qy] = ((hp[o] + hp[o + 2097152]) + (hp[o + 4194304] + hp[o + 6291456])) * inv;
  }
  float sum = vq[0] + vq[1] + vq[2] + vq[3];
#pragma unroll
  for (int off = 32; off > 0; off >>= 1) sum += __shfl_xor(sum, off);
  float mu = sum * (1.0f / 256.0f);
  float d0 = vq[0] - mu, d1 = vq[1] - mu, d2 = vq[2] - mu, d3 = vq[3] - mu;
  float vs = d0 * d0 + d1 * d1 + d2 * d2 + d3 * d3;
#pragma unroll
  for (int off = 32; off > 0; off >>= 1) vs += __shfl_xor(vs, off);
  float rstd = rsqrtf(vs * (1.0f / 256.0f) + 1e-6f);
  float dn[4] = {d0, d1, d2, d3};
#pragma unroll
  for (int qy = 0; qy < 4; ++qy) {
    int c = head * 256 + qy * 64 + lane;
    float ov = og[(size_t)s * DMODEL + c];
    gact[(size_t)s * DMODEL + c] = bf_us(dn[qy] * rstd * mhw[c] * fast_sigmoid(ov));
  }
}

extern "C" void kernel_launch(void* const* d_in, const int* in_sizes, int n_in,
                              void* d_out, int out_size, void* d_ws, size_t ws_size,
                              hipStream_t stream) {
  (void)in_sizes; (void)n_in; (void)out_size; (void)ws_size;
  const int*   tok   = (const int*)d_in[0];
  const float* emb   = (const float*)d_in[1];
  const float* norm1 = (const float*)d_in[2];
  const float* Wq    = (const float*)d_in[3];
  const float* Wk    = (const float*)d_in[4];
  const float* Wv    = (const float*)d_in[5];
  const float* Wog   = (const float*)d_in[6];
  const float* Wi    = (const float*)d_in[7];
  const float* bi    = (const float*)d_in[8];
  const float* Wf    = (const float*)d_in[9];
  const float* bfp   = (const float*)d_in[10];
  const float* mhw   = (const float*)d_in[11];
  const float* Wout  = (const float*)d_in[12];
  const float* norm2 = (const float*)d_in[13];
  const float* Wg    = (const float*)d_in[14];
  const float* Wu    = (const float*)d_in[15];
  const float* Wd    = (const float*)d_in[16];
  const float* onw   = (const float*)d_in[17];
  const float* Wlm   = (const float*)d_in[18];

  char* wsb = (char*)d_ws;
  const size_t MB = 1ull << 20;
  float*          x    = (float*)wsb;                          // 8 MiB
  unsigned short* xmb  = (unsigned short*)(wsb + 8 * MB);      // 4 MiB
  float*          ipre = (float*)(wsb + 12 * MB);              // scalars region
  float*          fpre = ipre + 8192;
  float*          garr = fpre + 8192;
  float*          Marr = garr + 8192;
  float*          earr = Marr + 8192;
  float*          npart = earr + 8192;                         // 4 x 32 KiB
  unsigned short* W16  = (unsigned short*)(wsb + 13 * MB);     // 49 MiB -> ends 62
  const size_t OQ = 0, OKk = 524288, OV = 1048576, OOG = 2097152, OOUT = 3145728,
               OGt = 4194304, OU = 7077888, OD = 9961472;
  unsigned short* qb    = (unsigned short*)(wsb + 62 * MB);    // 2 MiB
  unsigned short* kb    = (unsigned short*)(wsb + 64 * MB);    // 2 MiB
  unsigned short* vTb   = (unsigned short*)(wsb + 66 * MB);    // 4 MiB
  float*          og    = (float*)(wsb + 70 * MB);             // 8 MiB
  float*          hp    = (float*)(wsb + 78 * MB);             // 4 x 8 MiB -> ends 110
  unsigned short* gact  = (unsigned short*)(wsb + 110 * MB);   // 4 MiB
  unsigned short* Gb16  = (unsigned short*)(wsb + 114 * MB);   // 11 MiB -> ends 125
  unsigned short* wlm16 = (unsigned short*)(wsb + 126 * MB);   // 62.5 MiB -> ends 188.5

  embed_kernel<<<2048, 256, 0, stream>>>(tok, emb, x);
  wcvt8_kernel<<<28544, 256, 0, stream>>>(Wq, Wk, Wv, Wog, Wout, Wg, Wu, Wd, Wlm,
                                          W16, wlm16);

  for (int l = 0; l < 2; ++l) {
    const unsigned short* Wl = W16 + (size_t)l * WLAYER;
    const float* n1   = norm1 + (size_t)l * 1024;
    const float* wiv  = Wi   + (size_t)l * 4 * 1024;
    const float* bil  = bi   + (size_t)l * 4;
    const float* wfv  = Wf   + (size_t)l * 4 * 1024;
    const float* bfl  = bfp  + (size_t)l * 4;
    const float* mhwl = mhw  + (size_t)l * 1024;
    const float* n2   = norm2 + (size_t)l * 1024;

    rmsnorm_kernel<<<2048, 256, 0, stream>>>(x, n1, xmb);
    qkvo_kernel<<<dim3(16, 24), 256, 0, stream>>>(xmb, Wl + OQ, Wl + OKk, Wl + OV,
                                                  Wl + OOG, qb, kb, vTb, og);
    gates_kernel<<<2048, 256, 0, stream>>>(x, n1, wiv, bil, wfv, bfl, ipre, fpre);
    scan_kernel<<<1, 256, 0, stream>>>(ipre, fpre, garr, Marr, earr);
    mlstm_mfma_kernel<<<dim3(32, 4, 4), 256, 0, stream>>>(qb, kb, vTb, garr, Marr,
                                                          hp, npart);
    mhln_gate_kernel<<<2048, 256, 0, stream>>>(hp, npart, earr, mhwl, og, gact);
    gemm_bn64_kernel<1><<<dim3(16, 16), 256, 0, stream>>>(gact, Wl + OOUT, x, x, 1024, 1024);
    rmsnorm_kernel<<<2048, 256, 0, stream>>>(x, n2, xmb);
    ffn_kernel<<<dim3(16, 44), 256, 0, stream>>>(xmb, Wl + OGt, Wl + OU, Gb16);
    gemm_bn64_kernel<1><<<dim3(16, 16), 256, 0, stream>>>(Gb16, Wl + OD, x, x, 2816, 1024);
  }

  rmsnorm_kernel<<<2048, 256, 0, stream>>>(x, onw, xmb);
  lm256_kernel<<<dim3(8, 125), 512, 0, stream>>>(xmb, wlm16, (float*)d_out);
}